// Round 7
// baseline (412.725 us; speedup 1.0000x reference)
//
#include <hip/hip_runtime.h>
#include <cstddef>

#define NN 50000
#define NREL 3
#define NE 250000
#define NP 100000
#define FIN 128
#define HD 256
#define SLOPE 0.2f

typedef short bf16x8 __attribute__((ext_vector_type(8)));
typedef float f32x4 __attribute__((ext_vector_type(4)));

__device__ __forceinline__ short f2bf(float f) {
  unsigned u = __float_as_uint(f);
  unsigned r = (u + 0x7FFFu + ((u >> 16) & 1u)) >> 16;   // RNE
  return (short)r;
}
__device__ __forceinline__ float bf2f(short s) {
  return __uint_as_float(((unsigned)(unsigned short)s) << 16);
}

// ---- fused bf16 MFMA GEMM + el/er epilogue, batched over relations -------
// C = A[M,K] @ Wt[r][N_][K]^T ; writes featb[r] (bf16) and el/er[r] (f32).
// Block covers WM*64 rows x WN*64 = N_ cols (full row width).
template<int N_, int WM, int WN>
__global__ __launch_bounds__(256) void gemm_fused(
    const short* __restrict__ A,     // [M][K] bf16
    const short* __restrict__ Wt,    // [NREL][N_][K] bf16
    const float* __restrict__ al,    // [NREL][N_]
    const float* __restrict__ ar,    // [NREL][N_]
    short* __restrict__ featb,       // [NREL][M][N_] bf16
    float* __restrict__ el,          // [NREL][NN]
    float* __restrict__ er,          // [NREL][NN]
    int M, int K)
{
  const int r = blockIdx.y;
  const short* Bt  = Wt + (size_t)r * N_ * K;
  const float* alr = al + r * N_;
  const float* arr = ar + r * N_;
  short* fb  = featb + (size_t)r * M * N_;
  float* elr = el + r * NN;
  float* err = er + r * NN;

  const int lane = threadIdx.x & 63;
  const int wave = threadIdx.x >> 6;
  const int wm = wave / WN;
  const int wn = wave % WN;
  const int m0 = blockIdx.x * (WM * 64) + wm * 64;
  const int n0 = wn * 64;
  const int c    = lane & 15;
  const int rgrp = lane >> 4;
  const int koff = rgrp * 8;

  f32x4 acc[4][4] = {};
  for (int k0 = 0; k0 < K; k0 += 32) {
    bf16x8 a[4], b[4];
#pragma unroll
    for (int i = 0; i < 4; ++i) {
      int row = m0 + i * 16 + c;
      row = row < M ? row : M - 1;
      a[i] = *(const bf16x8*)&A[(size_t)row * K + k0 + koff];
    }
#pragma unroll
    for (int j = 0; j < 4; ++j)
      b[j] = *(const bf16x8*)&Bt[(size_t)(n0 + j * 16 + c) * K + k0 + koff];
#pragma unroll
    for (int i = 0; i < 4; ++i)
#pragma unroll
      for (int j = 0; j < 4; ++j)
        acc[i][j] = __builtin_amdgcn_mfma_f32_16x16x32_bf16(a[i], b[j], acc[i][j], 0, 0, 0);
  }

  // ---- epilogue: featb (bf16) + el/er partial dots from f32 acc ----------
  __shared__ float2 part[WN][WM * 64];
  float pe[4][4], pr[4][4];                     // [i][v]
#pragma unroll
  for (int i = 0; i < 4; ++i)
#pragma unroll
    for (int v = 0; v < 4; ++v) {
      float se = 0.f, sr = 0.f;
#pragma unroll
      for (int j = 0; j < 4; ++j) {
        float av = acc[i][j][v];
        int col = n0 + j * 16 + c;
        se = fmaf(av, alr[col], se);
        sr = fmaf(av, arr[col], sr);
      }
      pe[i][v] = se; pr[i][v] = sr;
    }
#pragma unroll
  for (int i = 0; i < 4; ++i) {
#pragma unroll
    for (int v = 0; v < 4; ++v) {
      int row = m0 + i * 16 + rgrp * 4 + v;
      if (row < M) {
#pragma unroll
        for (int j = 0; j < 4; ++j)
          fb[(size_t)row * N_ + n0 + j * 16 + c] = f2bf(acc[i][j][v]);
      }
#pragma unroll
      for (int off = 1; off < 16; off <<= 1) {
        pe[i][v] += __shfl_xor(pe[i][v], off);
        pr[i][v] += __shfl_xor(pr[i][v], off);
      }
    }
  }
  if (c == 0) {
#pragma unroll
    for (int i = 0; i < 4; ++i)
#pragma unroll
      for (int v = 0; v < 4; ++v)
        part[wn][wm * 64 + i * 16 + rgrp * 4 + v] = make_float2(pe[i][v], pr[i][v]);
  }
  __syncthreads();
  const int t = threadIdx.x;
  if (t < WM * 64) {
    float se = 0.f, sr = 0.f;
#pragma unroll
    for (int w = 0; w < WN; ++w) { se += part[w][t].x; sr += part[w][t].y; }
    int row = blockIdx.x * (WM * 64) + t;
    if (row < M) { elr[row] = se; err[row] = sr; }
  }
}

// ---------------- f32 -> bf16 (flat, n multiple of 4) ---------------------
__global__ __launch_bounds__(256) void conv_bf16(
    const float* __restrict__ in, short* __restrict__ out, int n)
{
  int i = (blockIdx.x * 256 + threadIdx.x) * 4;
  if (i >= n) return;
  float4 v = *(const float4*)&in[i];
  short4 o = {f2bf(v.x), f2bf(v.y), f2bf(v.z), f2bf(v.w)};
  *(short4*)&out[i] = o;
}

// ---------------- W[r][K][N] f32 -> Wt[r][N][K] bf16 ----------------------
__global__ __launch_bounds__(256) void wt_conv(
    const float* __restrict__ W, short* __restrict__ Wt, int R, int K, int N)
{
  int tid = blockIdx.x * 256 + threadIdx.x;
  if (tid >= R * K * N) return;
  int r = tid / (K * N);
  int rem = tid - r * K * N;
  int n = rem / K;
  int k = rem - n * K;
  Wt[tid] = f2bf(W[((size_t)r * K + k) * N + n]);
}

// ------- beff1[n] = sum_r b1[r][n]/3 ; beff2 likewise ---------------------
__global__ __launch_bounds__(256) void make_beff(
    const float* __restrict__ b1, const float* __restrict__ b2,
    float* __restrict__ beff1, float* __restrict__ beff2)
{
  int t = blockIdx.x * 256 + threadIdx.x;
  if (t < HD) beff1[t] = (b1[t] + b1[HD + t] + b1[2 * HD + t]) * (1.f / 3.f);
  else if (t < HD + FIN) {
    int k = t - HD;
    beff2[k] = (b2[k] + b2[FIN + k] + b2[2 * FIN + k]) * (1.f / 3.f);
  }
}

// ------------- CSR build: degree count ------------------------------------
__global__ __launch_bounds__(256) void count_deg(
    const int* __restrict__ edges, int* __restrict__ deg)
{
  int tid = blockIdx.x * blockDim.x + threadIdx.x;
  if (tid >= NREL * NE) return;
  int r = tid / NE;
  int e = tid - r * NE;
  int d = edges[(size_t)r * 2 * NE + NE + e];
  atomicAdd(&deg[r * NN + d], 1);
}

// ------------- CSR scan phase 1: per-block (1000 nodes) partial sums ------
__global__ __launch_bounds__(256) void deg_partial(
    const int* __restrict__ deg, int* __restrict__ psum)
{
  const int b = blockIdx.x;
  const int t = threadIdx.x;
  int4 v = {0, 0, 0, 0};
  if (t < 250) v = *(const int4*)&deg[b * 1000 + t * 4];
  int s = v.x + v.y + v.z + v.w;
#pragma unroll
  for (int off = 32; off > 0; off >>= 1) s += __shfl_down(s, off);
  __shared__ int ws[4];
  if ((t & 63) == 0) ws[t >> 6] = s;
  __syncthreads();
  if (t == 0) psum[b] = ws[0] + ws[1] + ws[2] + ws[3];
}

// ------------- CSR scan phase 2: scan the 150 partials (1 block) ----------
__global__ __launch_bounds__(256) void scan_psum(
    const int* __restrict__ psum, int* __restrict__ pexcl)
{
  __shared__ int lds[256];
  const int t = threadIdx.x;
  int v = (t < 150) ? psum[t] : 0;
  lds[t] = v;
  __syncthreads();
  for (int off = 1; off < 256; off <<= 1) {
    int add = (t >= off) ? lds[t - off] : 0;
    __syncthreads();
    lds[t] += add;
    __syncthreads();
  }
  if (t < 150) pexcl[t] = lds[t] - v;
}

// ------------- CSR scan phase 3: local scan + write row_ptr ---------------
__global__ __launch_bounds__(256) void deg_rowptr(
    const int* __restrict__ deg, const int* __restrict__ pexcl,
    int* __restrict__ row_ptr)
{
  const int b = blockIdx.x;
  const int t = threadIdx.x;
  int4 v = {0, 0, 0, 0};
  if (t < 250) v = *(const int4*)&deg[b * 1000 + t * 4];
  int s = v.x + v.y + v.z + v.w;
  __shared__ int lds[256];
  lds[t] = s;
  __syncthreads();
  for (int off = 1; off < 256; off <<= 1) {
    int add = (t >= off) ? lds[t - off] : 0;
    __syncthreads();
    lds[t] += add;
    __syncthreads();
  }
  int run = lds[t] - s + pexcl[b];
  if (t < 250) {
    int i = b * 1000 + t * 4;
    row_ptr[i] = run;     run += v.x;
    row_ptr[i + 1] = run; run += v.y;
    row_ptr[i + 2] = run; run += v.z;
    row_ptr[i + 3] = run;
  }
  if (b == 0 && t == 0) row_ptr[NREL * NN] = NREL * NE;
}

// ------------- CSR build: fill src lists ----------------------------------
__global__ __launch_bounds__(256) void fill_csr(
    const int* __restrict__ edges, const int* __restrict__ row_ptr,
    int* __restrict__ cursor, int* __restrict__ csr_src)
{
  int tid = blockIdx.x * blockDim.x + threadIdx.x;
  if (tid >= NREL * NE) return;
  int r = tid / NE;
  int e = tid - r * NE;
  const int* base = edges + (size_t)r * 2 * NE;
  int s = base[e];
  int d = base[NE + e];
  int pos = atomicAdd(&cursor[r * NN + d], 1);
  csr_src[row_ptr[r * NN + d] + pos] = s;
}

// ------- fused 3-relation group-parallel gather over PROJECTED feats ------
// wave per node; within pass 2, GL lanes/group fetch NG=64/GL edges at once.
// L1MODE: out = relu(tot/3+beff) -> hb bf16.  else: fused predictor dots.
template<int D, int GL, int L1MODE>
__global__ __launch_bounds__(256) void gat_agg3(
    const int* __restrict__ row_ptr,   // [NREL*NN+1] absolute
    const int* __restrict__ csr_src,
    const float* __restrict__ el,      // [NREL][NN]
    const float* __restrict__ er,
    const short* __restrict__ featb,   // [NREL][NN][D] bf16
    const float* __restrict__ beff,    // [D]
    short* __restrict__ hb,            // L1MODE
    const float* __restrict__ Wlin,    // !L1MODE
    float* __restrict__ dotl, float* __restrict__ dotr)
{
  constexpr int CPL = D / GL;          // 16
  constexpr int NG  = 64 / GL;
  typedef short svec __attribute__((ext_vector_type(CPL)));
  const int lane = threadIdx.x & 63;
  const int node = blockIdx.x * 4 + (threadIdx.x >> 6);
  if (node >= NN) return;
  const int g  = lane / GL;
  const int cl = lane - g * GL;

  float tot[CPL];
#pragma unroll
  for (int k = 0; k < CPL; ++k) tot[k] = 0.f;

#pragma unroll
  for (int r = 0; r < NREL; ++r) {
    const int beg = row_ptr[r * NN + node];
    const int end = row_ptr[r * NN + node + 1];
    const float eri = er[r * NN + node];
    const float* elr = el + r * NN;
    const short* fb  = featb + (size_t)r * NN * D;

    // pass 1: segment max (first-chunk score cached)
    int   sidx0 = 0;
    float s0 = -3.4e38f;
    if (beg + lane < end) {
      sidx0 = csr_src[beg + lane];
      float t = elr[sidx0] + eri;
      s0 = t > 0.f ? t : SLOPE * t;
    }
    float m = s0;
    for (int e = beg + 64 + lane; e < end; e += 64) {
      int si = csr_src[e];
      float t = elr[si] + eri;
      t = t > 0.f ? t : SLOPE * t;
      m = fmaxf(m, t);
    }
#pragma unroll
    for (int off = 32; off > 0; off >>= 1) m = fmaxf(m, __shfl_xor(m, off));

    // pass 2: exp + denom + group-parallel weighted gather
    float dsum = 0.f;
    float facc[CPL];
#pragma unroll
    for (int k = 0; k < CPL; ++k) facc[k] = 0.f;

    for (int chunk = beg; chunk < end; chunk += 64) {
      int e = chunk + lane;
      int sidx; float s;
      if (chunk == beg) { sidx = sidx0; s = s0; }
      else {
        sidx = 0; s = -3.4e38f;
        if (e < end) {
          sidx = csr_src[e];
          float t = elr[sidx] + eri;
          s = t > 0.f ? t : SLOPE * t;
        }
      }
      float a = (e < end) ? __expf(s - m) : 0.f;
      dsum += a;
      const int cnt = (end - chunk < 64) ? end - chunk : 64;
      for (int i = g; i < cnt; i += NG) {
        float aj = __shfl(a, i);
        int   sj = __shfl(sidx, i);
        svec f16 = *(const svec*)&fb[(size_t)sj * D + cl * CPL];
#pragma unroll
        for (int k = 0; k < CPL; ++k) facc[k] = fmaf(bf2f(f16[k]), aj, facc[k]);
      }
    }
#pragma unroll
    for (int off = 32; off > 0; off >>= 1) dsum += __shfl_xor(dsum, off);
    const float inv = 1.f / fmaxf(dsum, 1e-9f);
#pragma unroll
    for (int k = 0; k < CPL; ++k) tot[k] = fmaf(facc[k], inv, tot[k]);
  }

  // reduce across the NG groups
#pragma unroll
  for (int off = GL; off < 64; off <<= 1)
#pragma unroll
    for (int k = 0; k < CPL; ++k) tot[k] += __shfl_xor(tot[k], off);

  if (L1MODE) {
    if (g == 0) {
      svec o;
#pragma unroll
      for (int k = 0; k < CPL; ++k)
        o[k] = f2bf(fmaxf(tot[k] * (1.f / 3.f) + beff[cl * CPL + k], 0.f));
      *(svec*)&hb[(size_t)node * D + cl * CPL] = o;
    }
  } else {
    float dl = 0.f, dr = 0.f;
    if (g == 0) {
#pragma unroll
      for (int k = 0; k < CPL; ++k) {
        int c = cl * CPL + k;
        float f = fmaxf(tot[k] * (1.f / 3.f) + beff[c], 0.f);
        dl = fmaf(f, Wlin[c], dl);
        dr = fmaf(f, Wlin[D + c], dr);
      }
    }
#pragma unroll
    for (int off = 32; off > 0; off >>= 1) {
      dl += __shfl_xor(dl, off);
      dr += __shfl_xor(dr, off);
    }
    if (lane == 0) { dotl[node] = dl; dotr[node] = dr; }
  }
}

// ------------- pair logits -------------------------------------------------
__global__ __launch_bounds__(256) void pair_out(
    const int* __restrict__ edges, const int* __restrict__ n_pairs,
    const float* __restrict__ dotl, const float* __restrict__ dotr,
    const float* __restrict__ blin, float* __restrict__ out)
{
  const int TOT = NREL * NE + NP;
  int p = blockIdx.x * blockDim.x + threadIdx.x;
  if (p >= TOT) return;
  int s, d;
  if (p < NREL * NE) {
    int r = p / NE;
    int e = p - r * NE;
    const int* base = edges + (size_t)r * 2 * NE;
    s = base[e];
    d = base[NE + e];
  } else {
    int q = p - NREL * NE;
    s = n_pairs[2 * q];
    d = n_pairs[2 * q + 1];
  }
  float logit = dotl[s] + dotr[d] + blin[0];
  out[p] = 1.f / (1.f + expf(-logit));
}

extern "C" void kernel_launch(void* const* d_in, const int* in_sizes, int n_in,
                              void* d_out, int out_size, void* d_ws, size_t ws_size,
                              hipStream_t stream) {
  const float* x      = (const float*)d_in[0];
  const int*   edges  = (const int*)d_in[1];
  const int*   npairs = (const int*)d_in[2];
  const float* W1     = (const float*)d_in[3];
  const float* al1    = (const float*)d_in[4];
  const float* ar1    = (const float*)d_in[5];
  const float* b1     = (const float*)d_in[6];
  const float* W2     = (const float*)d_in[7];
  const float* al2    = (const float*)d_in[8];
  const float* ar2    = (const float*)d_in[9];
  const float* b2     = (const float*)d_in[10];
  const float* Wlin   = (const float*)d_in[11];
  const float* blin   = (const float*)d_in[12];
  float* out = (float*)d_out;

  char* w = (char*)d_ws;
  size_t off = 0;
  auto alloc = [&](size_t bytes) {
    char* p = w + off;
    off = (off + bytes + 255) & ~(size_t)255;
    return p;
  };
  short* xb      = (short*)alloc((size_t)NN * FIN * 2);            // 12.8 MB
  short* hb      = (short*)alloc((size_t)NN * HD * 2);             // 25.6 MB
  short* featb   = (short*)alloc((size_t)NREL * NN * HD * 2);      // 76.8 MB (L2 reuses)
  short* W1t     = (short*)alloc((size_t)NREL * FIN * HD * 2);
  short* W2t     = (short*)alloc((size_t)NREL * FIN * HD * 2);
  float* beff1   = (float*)alloc(HD * 4);
  float* beff2   = (float*)alloc(FIN * 4);
  float* el      = (float*)alloc((size_t)NREL * NN * 4);
  float* er      = (float*)alloc((size_t)NREL * NN * 4);
  float* dotl    = (float*)alloc((size_t)NN * 4);
  float* dotr    = (float*)alloc((size_t)NN * 4);
  int*   deg     = (int*)  alloc((size_t)NREL * NN * 4);
  int*   cursor  = (int*)  alloc((size_t)NREL * NN * 4);
  int*   row_ptr = (int*)  alloc((size_t)(NREL * NN + 16) * 4);
  int*   psum    = (int*)  alloc(1024);
  int*   pexcl   = (int*)  alloc(1024);
  int*   csr_src = (int*)  alloc((size_t)NREL * NE * 4);

  const int B = 256;

  // ---------------- prep: conversions -------------------------------------
  conv_bf16<<<(NN * FIN / 4 + B - 1) / B, B, 0, stream>>>(x, xb, NN * FIN);
  wt_conv<<<(NREL * FIN * HD + B - 1) / B, B, 0, stream>>>(W1, W1t, NREL, FIN, HD);
  wt_conv<<<(NREL * HD * FIN + B - 1) / B, B, 0, stream>>>(W2, W2t, NREL, HD, FIN);
  make_beff<<<2, B, 0, stream>>>(b1, b2, beff1, beff2);

  // ---------------- CSR build (shared by both layers) ---------------------
  hipMemsetAsync(deg, 0, (size_t)NREL * NN * 4, stream);
  hipMemsetAsync(cursor, 0, (size_t)NREL * NN * 4, stream);
  count_deg<<<(NREL * NE + B - 1) / B, B, 0, stream>>>(edges, deg);
  deg_partial<<<150, B, 0, stream>>>(deg, psum);
  scan_psum<<<1, B, 0, stream>>>(psum, pexcl);
  deg_rowptr<<<150, B, 0, stream>>>(deg, pexcl, row_ptr);
  fill_csr<<<(NREL * NE + B - 1) / B, B, 0, stream>>>(edges, row_ptr, cursor, csr_src);

  const int AGG_G = (NN + 3) / 4;

  // ---------------- layer 1: feat = x@W1_r, gather -> hb ------------------
  {
    dim3 g((NN + 63) / 64, NREL);
    gemm_fused<HD, 1, 4><<<g, B, 0, stream>>>(xb, W1t, al1, ar1, featb, el, er, NN, FIN);
  }
  gat_agg3<HD, 16, 1><<<AGG_G, B, 0, stream>>>(
      row_ptr, csr_src, el, er, featb, beff1, hb, nullptr, nullptr, nullptr);

  // ---------------- layer 2: feat = h@W2_r, gather -> dots ----------------
  {
    dim3 g((NN + 127) / 128, NREL);
    gemm_fused<FIN, 2, 2><<<g, B, 0, stream>>>(hb, W2t, al2, ar2, featb, el, er, NN, HD);
  }
  gat_agg3<FIN, 8, 0><<<AGG_G, B, 0, stream>>>(
      row_ptr, csr_src, el, er, featb, beff2, nullptr, Wlin, dotl, dotr);

  // ---------------- pair predictor ----------------------------------------
  const int TOT = NREL * NE + NP;
  pair_out<<<(TOT + B - 1) / B, B, 0, stream>>>(edges, npairs, dotl, dotr, blin, out);
}

// Round 8
// 411.627 us; speedup vs baseline: 1.0027x; 1.0027x over previous
//
#include <hip/hip_runtime.h>
#include <cstddef>

#define NN 50000
#define NREL 3
#define NE 250000
#define NP 100000
#define FIN 128
#define HD 256
#define SLOPE 0.2f

typedef short bf16x8 __attribute__((ext_vector_type(8)));
typedef short bf16x2 __attribute__((ext_vector_type(2)));
typedef float f32x4 __attribute__((ext_vector_type(4)));

__device__ __forceinline__ short f2bf(float f) {
  unsigned u = __float_as_uint(f);
  unsigned r = (u + 0x7FFFu + ((u >> 16) & 1u)) >> 16;   // RNE
  return (short)r;
}
__device__ __forceinline__ float bf2f(short s) {
  return __uint_as_float(((unsigned)(unsigned short)s) << 16);
}

// ---------------- fused prep: xb, W1d (dup hi/lo), W2t, wvec1, beff -------
// block ranges: [0,6250) xconv | [6250,7018) W1d | [7018,7402) W2t
//               [7402,7594) wvec1 | [7594,7596) beff
__global__ __launch_bounds__(256) void prep_all(
    const float* __restrict__ x,  const float* __restrict__ W1,
    const float* __restrict__ W2, const float* __restrict__ al1,
    const float* __restrict__ ar1, const float* __restrict__ b1,
    const float* __restrict__ b2,
    short* __restrict__ xb, short* __restrict__ W1d, short* __restrict__ W2t,
    float* __restrict__ wvec1, float* __restrict__ beff1, float* __restrict__ beff2)
{
  const int blk = blockIdx.x;
  const int t = threadIdx.x;
  if (blk < 6250) {                                   // x -> bf16
    int i = (blk * 256 + t) * 4;
    float4 v = *(const float4*)&x[i];
    short4 o = {f2bf(v.x), f2bf(v.y), f2bf(v.z), f2bf(v.w)};
    *(short4*)&xb[i] = o;
  } else if (blk < 7018) {                            // W1d[n][k], k<768
    int o = (blk - 6250) * 256 + t;
    if (o < HD * 2 * NREL * FIN) {
      int n = o / (2 * NREL * FIN);
      int k = o - n * (2 * NREL * FIN);
      int k2 = (k < NREL * FIN) ? k : k - NREL * FIN;
      int r = k2 / FIN, kk = k2 - r * FIN;
      W1d[o] = f2bf(W1[((size_t)r * FIN + kk) * HD + n]);
    }
  } else if (blk < 7402) {                            // W2t[r][n][k]
    int o = (blk - 7018) * 256 + t;
    if (o < NREL * FIN * HD) {
      int r = o / (FIN * HD);
      int rem = o - r * (FIN * HD);
      int n = rem / HD, k = rem - n * HD;
      W2t[o] = f2bf(W2[((size_t)r * HD + k) * FIN + n]);
    }
  } else if (blk < 7594) {                            // wvec1[j][k] = W1_r[k,:]·v
    int wid = (blk - 7402) * 4 + (t >> 6);
    int lane = t & 63;
    if (wid < 6 * FIN) {
      int j = wid / FIN, k = wid - j * FIN;
      int side = j / 3, r = j - side * 3;
      const float* v  = (side ? ar1 : al1) + r * HD;
      const float* Wr = W1 + ((size_t)r * FIN + k) * HD;
      float s = 0.f;
      for (int n = lane; n < HD; n += 64) s += Wr[n] * v[n];
#pragma unroll
      for (int off = 32; off > 0; off >>= 1) s += __shfl_down(s, off);
      if (lane == 0) wvec1[wid] = s;
    }
  } else {                                            // beff
    int t2 = (blk - 7594) * 256 + t;
    if (t2 < HD) beff1[t2] = (b1[t2] + b1[HD + t2] + b1[2 * HD + t2]) * (1.f / 3.f);
    else if (t2 < HD + FIN) {
      int k = t2 - HD;
      beff2[k] = (b2[k] + b2[FIN + k] + b2[2 * FIN + k]) * (1.f / 3.f);
    }
  }
}

// ------- el/er for layer 1: d[j] = xb[i,:]·wvec1[j,:], j<6 ----------------
__global__ __launch_bounds__(256) void rowdot6(
    const short* __restrict__ feat, const float* __restrict__ wvec,
    float* __restrict__ el, float* __restrict__ er)
{
  const int lane = threadIdx.x & 63;
  const int node = blockIdx.x * 4 + (threadIdx.x >> 6);
  if (node >= NN) return;
  bf16x2 f16 = *(const bf16x2*)&feat[(size_t)node * FIN + lane * 2];
  float f0 = bf2f(f16[0]), f1 = bf2f(f16[1]);
  float d[6];
#pragma unroll
  for (int j = 0; j < 6; ++j)
    d[j] = f0 * wvec[j * FIN + lane * 2] + f1 * wvec[j * FIN + lane * 2 + 1];
#pragma unroll
  for (int off = 32; off > 0; off >>= 1)
#pragma unroll
    for (int j = 0; j < 6; ++j) d[j] += __shfl_xor(d[j], off);
  if (lane == 0) {
    el[0 * NN + node] = d[0]; el[1 * NN + node] = d[1]; el[2 * NN + node] = d[2];
    er[0 * NN + node] = d[3]; er[1 * NN + node] = d[4]; er[2 * NN + node] = d[5];
  }
}

// ------------- CSR build: degree count ------------------------------------
__global__ __launch_bounds__(256) void count_deg(
    const int* __restrict__ edges, int* __restrict__ deg)
{
  int tid = blockIdx.x * blockDim.x + threadIdx.x;
  if (tid >= NREL * NE) return;
  int r = tid / NE;
  int e = tid - r * NE;
  int d = edges[(size_t)r * 2 * NE + NE + e];
  atomicAdd(&deg[r * NN + d], 1);
}

// ------------- CSR scan phase 1 -------------------------------------------
__global__ __launch_bounds__(256) void deg_partial(
    const int* __restrict__ deg, int* __restrict__ psum)
{
  const int b = blockIdx.x;
  const int t = threadIdx.x;
  int4 v = {0, 0, 0, 0};
  if (t < 250) v = *(const int4*)&deg[b * 1000 + t * 4];
  int s = v.x + v.y + v.z + v.w;
#pragma unroll
  for (int off = 32; off > 0; off >>= 1) s += __shfl_down(s, off);
  __shared__ int ws[4];
  if ((t & 63) == 0) ws[t >> 6] = s;
  __syncthreads();
  if (t == 0) psum[b] = ws[0] + ws[1] + ws[2] + ws[3];
}

// ------------- CSR scan phase 2 -------------------------------------------
__global__ __launch_bounds__(256) void scan_psum(
    const int* __restrict__ psum, int* __restrict__ pexcl)
{
  __shared__ int lds[256];
  const int t = threadIdx.x;
  int v = (t < 150) ? psum[t] : 0;
  lds[t] = v;
  __syncthreads();
  for (int off = 1; off < 256; off <<= 1) {
    int add = (t >= off) ? lds[t - off] : 0;
    __syncthreads();
    lds[t] += add;
    __syncthreads();
  }
  if (t < 150) pexcl[t] = lds[t] - v;
}

// ------------- CSR scan phase 3: row_ptr + cursor init --------------------
__global__ __launch_bounds__(256) void deg_rowptr(
    const int* __restrict__ deg, const int* __restrict__ pexcl,
    int* __restrict__ row_ptr, int* __restrict__ cursor)
{
  const int b = blockIdx.x;
  const int t = threadIdx.x;
  int4 v = {0, 0, 0, 0};
  if (t < 250) v = *(const int4*)&deg[b * 1000 + t * 4];
  int s = v.x + v.y + v.z + v.w;
  __shared__ int lds[256];
  lds[t] = s;
  __syncthreads();
  for (int off = 1; off < 256; off <<= 1) {
    int add = (t >= off) ? lds[t - off] : 0;
    __syncthreads();
    lds[t] += add;
    __syncthreads();
  }
  int run = lds[t] - s + pexcl[b];
  if (t < 250) {
    int i = b * 1000 + t * 4;
    row_ptr[i] = run;     cursor[i] = run;     run += v.x;
    row_ptr[i + 1] = run; cursor[i + 1] = run; run += v.y;
    row_ptr[i + 2] = run; cursor[i + 2] = run; run += v.z;
    row_ptr[i + 3] = run; cursor[i + 3] = run;
  }
  if (b == 0 && t == 0) row_ptr[NREL * NN] = NREL * NE;
}

// ------------- CSR build: fill src lists (cursor pre-filled) --------------
__global__ __launch_bounds__(256) void fill_csr(
    const int* __restrict__ edges, int* __restrict__ cursor,
    int* __restrict__ csr_src)
{
  int tid = blockIdx.x * blockDim.x + threadIdx.x;
  if (tid >= NREL * NE) return;
  int r = tid / NE;
  int e = tid - r * NE;
  const int* base = edges + (size_t)r * 2 * NE;
  int s = base[e];
  int d = base[NE + e];
  int pos = atomicAdd(&cursor[r * NN + d], 1);
  csr_src[pos] = s;
}

// ------- L1: input-space fused 3-relation gather, hi/lo bf16 out ----------
// wave per node; serial broadcast (low VGPR). A1[n][k]: hi at k=r*128+c,
// lo at k=384+r*128+c. 1/3 folded into inv.
__global__ __launch_bounds__(256) void gat_gather_hl(
    const int* __restrict__ row_ptr, const int* __restrict__ csr_src,
    const float* __restrict__ el, const float* __restrict__ er,
    const short* __restrict__ xb,       // [NN][FIN] bf16
    short* __restrict__ A1)             // [NN][768] bf16
{
  const int lane = threadIdx.x & 63;
  const int node = blockIdx.x * 4 + (threadIdx.x >> 6);
  if (node >= NN) return;

#pragma unroll
  for (int r = 0; r < NREL; ++r) {
    const int beg = row_ptr[r * NN + node];
    const int end = row_ptr[r * NN + node + 1];
    const float eri = er[r * NN + node];
    const float* elr = el + r * NN;

    int   sidx0 = 0;
    float s0 = -3.4e38f;
    if (beg + lane < end) {
      sidx0 = csr_src[beg + lane];
      float tv = elr[sidx0] + eri;
      s0 = tv > 0.f ? tv : SLOPE * tv;
    }
    float m = s0;
    for (int e = beg + 64 + lane; e < end; e += 64) {
      int si = csr_src[e];
      float tv = elr[si] + eri;
      tv = tv > 0.f ? tv : SLOPE * tv;
      m = fmaxf(m, tv);
    }
#pragma unroll
    for (int off = 32; off > 0; off >>= 1) m = fmaxf(m, __shfl_xor(m, off));

    float dsum = 0.f;
    float f0 = 0.f, f1 = 0.f;
    for (int chunk = beg; chunk < end; chunk += 64) {
      int e = chunk + lane;
      int sidx; float s;
      if (chunk == beg) { sidx = sidx0; s = s0; }
      else {
        sidx = 0; s = -3.4e38f;
        if (e < end) {
          sidx = csr_src[e];
          float tv = elr[sidx] + eri;
          s = tv > 0.f ? tv : SLOPE * tv;
        }
      }
      float a = (e < end) ? __expf(s - m) : 0.f;
      dsum += a;
      const int cnt = (end - chunk < 64) ? end - chunk : 64;
      for (int j = 0; j < cnt; ++j) {
        float aj = __shfl(a, j);
        int   sj = __shfl(sidx, j);
        bf16x2 v = *(const bf16x2*)&xb[(size_t)sj * FIN + lane * 2];
        f0 = fmaf(bf2f(v[0]), aj, f0);
        f1 = fmaf(bf2f(v[1]), aj, f1);
      }
    }
#pragma unroll
    for (int off = 32; off > 0; off >>= 1) dsum += __shfl_xor(dsum, off);
    const float inv = 1.f / (3.f * fmaxf(dsum, 1e-9f));
    float a0 = f0 * inv, a1 = f1 * inv;
    short h0 = f2bf(a0), h1 = f2bf(a1);
    bf16x2 hi = {h0, h1};
    bf16x2 lo = {f2bf(a0 - bf2f(h0)), f2bf(a1 - bf2f(h1))};
    size_t base = (size_t)node * (2 * NREL * FIN) + r * FIN + lane * 2;
    *(bf16x2*)&A1[base] = hi;
    *(bf16x2*)&A1[base + NREL * FIN] = lo;
  }
}

// ------- L1 GEMM: hb = relu(A1[M,768] @ W1d[256,768]^T + beff1) bf16 ------
__global__ __launch_bounds__(256) void gemm_hl(
    const short* __restrict__ A, const short* __restrict__ Bt,
    const float* __restrict__ beff, short* __restrict__ hb, int M)
{
  constexpr int K = 2 * NREL * FIN;    // 768
  const int lane = threadIdx.x & 63;
  const int wave = threadIdx.x >> 6;
  const int m0 = blockIdx.x * 64;
  const int n0 = wave * 64;
  const int c    = lane & 15;
  const int rgrp = lane >> 4;
  const int koff = rgrp * 8;

  f32x4 acc[4][4] = {};
  for (int k0 = 0; k0 < K; k0 += 32) {
    bf16x8 a[4], b[4];
#pragma unroll
    for (int i = 0; i < 4; ++i) {
      int row = m0 + i * 16 + c;
      row = row < M ? row : M - 1;
      a[i] = *(const bf16x8*)&A[(size_t)row * K + k0 + koff];
    }
#pragma unroll
    for (int j = 0; j < 4; ++j)
      b[j] = *(const bf16x8*)&Bt[(size_t)(n0 + j * 16 + c) * K + k0 + koff];
#pragma unroll
    for (int i = 0; i < 4; ++i)
#pragma unroll
      for (int j = 0; j < 4; ++j)
        acc[i][j] = __builtin_amdgcn_mfma_f32_16x16x32_bf16(a[i], b[j], acc[i][j], 0, 0, 0);
  }
#pragma unroll
  for (int i = 0; i < 4; ++i)
#pragma unroll
    for (int v = 0; v < 4; ++v) {
      int row = m0 + i * 16 + rgrp * 4 + v;
      if (row < M) {
#pragma unroll
        for (int j = 0; j < 4; ++j) {
          int col = n0 + j * 16 + c;
          hb[(size_t)row * HD + col] = f2bf(fmaxf(acc[i][j][v] + beff[col], 0.f));
        }
      }
    }
}

// ---- L2 GEMM: featb2[r] = hb @ W2t[r]^T (bf16) + el/er epilogue ----------
template<int N_, int WM, int WN>
__global__ __launch_bounds__(256) void gemm_fused(
    const short* __restrict__ A, const short* __restrict__ Wt,
    const float* __restrict__ al, const float* __restrict__ ar,
    short* __restrict__ featb, float* __restrict__ el, float* __restrict__ er,
    int M, int K)
{
  const int r = blockIdx.y;
  const short* Bt  = Wt + (size_t)r * N_ * K;
  const float* alr = al + r * N_;
  const float* arr = ar + r * N_;
  short* fb  = featb + (size_t)r * M * N_;
  float* elr = el + r * NN;
  float* err = er + r * NN;

  const int lane = threadIdx.x & 63;
  const int wave = threadIdx.x >> 6;
  const int wm = wave / WN;
  const int wn = wave % WN;
  const int m0 = blockIdx.x * (WM * 64) + wm * 64;
  const int n0 = wn * 64;
  const int c    = lane & 15;
  const int rgrp = lane >> 4;
  const int koff = rgrp * 8;

  f32x4 acc[4][4] = {};
  for (int k0 = 0; k0 < K; k0 += 32) {
    bf16x8 a[4], b[4];
#pragma unroll
    for (int i = 0; i < 4; ++i) {
      int row = m0 + i * 16 + c;
      row = row < M ? row : M - 1;
      a[i] = *(const bf16x8*)&A[(size_t)row * K + k0 + koff];
    }
#pragma unroll
    for (int j = 0; j < 4; ++j)
      b[j] = *(const bf16x8*)&Bt[(size_t)(n0 + j * 16 + c) * K + k0 + koff];
#pragma unroll
    for (int i = 0; i < 4; ++i)
#pragma unroll
      for (int j = 0; j < 4; ++j)
        acc[i][j] = __builtin_amdgcn_mfma_f32_16x16x32_bf16(a[i], b[j], acc[i][j], 0, 0, 0);
  }

  __shared__ float2 part[WN][WM * 64];
  float pe[4][4], pr[4][4];
#pragma unroll
  for (int i = 0; i < 4; ++i)
#pragma unroll
    for (int v = 0; v < 4; ++v) {
      float se = 0.f, sr = 0.f;
#pragma unroll
      for (int j = 0; j < 4; ++j) {
        float av = acc[i][j][v];
        int col = n0 + j * 16 + c;
        se = fmaf(av, alr[col], se);
        sr = fmaf(av, arr[col], sr);
      }
      pe[i][v] = se; pr[i][v] = sr;
    }
#pragma unroll
  for (int i = 0; i < 4; ++i)
#pragma unroll
    for (int v = 0; v < 4; ++v) {
      int row = m0 + i * 16 + rgrp * 4 + v;
      if (row < M) {
#pragma unroll
        for (int j = 0; j < 4; ++j)
          fb[(size_t)row * N_ + n0 + j * 16 + c] = f2bf(acc[i][j][v]);
      }
#pragma unroll
      for (int off = 1; off < 16; off <<= 1) {
        pe[i][v] += __shfl_xor(pe[i][v], off);
        pr[i][v] += __shfl_xor(pr[i][v], off);
      }
    }
  if (c == 0) {
#pragma unroll
    for (int i = 0; i < 4; ++i)
#pragma unroll
      for (int v = 0; v < 4; ++v)
        part[wn][wm * 64 + i * 16 + rgrp * 4 + v] = make_float2(pe[i][v], pr[i][v]);
  }
  __syncthreads();
  const int t = threadIdx.x;
  if (t < WM * 64) {
    float se = 0.f, sr = 0.f;
#pragma unroll
    for (int w = 0; w < WN; ++w) { se += part[w][t].x; sr += part[w][t].y; }
    int row = blockIdx.x * (WM * 64) + t;
    if (row < M) { elr[row] = se; err[row] = sr; }
  }
}

// ---- L2: projected-space fused 3-relation gather + relu + predictor dots -
__global__ __launch_bounds__(256) void gat_agg_dots(
    const int* __restrict__ row_ptr, const int* __restrict__ csr_src,
    const float* __restrict__ el, const float* __restrict__ er,
    const short* __restrict__ featb,    // [NREL][NN][FIN] bf16
    const float* __restrict__ beff,     // [FIN]
    const float* __restrict__ Wlin,     // [2*FIN]
    float* __restrict__ dotl, float* __restrict__ dotr)
{
  const int lane = threadIdx.x & 63;
  const int node = blockIdx.x * 4 + (threadIdx.x >> 6);
  if (node >= NN) return;

  float t0 = 0.f, t1 = 0.f;
#pragma unroll
  for (int r = 0; r < NREL; ++r) {
    const int beg = row_ptr[r * NN + node];
    const int end = row_ptr[r * NN + node + 1];
    const float eri = er[r * NN + node];
    const float* elr = el + r * NN;
    const short* fb  = featb + (size_t)r * NN * FIN;

    int   sidx0 = 0;
    float s0 = -3.4e38f;
    if (beg + lane < end) {
      sidx0 = csr_src[beg + lane];
      float tv = elr[sidx0] + eri;
      s0 = tv > 0.f ? tv : SLOPE * tv;
    }
    float m = s0;
    for (int e = beg + 64 + lane; e < end; e += 64) {
      int si = csr_src[e];
      float tv = elr[si] + eri;
      tv = tv > 0.f ? tv : SLOPE * tv;
      m = fmaxf(m, tv);
    }
#pragma unroll
    for (int off = 32; off > 0; off >>= 1) m = fmaxf(m, __shfl_xor(m, off));

    float dsum = 0.f;
    float f0 = 0.f, f1 = 0.f;
    for (int chunk = beg; chunk < end; chunk += 64) {
      int e = chunk + lane;
      int sidx; float s;
      if (chunk == beg) { sidx = sidx0; s = s0; }
      else {
        sidx = 0; s = -3.4e38f;
        if (e < end) {
          sidx = csr_src[e];
          float tv = elr[sidx] + eri;
          s = tv > 0.f ? tv : SLOPE * tv;
        }
      }
      float a = (e < end) ? __expf(s - m) : 0.f;
      dsum += a;
      const int cnt = (end - chunk < 64) ? end - chunk : 64;
      for (int j = 0; j < cnt; ++j) {
        float aj = __shfl(a, j);
        int   sj = __shfl(sidx, j);
        bf16x2 v = *(const bf16x2*)&fb[(size_t)sj * FIN + lane * 2];
        f0 = fmaf(bf2f(v[0]), aj, f0);
        f1 = fmaf(bf2f(v[1]), aj, f1);
      }
    }
#pragma unroll
    for (int off = 32; off > 0; off >>= 1) dsum += __shfl_xor(dsum, off);
    const float inv = 1.f / (3.f * fmaxf(dsum, 1e-9f));
    t0 = fmaf(f0, inv, t0);
    t1 = fmaf(f1, inv, t1);
  }

  const int c = lane * 2;
  float g0 = fmaxf(t0 + beff[c], 0.f);
  float g1 = fmaxf(t1 + beff[c + 1], 0.f);
  float dl = g0 * Wlin[c] + g1 * Wlin[c + 1];
  float dr = g0 * Wlin[FIN + c] + g1 * Wlin[FIN + c + 1];
#pragma unroll
  for (int off = 32; off > 0; off >>= 1) {
    dl += __shfl_xor(dl, off);
    dr += __shfl_xor(dr, off);
  }
  if (lane == 0) { dotl[node] = dl; dotr[node] = dr; }
}

// ------------- pair logits -------------------------------------------------
__global__ __launch_bounds__(256) void pair_out(
    const int* __restrict__ edges, const int* __restrict__ n_pairs,
    const float* __restrict__ dotl, const float* __restrict__ dotr,
    const float* __restrict__ blin, float* __restrict__ out)
{
  const int TOT = NREL * NE + NP;
  int p = blockIdx.x * blockDim.x + threadIdx.x;
  if (p >= TOT) return;
  int s, d;
  if (p < NREL * NE) {
    int r = p / NE;
    int e = p - r * NE;
    const int* base = edges + (size_t)r * 2 * NE;
    s = base[e];
    d = base[NE + e];
  } else {
    int q = p - NREL * NE;
    s = n_pairs[2 * q];
    d = n_pairs[2 * q + 1];
  }
  float logit = dotl[s] + dotr[d] + blin[0];
  out[p] = 1.f / (1.f + expf(-logit));
}

extern "C" void kernel_launch(void* const* d_in, const int* in_sizes, int n_in,
                              void* d_out, int out_size, void* d_ws, size_t ws_size,
                              hipStream_t stream) {
  const float* x      = (const float*)d_in[0];
  const int*   edges  = (const int*)d_in[1];
  const int*   npairs = (const int*)d_in[2];
  const float* W1     = (const float*)d_in[3];
  const float* al1    = (const float*)d_in[4];
  const float* ar1    = (const float*)d_in[5];
  const float* b1     = (const float*)d_in[6];
  const float* W2     = (const float*)d_in[7];
  const float* al2    = (const float*)d_in[8];
  const float* ar2    = (const float*)d_in[9];
  const float* b2     = (const float*)d_in[10];
  const float* Wlin   = (const float*)d_in[11];
  const float* blin   = (const float*)d_in[12];
  float* out = (float*)d_out;

  char* w = (char*)d_ws;
  size_t off = 0;
  auto alloc = [&](size_t bytes) {
    char* p = w + off;
    off = (off + bytes + 255) & ~(size_t)255;
    return p;
  };
  short* xb      = (short*)alloc((size_t)NN * FIN * 2);             // 12.8 MB
  short* hb      = (short*)alloc((size_t)NN * HD * 2);              // 25.6 MB
  short* A1      = (short*)alloc((size_t)NN * 2 * NREL * FIN * 2);  // 76.8 MB
  short* featb2  = A1;   // aliased: A1 dead after gemm_hl, featb2 38.4 MB
  short* W1d     = (short*)alloc((size_t)HD * 2 * NREL * FIN * 2);  // 393 KB
  short* W2t     = (short*)alloc((size_t)NREL * FIN * HD * 2);      // 197 KB
  float* wvec1   = (float*)alloc(6 * FIN * 4);
  float* beff1   = (float*)alloc(HD * 4);
  float* beff2   = (float*)alloc(FIN * 4);
  float* el      = (float*)alloc((size_t)NREL * NN * 4);
  float* er      = (float*)alloc((size_t)NREL * NN * 4);
  float* dotl    = (float*)alloc((size_t)NN * 4);
  float* dotr    = (float*)alloc((size_t)NN * 4);
  int*   deg     = (int*)  alloc((size_t)NREL * NN * 4);
  int*   cursor  = (int*)  alloc((size_t)NREL * NN * 4);
  int*   row_ptr = (int*)  alloc((size_t)(NREL * NN + 16) * 4);
  int*   psum    = (int*)  alloc(1024);
  int*   pexcl   = (int*)  alloc(1024);
  int*   csr_src = (int*)  alloc((size_t)NREL * NE * 4);

  const int B = 256;

  // ---------------- prep (1 kernel) ---------------------------------------
  prep_all<<<7596, B, 0, stream>>>(x, W1, W2, al1, ar1, b1, b2,
                                   xb, W1d, W2t, wvec1, beff1, beff2);

  // ---------------- CSR build ---------------------------------------------
  hipMemsetAsync(deg, 0, (size_t)NREL * NN * 4, stream);
  count_deg<<<(NREL * NE + B - 1) / B, B, 0, stream>>>(edges, deg);
  deg_partial<<<150, B, 0, stream>>>(deg, psum);
  scan_psum<<<1, B, 0, stream>>>(psum, pexcl);
  deg_rowptr<<<150, B, 0, stream>>>(deg, pexcl, row_ptr, cursor);
  fill_csr<<<(NREL * NE + B - 1) / B, B, 0, stream>>>(edges, cursor, csr_src);

  const int AGG_G = (NN + 3) / 4;

  // ---------------- layer 1: scores, input-space gather, GEMM -> hb -------
  rowdot6<<<AGG_G, B, 0, stream>>>(xb, wvec1, el, er);
  gat_gather_hl<<<AGG_G, B, 0, stream>>>(row_ptr, csr_src, el, er, xb, A1);
  gemm_hl<<<(NN + 63) / 64, B, 0, stream>>>(A1, W1d, beff1, hb, NN);

  // ---------------- layer 2: project, gather+dots -------------------------
  {
    dim3 g((NN + 127) / 128, NREL);
    gemm_fused<FIN, 2, 2><<<g, B, 0, stream>>>(hb, W2t, al2, ar2, featb2, el, er, NN, HD);
  }
  gat_agg_dots<<<AGG_G, B, 0, stream>>>(row_ptr, csr_src, el, er, featb2,
                                        beff2, Wlin, dotl, dotr);

  // ---------------- pair predictor ----------------------------------------
  const int TOT = NREL * NE + NP;
  pair_out<<<(TOT + B - 1) / B, B, 0, stream>>>(edges, npairs, dotl, dotr, blin, out);
}

// Round 9
// 379.493 us; speedup vs baseline: 1.0876x; 1.0847x over previous
//
#include <hip/hip_runtime.h>
#include <cstddef>

#define NN 50000
#define NREL 3
#define NE 250000
#define NP 100000
#define FIN 128
#define HD 256
#define SLOPE 0.2f

typedef short bf16x8 __attribute__((ext_vector_type(8)));
typedef short bf16x2 __attribute__((ext_vector_type(2)));
typedef float f32x4 __attribute__((ext_vector_type(4)));

__device__ __forceinline__ short f2bf(float f) {
  unsigned u = __float_as_uint(f);
  unsigned r = (u + 0x7FFFu + ((u >> 16) & 1u)) >> 16;   // RNE
  return (short)r;
}
__device__ __forceinline__ float bf2f(short s) {
  return __uint_as_float(((unsigned)(unsigned short)s) << 16);
}

// ---------------- fused prep: xb, W1d (dup hi/lo), W2t, wvec1, beff -------
__global__ __launch_bounds__(256) void prep_all(
    const float* __restrict__ x,  const float* __restrict__ W1,
    const float* __restrict__ W2, const float* __restrict__ al1,
    const float* __restrict__ ar1, const float* __restrict__ b1,
    const float* __restrict__ b2,
    short* __restrict__ xb, short* __restrict__ W1d, short* __restrict__ W2t,
    float* __restrict__ wvec1, float* __restrict__ beff1, float* __restrict__ beff2)
{
  const int blk = blockIdx.x;
  const int t = threadIdx.x;
  if (blk < 6250) {                                   // x -> bf16
    int i = (blk * 256 + t) * 4;
    float4 v = *(const float4*)&x[i];
    short4 o = {f2bf(v.x), f2bf(v.y), f2bf(v.z), f2bf(v.w)};
    *(short4*)&xb[i] = o;
  } else if (blk < 7018) {                            // W1d[n][k], k<768
    int o = (blk - 6250) * 256 + t;
    if (o < HD * 2 * NREL * FIN) {
      int n = o / (2 * NREL * FIN);
      int k = o - n * (2 * NREL * FIN);
      int k2 = (k < NREL * FIN) ? k : k - NREL * FIN;
      int r = k2 / FIN, kk = k2 - r * FIN;
      W1d[o] = f2bf(W1[((size_t)r * FIN + kk) * HD + n]);
    }
  } else if (blk < 7402) {                            // W2t[r][n][k]
    int o = (blk - 7018) * 256 + t;
    if (o < NREL * FIN * HD) {
      int r = o / (FIN * HD);
      int rem = o - r * (FIN * HD);
      int n = rem / HD, k = rem - n * HD;
      W2t[o] = f2bf(W2[((size_t)r * HD + k) * FIN + n]);
    }
  } else if (blk < 7594) {                            // wvec1[j][k] = W1_r[k,:]·v
    int wid = (blk - 7402) * 4 + (t >> 6);
    int lane = t & 63;
    if (wid < 6 * FIN) {
      int j = wid / FIN, k = wid - j * FIN;
      int side = j / 3, r = j - side * 3;
      const float* v  = (side ? ar1 : al1) + r * HD;
      const float* Wr = W1 + ((size_t)r * FIN + k) * HD;
      float s = 0.f;
      for (int n = lane; n < HD; n += 64) s += Wr[n] * v[n];
#pragma unroll
      for (int off = 32; off > 0; off >>= 1) s += __shfl_down(s, off);
      if (lane == 0) wvec1[wid] = s;
    }
  } else {                                            // beff
    int t2 = (blk - 7594) * 256 + t;
    if (t2 < HD) beff1[t2] = (b1[t2] + b1[HD + t2] + b1[2 * HD + t2]) * (1.f / 3.f);
    else if (t2 < HD + FIN) {
      int k = t2 - HD;
      beff2[k] = (b2[k] + b2[FIN + k] + b2[2 * FIN + k]) * (1.f / 3.f);
    }
  }
}

// ------- el/er for layer 1: d[j] = xb[i,:]·wvec1[j,:], j<6 ----------------
__global__ __launch_bounds__(256) void rowdot6(
    const short* __restrict__ feat, const float* __restrict__ wvec,
    float* __restrict__ el, float* __restrict__ er)
{
  const int lane = threadIdx.x & 63;
  const int node = blockIdx.x * 4 + (threadIdx.x >> 6);
  if (node >= NN) return;
  bf16x2 f16 = *(const bf16x2*)&feat[(size_t)node * FIN + lane * 2];
  float f0 = bf2f(f16[0]), f1 = bf2f(f16[1]);
  float d[6];
#pragma unroll
  for (int j = 0; j < 6; ++j)
    d[j] = f0 * wvec[j * FIN + lane * 2] + f1 * wvec[j * FIN + lane * 2 + 1];
#pragma unroll
  for (int off = 32; off > 0; off >>= 1)
#pragma unroll
    for (int j = 0; j < 6; ++j) d[j] += __shfl_xor(d[j], off);
  if (lane == 0) {
    el[0 * NN + node] = d[0]; el[1 * NN + node] = d[1]; el[2 * NN + node] = d[2];
    er[0 * NN + node] = d[3]; er[1 * NN + node] = d[4]; er[2 * NN + node] = d[5];
  }
}

// ------------- CSR build: degree count ------------------------------------
__global__ __launch_bounds__(256) void count_deg(
    const int* __restrict__ edges, int* __restrict__ deg)
{
  int tid = blockIdx.x * blockDim.x + threadIdx.x;
  if (tid >= NREL * NE) return;
  int r = tid / NE;
  int e = tid - r * NE;
  int d = edges[(size_t)r * 2 * NE + NE + e];
  atomicAdd(&deg[r * NN + d], 1);
}

// ------------- CSR scan phase 1 -------------------------------------------
__global__ __launch_bounds__(256) void deg_partial(
    const int* __restrict__ deg, int* __restrict__ psum)
{
  const int b = blockIdx.x;
  const int t = threadIdx.x;
  int4 v = {0, 0, 0, 0};
  if (t < 250) v = *(const int4*)&deg[b * 1000 + t * 4];
  int s = v.x + v.y + v.z + v.w;
#pragma unroll
  for (int off = 32; off > 0; off >>= 1) s += __shfl_down(s, off);
  __shared__ int ws[4];
  if ((t & 63) == 0) ws[t >> 6] = s;
  __syncthreads();
  if (t == 0) psum[b] = ws[0] + ws[1] + ws[2] + ws[3];
}

// ------------- CSR scan phase 2 -------------------------------------------
__global__ __launch_bounds__(256) void scan_psum(
    const int* __restrict__ psum, int* __restrict__ pexcl)
{
  __shared__ int lds[256];
  const int t = threadIdx.x;
  int v = (t < 150) ? psum[t] : 0;
  lds[t] = v;
  __syncthreads();
  for (int off = 1; off < 256; off <<= 1) {
    int add = (t >= off) ? lds[t - off] : 0;
    __syncthreads();
    lds[t] += add;
    __syncthreads();
  }
  if (t < 150) pexcl[t] = lds[t] - v;
}

// ------------- CSR scan phase 3: row_ptr + cursor init --------------------
__global__ __launch_bounds__(256) void deg_rowptr(
    const int* __restrict__ deg, const int* __restrict__ pexcl,
    int* __restrict__ row_ptr, int* __restrict__ cursor)
{
  const int b = blockIdx.x;
  const int t = threadIdx.x;
  int4 v = {0, 0, 0, 0};
  if (t < 250) v = *(const int4*)&deg[b * 1000 + t * 4];
  int s = v.x + v.y + v.z + v.w;
  __shared__ int lds[256];
  lds[t] = s;
  __syncthreads();
  for (int off = 1; off < 256; off <<= 1) {
    int add = (t >= off) ? lds[t - off] : 0;
    __syncthreads();
    lds[t] += add;
    __syncthreads();
  }
  int run = lds[t] - s + pexcl[b];
  if (t < 250) {
    int i = b * 1000 + t * 4;
    row_ptr[i] = run;     cursor[i] = run;     run += v.x;
    row_ptr[i + 1] = run; cursor[i + 1] = run; run += v.y;
    row_ptr[i + 2] = run; cursor[i + 2] = run; run += v.z;
    row_ptr[i + 3] = run; cursor[i + 3] = run;
  }
  if (b == 0 && t == 0) row_ptr[NREL * NN] = NREL * NE;
}

// ------------- CSR build: fill src lists ----------------------------------
__global__ __launch_bounds__(256) void fill_csr(
    const int* __restrict__ edges, int* __restrict__ cursor,
    int* __restrict__ csr_src)
{
  int tid = blockIdx.x * blockDim.x + threadIdx.x;
  if (tid >= NREL * NE) return;
  int r = tid / NE;
  int e = tid - r * NE;
  const int* base = edges + (size_t)r * 2 * NE;
  int s = base[e];
  int d = base[NE + e];
  int pos = atomicAdd(&cursor[r * NN + d], 1);
  csr_src[pos] = s;
}

// ------- L1: input-space fused 3-relation gather, hi/lo bf16 out ----------
__global__ __launch_bounds__(256) void gat_gather_hl(
    const int* __restrict__ row_ptr, const int* __restrict__ csr_src,
    const float* __restrict__ el, const float* __restrict__ er,
    const short* __restrict__ xb,       // [NN][FIN] bf16
    short* __restrict__ A1)             // [NN][768] bf16
{
  const int lane = threadIdx.x & 63;
  const int node = blockIdx.x * 4 + (threadIdx.x >> 6);
  if (node >= NN) return;

#pragma unroll
  for (int r = 0; r < NREL; ++r) {
    const int beg = row_ptr[r * NN + node];
    const int end = row_ptr[r * NN + node + 1];
    const float eri = er[r * NN + node];
    const float* elr = el + r * NN;

    int   sidx0 = 0;
    float s0 = -3.4e38f;
    if (beg + lane < end) {
      sidx0 = csr_src[beg + lane];
      float tv = elr[sidx0] + eri;
      s0 = tv > 0.f ? tv : SLOPE * tv;
    }
    float m = s0;
    for (int e = beg + 64 + lane; e < end; e += 64) {
      int si = csr_src[e];
      float tv = elr[si] + eri;
      tv = tv > 0.f ? tv : SLOPE * tv;
      m = fmaxf(m, tv);
    }
#pragma unroll
    for (int off = 32; off > 0; off >>= 1) m = fmaxf(m, __shfl_xor(m, off));

    float dsum = 0.f;
    float f0 = 0.f, f1 = 0.f;
    for (int chunk = beg; chunk < end; chunk += 64) {
      int e = chunk + lane;
      int sidx; float s;
      if (chunk == beg) { sidx = sidx0; s = s0; }
      else {
        sidx = 0; s = -3.4e38f;
        if (e < end) {
          sidx = csr_src[e];
          float tv = elr[sidx] + eri;
          s = tv > 0.f ? tv : SLOPE * tv;
        }
      }
      float a = (e < end) ? __expf(s - m) : 0.f;
      dsum += a;
      const int cnt = (end - chunk < 64) ? end - chunk : 64;
      for (int j = 0; j < cnt; ++j) {
        float aj = __shfl(a, j);
        int   sj = __shfl(sidx, j);
        bf16x2 v = *(const bf16x2*)&xb[(size_t)sj * FIN + lane * 2];
        f0 = fmaf(bf2f(v[0]), aj, f0);
        f1 = fmaf(bf2f(v[1]), aj, f1);
      }
    }
#pragma unroll
    for (int off = 32; off > 0; off >>= 1) dsum += __shfl_xor(dsum, off);
    const float inv = 1.f / (3.f * fmaxf(dsum, 1e-9f));
    float a0 = f0 * inv, a1 = f1 * inv;
    short h0 = f2bf(a0), h1 = f2bf(a1);
    bf16x2 hi = {h0, h1};
    bf16x2 lo = {f2bf(a0 - bf2f(h0)), f2bf(a1 - bf2f(h1))};
    size_t base = (size_t)node * (2 * NREL * FIN) + r * FIN + lane * 2;
    *(bf16x2*)&A1[base] = hi;
    *(bf16x2*)&A1[base + NREL * FIN] = lo;
  }
}

// ------- L1 GEMM (LDS-staged A): hb = relu(A1@W1d^T + beff1) bf16 ---------
// BM=64 rows/block, BN=256 (wave = n-tile). A-tile in padded LDS, B from L2.
__global__ __launch_bounds__(256) void gemm_hl(
    const short* __restrict__ A, const short* __restrict__ Bt,
    const float* __restrict__ beff, short* __restrict__ hb, int M)
{
  constexpr int K = 2 * NREL * FIN;    // 768
  constexpr int BK = 128;
  constexpr int LW = 136;              // padded row (shorts): 272 B, 2-way free
  __shared__ __align__(16) short As[64 * LW];   // 17.4 KB
  const int tid  = threadIdx.x;
  const int lane = tid & 63;
  const int wave = tid >> 6;
  const int m0 = blockIdx.x * 64;
  const int n0 = wave * 64;
  const int c    = lane & 15;
  const int rgrp = lane >> 4;

  f32x4 acc[4][4] = {};
  for (int k0 = 0; k0 < K; k0 += BK) {
    __syncthreads();
    // stage A: 64 rows x 128 shorts = 1024 chunks of 8 shorts
#pragma unroll
    for (int i = 0; i < 4; ++i) {
      int idx = i * 256 + tid;
      int row = idx >> 4;
      int ch  = idx & 15;
      int gr = m0 + row; gr = gr < M ? gr : M - 1;
      bf16x8 v = *(const bf16x8*)&A[(size_t)gr * K + k0 + ch * 8];
      *(bf16x8*)&As[row * LW + ch * 8] = v;
    }
    __syncthreads();
#pragma unroll
    for (int ks = 0; ks < 4; ++ks) {
      const int koff = ks * 32 + rgrp * 8;
      bf16x8 a[4], b[4];
#pragma unroll
      for (int i = 0; i < 4; ++i)
        a[i] = *(const bf16x8*)&As[(i * 16 + c) * LW + koff];
#pragma unroll
      for (int j = 0; j < 4; ++j)
        b[j] = *(const bf16x8*)&Bt[(size_t)(n0 + j * 16 + c) * K + k0 + koff];
#pragma unroll
      for (int i = 0; i < 4; ++i)
#pragma unroll
        for (int j = 0; j < 4; ++j)
          acc[i][j] = __builtin_amdgcn_mfma_f32_16x16x32_bf16(a[i], b[j], acc[i][j], 0, 0, 0);
    }
  }
#pragma unroll
  for (int i = 0; i < 4; ++i)
#pragma unroll
    for (int v = 0; v < 4; ++v) {
      int row = m0 + i * 16 + rgrp * 4 + v;
      if (row < M) {
#pragma unroll
        for (int j = 0; j < 4; ++j) {
          int col = n0 + j * 16 + c;
          hb[(size_t)row * HD + col] = f2bf(fmaxf(acc[i][j][v] + beff[col], 0.f));
        }
      }
    }
}

// ---- L2 GEMM (LDS-staged A): featb2[r] = hb @ W2t[r]^T + el/er epilogue --
// BM=128, BN=128, waves 2x2. K=256, BK=128.
__global__ __launch_bounds__(256) void gemm_fused2(
    const short* __restrict__ A, const short* __restrict__ Wt,
    const float* __restrict__ al, const float* __restrict__ ar,
    short* __restrict__ featb, float* __restrict__ el, float* __restrict__ er,
    int M)
{
  constexpr int K = HD;                // 256
  constexpr int BK = 128;
  constexpr int LW = 136;
  constexpr int N_ = FIN;              // 128
  __shared__ __align__(16) short As[128 * LW];  // 34.8 KB
  const int r = blockIdx.y;
  const short* Bt  = Wt + (size_t)r * N_ * K;
  const float* alr = al + r * N_;
  const float* arr = ar + r * N_;
  short* fb  = featb + (size_t)r * M * N_;
  float* elr = el + r * NN;
  float* err = er + r * NN;

  const int tid  = threadIdx.x;
  const int lane = tid & 63;
  const int wave = tid >> 6;
  const int wm = wave >> 1;
  const int wn = wave & 1;
  const int m0 = blockIdx.x * 128 + wm * 64;
  const int n0 = wn * 64;
  const int c    = lane & 15;
  const int rgrp = lane >> 4;

  f32x4 acc[4][4] = {};
  for (int k0 = 0; k0 < K; k0 += BK) {
    __syncthreads();
    // stage A: 128 rows x 128 shorts = 2048 chunks
#pragma unroll
    for (int i = 0; i < 8; ++i) {
      int idx = i * 256 + tid;
      int row = idx >> 4;
      int ch  = idx & 15;
      int gr = blockIdx.x * 128 + row; gr = gr < M ? gr : M - 1;
      bf16x8 v = *(const bf16x8*)&A[(size_t)gr * K + k0 + ch * 8];
      *(bf16x8*)&As[row * LW + ch * 8] = v;
    }
    __syncthreads();
#pragma unroll
    for (int ks = 0; ks < 4; ++ks) {
      const int koff = ks * 32 + rgrp * 8;
      bf16x8 a[4], b[4];
#pragma unroll
      for (int i = 0; i < 4; ++i)
        a[i] = *(const bf16x8*)&As[(wm * 64 + i * 16 + c) * LW + koff];
#pragma unroll
      for (int j = 0; j < 4; ++j)
        b[j] = *(const bf16x8*)&Bt[(size_t)(n0 + j * 16 + c) * K + k0 + koff];
#pragma unroll
      for (int i = 0; i < 4; ++i)
#pragma unroll
        for (int j = 0; j < 4; ++j)
          acc[i][j] = __builtin_amdgcn_mfma_f32_16x16x32_bf16(a[i], b[j], acc[i][j], 0, 0, 0);
    }
  }

  __shared__ float2 part[2][128];
  float pe[4][4], pr[4][4];
#pragma unroll
  for (int i = 0; i < 4; ++i)
#pragma unroll
    for (int v = 0; v < 4; ++v) {
      float se = 0.f, sr = 0.f;
#pragma unroll
      for (int j = 0; j < 4; ++j) {
        float av = acc[i][j][v];
        int col = n0 + j * 16 + c;
        se = fmaf(av, alr[col], se);
        sr = fmaf(av, arr[col], sr);
      }
      pe[i][v] = se; pr[i][v] = sr;
    }
#pragma unroll
  for (int i = 0; i < 4; ++i)
#pragma unroll
    for (int v = 0; v < 4; ++v) {
      int row = m0 + i * 16 + rgrp * 4 + v;
      if (row < M) {
#pragma unroll
        for (int j = 0; j < 4; ++j)
          fb[(size_t)row * N_ + n0 + j * 16 + c] = f2bf(acc[i][j][v]);
      }
#pragma unroll
      for (int off = 1; off < 16; off <<= 1) {
        pe[i][v] += __shfl_xor(pe[i][v], off);
        pr[i][v] += __shfl_xor(pr[i][v], off);
      }
    }
  __syncthreads();   // As reuse done; reuse LDS timing safe for part[]
  if (c == 0) {
#pragma unroll
    for (int i = 0; i < 4; ++i)
#pragma unroll
      for (int v = 0; v < 4; ++v)
        part[wn][wm * 64 + i * 16 + rgrp * 4 + v] = make_float2(pe[i][v], pr[i][v]);
  }
  __syncthreads();
  if (tid < 128) {
    float se = part[0][tid].x + part[1][tid].x;
    float sr = part[0][tid].y + part[1][tid].y;
    int row = blockIdx.x * 128 + tid;
    if (row < M) { elr[row] = se; err[row] = sr; }
  }
}

// ---- L2: projected-space fused 3-relation gather + relu + predictor dots -
__global__ __launch_bounds__(256) void gat_agg_dots(
    const int* __restrict__ row_ptr, const int* __restrict__ csr_src,
    const float* __restrict__ el, const float* __restrict__ er,
    const short* __restrict__ featb,    // [NREL][NN][FIN] bf16
    const float* __restrict__ beff,     // [FIN]
    const float* __restrict__ Wlin,     // [2*FIN]
    float* __restrict__ dotl, float* __restrict__ dotr)
{
  const int lane = threadIdx.x & 63;
  const int node = blockIdx.x * 4 + (threadIdx.x >> 6);
  if (node >= NN) return;

  float t0 = 0.f, t1 = 0.f;
#pragma unroll
  for (int r = 0; r < NREL; ++r) {
    const int beg = row_ptr[r * NN + node];
    const int end = row_ptr[r * NN + node + 1];
    const float eri = er[r * NN + node];
    const float* elr = el + r * NN;
    const short* fb  = featb + (size_t)r * NN * FIN;

    int   sidx0 = 0;
    float s0 = -3.4e38f;
    if (beg + lane < end) {
      sidx0 = csr_src[beg + lane];
      float tv = elr[sidx0] + eri;
      s0 = tv > 0.f ? tv : SLOPE * tv;
    }
    float m = s0;
    for (int e = beg + 64 + lane; e < end; e += 64) {
      int si = csr_src[e];
      float tv = elr[si] + eri;
      tv = tv > 0.f ? tv : SLOPE * tv;
      m = fmaxf(m, tv);
    }
#pragma unroll
    for (int off = 32; off > 0; off >>= 1) m = fmaxf(m, __shfl_xor(m, off));

    float dsum = 0.f;
    float f0 = 0.f, f1 = 0.f;
    for (int chunk = beg; chunk < end; chunk += 64) {
      int e = chunk + lane;
      int sidx; float s;
      if (chunk == beg) { sidx = sidx0; s = s0; }
      else {
        sidx = 0; s = -3.4e38f;
        if (e < end) {
          sidx = csr_src[e];
          float tv = elr[sidx] + eri;
          s = tv > 0.f ? tv : SLOPE * tv;
        }
      }
      float a = (e < end) ? __expf(s - m) : 0.f;
      dsum += a;
      const int cnt = (end - chunk < 64) ? end - chunk : 64;
      for (int j = 0; j < cnt; ++j) {
        float aj = __shfl(a, j);
        int   sj = __shfl(sidx, j);
        bf16x2 v = *(const bf16x2*)&fb[(size_t)sj * FIN + lane * 2];
        f0 = fmaf(bf2f(v[0]), aj, f0);
        f1 = fmaf(bf2f(v[1]), aj, f1);
      }
    }
#pragma unroll
    for (int off = 32; off > 0; off >>= 1) dsum += __shfl_xor(dsum, off);
    const float inv = 1.f / (3.f * fmaxf(dsum, 1e-9f));
    t0 = fmaf(f0, inv, t0);
    t1 = fmaf(f1, inv, t1);
  }

  const int c = lane * 2;
  float g0 = fmaxf(t0 + beff[c], 0.f);
  float g1 = fmaxf(t1 + beff[c + 1], 0.f);
  float dl = g0 * Wlin[c] + g1 * Wlin[c + 1];
  float dr = g0 * Wlin[FIN + c] + g1 * Wlin[FIN + c + 1];
#pragma unroll
  for (int off = 32; off > 0; off >>= 1) {
    dl += __shfl_xor(dl, off);
    dr += __shfl_xor(dr, off);
  }
  if (lane == 0) { dotl[node] = dl; dotr[node] = dr; }
}

// ------------- pair logits -------------------------------------------------
__global__ __launch_bounds__(256) void pair_out(
    const int* __restrict__ edges, const int* __restrict__ n_pairs,
    const float* __restrict__ dotl, const float* __restrict__ dotr,
    const float* __restrict__ blin, float* __restrict__ out)
{
  const int TOT = NREL * NE + NP;
  int p = blockIdx.x * blockDim.x + threadIdx.x;
  if (p >= TOT) return;
  int s, d;
  if (p < NREL * NE) {
    int r = p / NE;
    int e = p - r * NE;
    const int* base = edges + (size_t)r * 2 * NE;
    s = base[e];
    d = base[NE + e];
  } else {
    int q = p - NREL * NE;
    s = n_pairs[2 * q];
    d = n_pairs[2 * q + 1];
  }
  float logit = dotl[s] + dotr[d] + blin[0];
  out[p] = 1.f / (1.f + expf(-logit));
}

extern "C" void kernel_launch(void* const* d_in, const int* in_sizes, int n_in,
                              void* d_out, int out_size, void* d_ws, size_t ws_size,
                              hipStream_t stream) {
  const float* x      = (const float*)d_in[0];
  const int*   edges  = (const int*)d_in[1];
  const int*   npairs = (const int*)d_in[2];
  const float* W1     = (const float*)d_in[3];
  const float* al1    = (const float*)d_in[4];
  const float* ar1    = (const float*)d_in[5];
  const float* b1     = (const float*)d_in[6];
  const float* W2     = (const float*)d_in[7];
  const float* al2    = (const float*)d_in[8];
  const float* ar2    = (const float*)d_in[9];
  const float* b2     = (const float*)d_in[10];
  const float* Wlin   = (const float*)d_in[11];
  const float* blin   = (const float*)d_in[12];
  float* out = (float*)d_out;

  char* w = (char*)d_ws;
  size_t off = 0;
  auto alloc = [&](size_t bytes) {
    char* p = w + off;
    off = (off + bytes + 255) & ~(size_t)255;
    return p;
  };
  short* xb      = (short*)alloc((size_t)NN * FIN * 2);             // 12.8 MB
  short* hb      = (short*)alloc((size_t)NN * HD * 2);              // 25.6 MB
  short* A1      = (short*)alloc((size_t)NN * 2 * NREL * FIN * 2);  // 76.8 MB
  short* featb2  = A1;   // aliased: A1 dead after gemm_hl
  short* W1d     = (short*)alloc((size_t)HD * 2 * NREL * FIN * 2);  // 393 KB
  short* W2t     = (short*)alloc((size_t)NREL * FIN * HD * 2);      // 197 KB
  float* wvec1   = (float*)alloc(6 * FIN * 4);
  float* beff1   = (float*)alloc(HD * 4);
  float* beff2   = (float*)alloc(FIN * 4);
  float* el      = (float*)alloc((size_t)NREL * NN * 4);
  float* er      = (float*)alloc((size_t)NREL * NN * 4);
  float* dotl    = (float*)alloc((size_t)NN * 4);
  float* dotr    = (float*)alloc((size_t)NN * 4);
  int*   deg     = (int*)  alloc((size_t)NREL * NN * 4);
  int*   cursor  = (int*)  alloc((size_t)NREL * NN * 4);
  int*   row_ptr = (int*)  alloc((size_t)(NREL * NN + 16) * 4);
  int*   psum    = (int*)  alloc(1024);
  int*   pexcl   = (int*)  alloc(1024);
  int*   csr_src = (int*)  alloc((size_t)NREL * NE * 4);

  const int B = 256;

  // ---------------- prep (1 kernel) ---------------------------------------
  prep_all<<<7596, B, 0, stream>>>(x, W1, W2, al1, ar1, b1, b2,
                                   xb, W1d, W2t, wvec1, beff1, beff2);

  // ---------------- CSR build ---------------------------------------------
  hipMemsetAsync(deg, 0, (size_t)NREL * NN * 4, stream);
  count_deg<<<(NREL * NE + B - 1) / B, B, 0, stream>>>(edges, deg);
  deg_partial<<<150, B, 0, stream>>>(deg, psum);
  scan_psum<<<1, B, 0, stream>>>(psum, pexcl);
  deg_rowptr<<<150, B, 0, stream>>>(deg, pexcl, row_ptr, cursor);
  fill_csr<<<(NREL * NE + B - 1) / B, B, 0, stream>>>(edges, cursor, csr_src);

  const int AGG_G = (NN + 3) / 4;

  // ---------------- layer 1: scores, input-space gather, GEMM -> hb -------
  rowdot6<<<AGG_G, B, 0, stream>>>(xb, wvec1, el, er);
  gat_gather_hl<<<AGG_G, B, 0, stream>>>(row_ptr, csr_src, el, er, xb, A1);
  gemm_hl<<<(NN + 63) / 64, B, 0, stream>>>(A1, W1d, beff1, hb, NN);

  // ---------------- layer 2: project, gather+dots -------------------------
  {
    dim3 g((NN + 127) / 128, NREL);
    gemm_fused2<<<g, B, 0, stream>>>(hb, W2t, al2, ar2, featb2, el, er, NN);
  }
  gat_agg_dots<<<AGG_G, B, 0, stream>>>(row_ptr, csr_src, el, er, featb2,
                                        beff2, Wlin, dotl, dotr);

  // ---------------- pair predictor ----------------------------------------
  const int TOT = NREL * NE + NP;
  pair_out<<<(TOT + B - 1) / B, B, 0, stream>>>(edges, npairs, dotl, dotr, blin, out);
}

// Round 10
// 337.859 us; speedup vs baseline: 1.2216x; 1.1232x over previous
//
#include <hip/hip_runtime.h>
#include <cstddef>

#define NN 50000
#define NREL 3
#define NE 250000
#define NP 100000
#define FIN 128
#define HD 256
#define SLOPE 0.2f

typedef short bf16x8 __attribute__((ext_vector_type(8)));
typedef short bf16x4 __attribute__((ext_vector_type(4)));
typedef short bf16x2 __attribute__((ext_vector_type(2)));
typedef float f32x4 __attribute__((ext_vector_type(4)));

__device__ __forceinline__ short f2bf(float f) {
  unsigned u = __float_as_uint(f);
  unsigned r = (u + 0x7FFFu + ((u >> 16) & 1u)) >> 16;   // RNE
  return (short)r;
}
__device__ __forceinline__ float bf2f(short s) {
  return __uint_as_float(((unsigned)(unsigned short)s) << 16);
}

// ---------------- fused prep: xb, W1d (dup hi/lo), W2t, wvec1, beff -------
__global__ __launch_bounds__(256) void prep_all(
    const float* __restrict__ x,  const float* __restrict__ W1,
    const float* __restrict__ W2, const float* __restrict__ al1,
    const float* __restrict__ ar1, const float* __restrict__ b1,
    const float* __restrict__ b2,
    short* __restrict__ xb, short* __restrict__ W1d, short* __restrict__ W2t,
    float* __restrict__ wvec1, float* __restrict__ beff1, float* __restrict__ beff2)
{
  const int blk = blockIdx.x;
  const int t = threadIdx.x;
  if (blk < 6250) {                                   // x -> bf16
    int i = (blk * 256 + t) * 4;
    float4 v = *(const float4*)&x[i];
    short4 o = {f2bf(v.x), f2bf(v.y), f2bf(v.z), f2bf(v.w)};
    *(short4*)&xb[i] = o;
  } else if (blk < 7018) {                            // W1d[n][k], k<768
    int o = (blk - 6250) * 256 + t;
    if (o < HD * 2 * NREL * FIN) {
      int n = o / (2 * NREL * FIN);
      int k = o - n * (2 * NREL * FIN);
      int k2 = (k < NREL * FIN) ? k : k - NREL * FIN;
      int r = k2 / FIN, kk = k2 - r * FIN;
      W1d[o] = f2bf(W1[((size_t)r * FIN + kk) * HD + n]);
    }
  } else if (blk < 7402) {                            // W2t[r][n][k]
    int o = (blk - 7018) * 256 + t;
    if (o < NREL * FIN * HD) {
      int r = o / (FIN * HD);
      int rem = o - r * (FIN * HD);
      int n = rem / HD, k = rem - n * HD;
      W2t[o] = f2bf(W2[((size_t)r * HD + k) * FIN + n]);
    }
  } else if (blk < 7594) {                            // wvec1[j][k] = W1_r[k,:]·v
    int wid = (blk - 7402) * 4 + (t >> 6);
    int lane = t & 63;
    if (wid < 6 * FIN) {
      int j = wid / FIN, k = wid - j * FIN;
      int side = j / 3, r = j - side * 3;
      const float* v  = (side ? ar1 : al1) + r * HD;
      const float* Wr = W1 + ((size_t)r * FIN + k) * HD;
      float s = 0.f;
      for (int n = lane; n < HD; n += 64) s += Wr[n] * v[n];
#pragma unroll
      for (int off = 32; off > 0; off >>= 1) s += __shfl_down(s, off);
      if (lane == 0) wvec1[wid] = s;
    }
  } else {                                            // beff
    int t2 = (blk - 7594) * 256 + t;
    if (t2 < HD) beff1[t2] = (b1[t2] + b1[HD + t2] + b1[2 * HD + t2]) * (1.f / 3.f);
    else if (t2 < HD + FIN) {
      int k = t2 - HD;
      beff2[k] = (b2[k] + b2[FIN + k] + b2[2 * FIN + k]) * (1.f / 3.f);
    }
  }
}

// ------- el/er for layer 1: d[j] = xb[i,:]·wvec1[j,:], j<6 ----------------
__global__ __launch_bounds__(256) void rowdot6(
    const short* __restrict__ feat, const float* __restrict__ wvec,
    float* __restrict__ el, float* __restrict__ er)
{
  const int lane = threadIdx.x & 63;
  const int node = blockIdx.x * 4 + (threadIdx.x >> 6);
  if (node >= NN) return;
  bf16x2 f16 = *(const bf16x2*)&feat[(size_t)node * FIN + lane * 2];
  float f0 = bf2f(f16[0]), f1 = bf2f(f16[1]);
  float d[6];
#pragma unroll
  for (int j = 0; j < 6; ++j)
    d[j] = f0 * wvec[j * FIN + lane * 2] + f1 * wvec[j * FIN + lane * 2 + 1];
#pragma unroll
  for (int off = 32; off > 0; off >>= 1)
#pragma unroll
    for (int j = 0; j < 6; ++j) d[j] += __shfl_xor(d[j], off);
  if (lane == 0) {
    el[0 * NN + node] = d[0]; el[1 * NN + node] = d[1]; el[2 * NN + node] = d[2];
    er[0 * NN + node] = d[3]; er[1 * NN + node] = d[4]; er[2 * NN + node] = d[5];
  }
}

// ------------- CSR build: degree count ------------------------------------
__global__ __launch_bounds__(256) void count_deg(
    const int* __restrict__ edges, int* __restrict__ deg)
{
  int tid = blockIdx.x * blockDim.x + threadIdx.x;
  if (tid >= NREL * NE) return;
  int r = tid / NE;
  int e = tid - r * NE;
  int d = edges[(size_t)r * 2 * NE + NE + e];
  atomicAdd(&deg[r * NN + d], 1);
}

// ------------- CSR scan phase 1 -------------------------------------------
__global__ __launch_bounds__(256) void deg_partial(
    const int* __restrict__ deg, int* __restrict__ psum)
{
  const int b = blockIdx.x;
  const int t = threadIdx.x;
  int4 v = {0, 0, 0, 0};
  if (t < 250) v = *(const int4*)&deg[b * 1000 + t * 4];
  int s = v.x + v.y + v.z + v.w;
#pragma unroll
  for (int off = 32; off > 0; off >>= 1) s += __shfl_down(s, off);
  __shared__ int ws[4];
  if ((t & 63) == 0) ws[t >> 6] = s;
  __syncthreads();
  if (t == 0) psum[b] = ws[0] + ws[1] + ws[2] + ws[3];
}

// ------------- CSR scan phase 2 -------------------------------------------
__global__ __launch_bounds__(256) void scan_psum(
    const int* __restrict__ psum, int* __restrict__ pexcl)
{
  __shared__ int lds[256];
  const int t = threadIdx.x;
  int v = (t < 150) ? psum[t] : 0;
  lds[t] = v;
  __syncthreads();
  for (int off = 1; off < 256; off <<= 1) {
    int add = (t >= off) ? lds[t - off] : 0;
    __syncthreads();
    lds[t] += add;
    __syncthreads();
  }
  if (t < 150) pexcl[t] = lds[t] - v;
}

// ------------- CSR scan phase 3: row_ptr + cursor init --------------------
__global__ __launch_bounds__(256) void deg_rowptr(
    const int* __restrict__ deg, const int* __restrict__ pexcl,
    int* __restrict__ row_ptr, int* __restrict__ cursor)
{
  const int b = blockIdx.x;
  const int t = threadIdx.x;
  int4 v = {0, 0, 0, 0};
  if (t < 250) v = *(const int4*)&deg[b * 1000 + t * 4];
  int s = v.x + v.y + v.z + v.w;
  __shared__ int lds[256];
  lds[t] = s;
  __syncthreads();
  for (int off = 1; off < 256; off <<= 1) {
    int add = (t >= off) ? lds[t - off] : 0;
    __syncthreads();
    lds[t] += add;
    __syncthreads();
  }
  int run = lds[t] - s + pexcl[b];
  if (t < 250) {
    int i = b * 1000 + t * 4;
    row_ptr[i] = run;     cursor[i] = run;     run += v.x;
    row_ptr[i + 1] = run; cursor[i + 1] = run; run += v.y;
    row_ptr[i + 2] = run; cursor[i + 2] = run; run += v.z;
    row_ptr[i + 3] = run; cursor[i + 3] = run;
  }
  if (b == 0 && t == 0) row_ptr[NREL * NN] = NREL * NE;
}

// ------------- CSR build: fill src lists ----------------------------------
__global__ __launch_bounds__(256) void fill_csr(
    const int* __restrict__ edges, int* __restrict__ cursor,
    int* __restrict__ csr_src)
{
  int tid = blockIdx.x * blockDim.x + threadIdx.x;
  if (tid >= NREL * NE) return;
  int r = tid / NE;
  int e = tid - r * NE;
  const int* base = edges + (size_t)r * 2 * NE;
  int s = base[e];
  int d = base[NE + e];
  int pos = atomicAdd(&cursor[r * NN + d], 1);
  csr_src[pos] = s;
}

// ------- L1: input-space fused 3-relation gather, hi/lo bf16 out ----------
// One pass (no segment-max: softmax is shift-invariant; |s|<~10 so exp safe).
// 2 edge-groups of 32 lanes x bf16x4 cols in flight.
__global__ __launch_bounds__(256) void gat_gather_hl(
    const int* __restrict__ row_ptr, const int* __restrict__ csr_src,
    const float* __restrict__ el, const float* __restrict__ er,
    const short* __restrict__ xb,       // [NN][FIN] bf16
    short* __restrict__ A1)             // [NN][768] bf16
{
  const int lane = threadIdx.x & 63;
  const int node = blockIdx.x * 4 + (threadIdx.x >> 6);
  if (node >= NN) return;
  const int g  = lane >> 5;
  const int cl = lane & 31;

#pragma unroll
  for (int r = 0; r < NREL; ++r) {
    const int beg = row_ptr[r * NN + node];
    const int end = row_ptr[r * NN + node + 1];
    const float eri = er[r * NN + node];
    const float* elr = el + r * NN;

    float dsum = 0.f;
    float f0 = 0.f, f1 = 0.f, f2 = 0.f, f3 = 0.f;
    for (int chunk = beg; chunk < end; chunk += 64) {
      int e = chunk + lane;
      int sidx = 0; float a = 0.f;
      if (e < end) {
        sidx = csr_src[e];
        float tv = elr[sidx] + eri;
        tv = tv > 0.f ? tv : SLOPE * tv;
        a = __expf(tv);
      }
      dsum += a;
      const int cnt = (end - chunk < 64) ? end - chunk : 64;
      for (int i = g; i < cnt; i += 2) {
        float aj = __shfl(a, i);
        int   sj = __shfl(sidx, i);
        bf16x4 v = *(const bf16x4*)&xb[(size_t)sj * FIN + cl * 4];
        f0 = fmaf(bf2f(v[0]), aj, f0);
        f1 = fmaf(bf2f(v[1]), aj, f1);
        f2 = fmaf(bf2f(v[2]), aj, f2);
        f3 = fmaf(bf2f(v[3]), aj, f3);
      }
    }
#pragma unroll
    for (int off = 32; off > 0; off >>= 1) dsum += __shfl_xor(dsum, off);
    f0 += __shfl_xor(f0, 32);
    f1 += __shfl_xor(f1, 32);
    f2 += __shfl_xor(f2, 32);
    f3 += __shfl_xor(f3, 32);

    const float inv = 1.f / (3.f * fmaxf(dsum, 1e-9f));
    if (g == 0) {
      float a0 = f0 * inv, a1 = f1 * inv, a2 = f2 * inv, a3 = f3 * inv;
      short h0 = f2bf(a0), h1 = f2bf(a1), h2 = f2bf(a2), h3 = f2bf(a3);
      bf16x4 hi = {h0, h1, h2, h3};
      bf16x4 lo = {f2bf(a0 - bf2f(h0)), f2bf(a1 - bf2f(h1)),
                   f2bf(a2 - bf2f(h2)), f2bf(a3 - bf2f(h3))};
      size_t base = (size_t)node * (2 * NREL * FIN) + r * FIN + cl * 4;
      *(bf16x4*)&A1[base] = hi;
      *(bf16x4*)&A1[base + NREL * FIN] = lo;
    }
  }
}

// ------- L1 GEMM (LDS-staged A): hb = relu(A1@W1d^T + beff1) bf16 ---------
__global__ __launch_bounds__(256) void gemm_hl(
    const short* __restrict__ A, const short* __restrict__ Bt,
    const float* __restrict__ beff, short* __restrict__ hb, int M)
{
  constexpr int K = 2 * NREL * FIN;    // 768
  constexpr int BK = 128;
  constexpr int LW = 136;
  __shared__ __align__(16) short As[64 * LW];
  const int tid  = threadIdx.x;
  const int lane = tid & 63;
  const int wave = tid >> 6;
  const int m0 = blockIdx.x * 64;
  const int n0 = wave * 64;
  const int c    = lane & 15;
  const int rgrp = lane >> 4;

  f32x4 acc[4][4] = {};
  for (int k0 = 0; k0 < K; k0 += BK) {
    __syncthreads();
#pragma unroll
    for (int i = 0; i < 4; ++i) {
      int idx = i * 256 + tid;
      int row = idx >> 4;
      int ch  = idx & 15;
      int gr = m0 + row; gr = gr < M ? gr : M - 1;
      bf16x8 v = *(const bf16x8*)&A[(size_t)gr * K + k0 + ch * 8];
      *(bf16x8*)&As[row * LW + ch * 8] = v;
    }
    __syncthreads();
#pragma unroll
    for (int ks = 0; ks < 4; ++ks) {
      const int koff = ks * 32 + rgrp * 8;
      bf16x8 a[4], b[4];
#pragma unroll
      for (int i = 0; i < 4; ++i)
        a[i] = *(const bf16x8*)&As[(i * 16 + c) * LW + koff];
#pragma unroll
      for (int j = 0; j < 4; ++j)
        b[j] = *(const bf16x8*)&Bt[(size_t)(n0 + j * 16 + c) * K + k0 + koff];
#pragma unroll
      for (int i = 0; i < 4; ++i)
#pragma unroll
        for (int j = 0; j < 4; ++j)
          acc[i][j] = __builtin_amdgcn_mfma_f32_16x16x32_bf16(a[i], b[j], acc[i][j], 0, 0, 0);
    }
  }
#pragma unroll
  for (int i = 0; i < 4; ++i)
#pragma unroll
    for (int v = 0; v < 4; ++v) {
      int row = m0 + i * 16 + rgrp * 4 + v;
      if (row < M) {
#pragma unroll
        for (int j = 0; j < 4; ++j) {
          int col = n0 + j * 16 + c;
          hb[(size_t)row * HD + col] = f2bf(fmaxf(acc[i][j][v] + beff[col], 0.f));
        }
      }
    }
}

// ---- L2 GEMM (LDS-staged A): featb2[r] = hb @ W2t[r]^T + el/er epilogue --
__global__ __launch_bounds__(256) void gemm_fused2(
    const short* __restrict__ A, const short* __restrict__ Wt,
    const float* __restrict__ al, const float* __restrict__ ar,
    short* __restrict__ featb, float* __restrict__ el, float* __restrict__ er,
    int M)
{
  constexpr int K = HD;
  constexpr int BK = 128;
  constexpr int LW = 136;
  constexpr int N_ = FIN;
  __shared__ __align__(16) short As[128 * LW];
  const int r = blockIdx.y;
  const short* Bt  = Wt + (size_t)r * N_ * K;
  const float* alr = al + r * N_;
  const float* arr = ar + r * N_;
  short* fb  = featb + (size_t)r * M * N_;
  float* elr = el + r * NN;
  float* err = er + r * NN;

  const int tid  = threadIdx.x;
  const int lane = tid & 63;
  const int wave = tid >> 6;
  const int wm = wave >> 1;
  const int wn = wave & 1;
  const int m0 = blockIdx.x * 128 + wm * 64;
  const int n0 = wn * 64;
  const int c    = lane & 15;
  const int rgrp = lane >> 4;

  f32x4 acc[4][4] = {};
  for (int k0 = 0; k0 < K; k0 += BK) {
    __syncthreads();
#pragma unroll
    for (int i = 0; i < 8; ++i) {
      int idx = i * 256 + tid;
      int row = idx >> 4;
      int ch  = idx & 15;
      int gr = blockIdx.x * 128 + row; gr = gr < M ? gr : M - 1;
      bf16x8 v = *(const bf16x8*)&A[(size_t)gr * K + k0 + ch * 8];
      *(bf16x8*)&As[row * LW + ch * 8] = v;
    }
    __syncthreads();
#pragma unroll
    for (int ks = 0; ks < 4; ++ks) {
      const int koff = ks * 32 + rgrp * 8;
      bf16x8 a[4], b[4];
#pragma unroll
      for (int i = 0; i < 4; ++i)
        a[i] = *(const bf16x8*)&As[(wm * 64 + i * 16 + c) * LW + koff];
#pragma unroll
      for (int j = 0; j < 4; ++j)
        b[j] = *(const bf16x8*)&Bt[(size_t)(n0 + j * 16 + c) * K + k0 + koff];
#pragma unroll
      for (int i = 0; i < 4; ++i)
#pragma unroll
        for (int j = 0; j < 4; ++j)
          acc[i][j] = __builtin_amdgcn_mfma_f32_16x16x32_bf16(a[i], b[j], acc[i][j], 0, 0, 0);
    }
  }

  __shared__ float2 part[2][128];
  float pe[4][4], pr[4][4];
#pragma unroll
  for (int i = 0; i < 4; ++i)
#pragma unroll
    for (int v = 0; v < 4; ++v) {
      float se = 0.f, sr = 0.f;
#pragma unroll
      for (int j = 0; j < 4; ++j) {
        float av = acc[i][j][v];
        int col = n0 + j * 16 + c;
        se = fmaf(av, alr[col], se);
        sr = fmaf(av, arr[col], sr);
      }
      pe[i][v] = se; pr[i][v] = sr;
    }
#pragma unroll
  for (int i = 0; i < 4; ++i)
#pragma unroll
    for (int v = 0; v < 4; ++v) {
      int row = m0 + i * 16 + rgrp * 4 + v;
      if (row < M) {
#pragma unroll
        for (int j = 0; j < 4; ++j)
          fb[(size_t)row * N_ + n0 + j * 16 + c] = f2bf(acc[i][j][v]);
      }
#pragma unroll
      for (int off = 1; off < 16; off <<= 1) {
        pe[i][v] += __shfl_xor(pe[i][v], off);
        pr[i][v] += __shfl_xor(pr[i][v], off);
      }
    }
  __syncthreads();
  if (c == 0) {
#pragma unroll
    for (int i = 0; i < 4; ++i)
#pragma unroll
      for (int v = 0; v < 4; ++v)
        part[wn][wm * 64 + i * 16 + rgrp * 4 + v] = make_float2(pe[i][v], pr[i][v]);
  }
  __syncthreads();
  if (tid < 128) {
    float se = part[0][tid].x + part[1][tid].x;
    float sr = part[0][tid].y + part[1][tid].y;
    int row = blockIdx.x * 128 + tid;
    if (row < M) { elr[row] = se; err[row] = sr; }
  }
}

// ---- L2: projected-space fused 3-relation gather + relu + predictor dots -
// One pass (no segment-max), 2 edge-groups of 32 lanes x bf16x4.
__global__ __launch_bounds__(256) void gat_agg_dots(
    const int* __restrict__ row_ptr, const int* __restrict__ csr_src,
    const float* __restrict__ el, const float* __restrict__ er,
    const short* __restrict__ featb,    // [NREL][NN][FIN] bf16
    const float* __restrict__ beff,     // [FIN]
    const float* __restrict__ Wlin,     // [2*FIN]
    float* __restrict__ dotl, float* __restrict__ dotr)
{
  const int lane = threadIdx.x & 63;
  const int node = blockIdx.x * 4 + (threadIdx.x >> 6);
  if (node >= NN) return;
  const int g  = lane >> 5;
  const int cl = lane & 31;

  float t0 = 0.f, t1 = 0.f, t2 = 0.f, t3 = 0.f;
#pragma unroll
  for (int r = 0; r < NREL; ++r) {
    const int beg = row_ptr[r * NN + node];
    const int end = row_ptr[r * NN + node + 1];
    const float eri = er[r * NN + node];
    const float* elr = el + r * NN;
    const short* fb  = featb + (size_t)r * NN * FIN;

    float dsum = 0.f;
    float f0 = 0.f, f1 = 0.f, f2 = 0.f, f3 = 0.f;
    for (int chunk = beg; chunk < end; chunk += 64) {
      int e = chunk + lane;
      int sidx = 0; float a = 0.f;
      if (e < end) {
        sidx = csr_src[e];
        float tv = elr[sidx] + eri;
        tv = tv > 0.f ? tv : SLOPE * tv;
        a = __expf(tv);
      }
      dsum += a;
      const int cnt = (end - chunk < 64) ? end - chunk : 64;
      for (int i = g; i < cnt; i += 2) {
        float aj = __shfl(a, i);
        int   sj = __shfl(sidx, i);
        bf16x4 v = *(const bf16x4*)&fb[(size_t)sj * FIN + cl * 4];
        f0 = fmaf(bf2f(v[0]), aj, f0);
        f1 = fmaf(bf2f(v[1]), aj, f1);
        f2 = fmaf(bf2f(v[2]), aj, f2);
        f3 = fmaf(bf2f(v[3]), aj, f3);
      }
    }
#pragma unroll
    for (int off = 32; off > 0; off >>= 1) dsum += __shfl_xor(dsum, off);
    const float inv = 1.f / (3.f * fmaxf(dsum, 1e-9f));
    t0 = fmaf(f0, inv, t0);
    t1 = fmaf(f1, inv, t1);
    t2 = fmaf(f2, inv, t2);
    t3 = fmaf(f3, inv, t3);
  }
  // cross-group reduce (deferred; inv is wave-uniform)
  t0 += __shfl_xor(t0, 32);
  t1 += __shfl_xor(t1, 32);
  t2 += __shfl_xor(t2, 32);
  t3 += __shfl_xor(t3, 32);

  float dl = 0.f, dr = 0.f;
  if (g == 0) {
    const int c = cl * 4;
    float g0 = fmaxf(t0 + beff[c + 0], 0.f);
    float g1 = fmaxf(t1 + beff[c + 1], 0.f);
    float g2 = fmaxf(t2 + beff[c + 2], 0.f);
    float g3 = fmaxf(t3 + beff[c + 3], 0.f);
    dl = g0 * Wlin[c] + g1 * Wlin[c + 1] + g2 * Wlin[c + 2] + g3 * Wlin[c + 3];
    dr = g0 * Wlin[FIN + c] + g1 * Wlin[FIN + c + 1]
       + g2 * Wlin[FIN + c + 2] + g3 * Wlin[FIN + c + 3];
  }
#pragma unroll
  for (int off = 32; off > 0; off >>= 1) {
    dl += __shfl_xor(dl, off);
    dr += __shfl_xor(dr, off);
  }
  if (lane == 0) { dotl[node] = dl; dotr[node] = dr; }
}

// ------------- pair logits -------------------------------------------------
__global__ __launch_bounds__(256) void pair_out(
    const int* __restrict__ edges, const int* __restrict__ n_pairs,
    const float* __restrict__ dotl, const float* __restrict__ dotr,
    const float* __restrict__ blin, float* __restrict__ out)
{
  const int TOT = NREL * NE + NP;
  int p = blockIdx.x * blockDim.x + threadIdx.x;
  if (p >= TOT) return;
  int s, d;
  if (p < NREL * NE) {
    int r = p / NE;
    int e = p - r * NE;
    const int* base = edges + (size_t)r * 2 * NE;
    s = base[e];
    d = base[NE + e];
  } else {
    int q = p - NREL * NE;
    s = n_pairs[2 * q];
    d = n_pairs[2 * q + 1];
  }
  float logit = dotl[s] + dotr[d] + blin[0];
  out[p] = 1.f / (1.f + expf(-logit));
}

extern "C" void kernel_launch(void* const* d_in, const int* in_sizes, int n_in,
                              void* d_out, int out_size, void* d_ws, size_t ws_size,
                              hipStream_t stream) {
  const float* x      = (const float*)d_in[0];
  const int*   edges  = (const int*)d_in[1];
  const int*   npairs = (const int*)d_in[2];
  const float* W1     = (const float*)d_in[3];
  const float* al1    = (const float*)d_in[4];
  const float* ar1    = (const float*)d_in[5];
  const float* b1     = (const float*)d_in[6];
  const float* W2     = (const float*)d_in[7];
  const float* al2    = (const float*)d_in[8];
  const float* ar2    = (const float*)d_in[9];
  const float* b2     = (const float*)d_in[10];
  const float* Wlin   = (const float*)d_in[11];
  const float* blin   = (const float*)d_in[12];
  float* out = (float*)d_out;

  char* w = (char*)d_ws;
  size_t off = 0;
  auto alloc = [&](size_t bytes) {
    char* p = w + off;
    off = (off + bytes + 255) & ~(size_t)255;
    return p;
  };
  short* xb      = (short*)alloc((size_t)NN * FIN * 2);
  short* hb      = (short*)alloc((size_t)NN * HD * 2);
  short* A1      = (short*)alloc((size_t)NN * 2 * NREL * FIN * 2);
  short* featb2  = A1;   // aliased: A1 dead after gemm_hl
  short* W1d     = (short*)alloc((size_t)HD * 2 * NREL * FIN * 2);
  short* W2t     = (short*)alloc((size_t)NREL * FIN * HD * 2);
  float* wvec1   = (float*)alloc(6 * FIN * 4);
  float* beff1   = (float*)alloc(HD * 4);
  float* beff2   = (float*)alloc(FIN * 4);
  float* el      = (float*)alloc((size_t)NREL * NN * 4);
  float* er      = (float*)alloc((size_t)NREL * NN * 4);
  float* dotl    = (float*)alloc((size_t)NN * 4);
  float* dotr    = (float*)alloc((size_t)NN * 4);
  int*   deg     = (int*)  alloc((size_t)NREL * NN * 4);
  int*   cursor  = (int*)  alloc((size_t)NREL * NN * 4);
  int*   row_ptr = (int*)  alloc((size_t)(NREL * NN + 16) * 4);
  int*   psum    = (int*)  alloc(1024);
  int*   pexcl   = (int*)  alloc(1024);
  int*   csr_src = (int*)  alloc((size_t)NREL * NE * 4);

  const int B = 256;

  // ---------------- prep (1 kernel) ---------------------------------------
  prep_all<<<7596, B, 0, stream>>>(x, W1, W2, al1, ar1, b1, b2,
                                   xb, W1d, W2t, wvec1, beff1, beff2);

  // ---------------- CSR build ---------------------------------------------
  hipMemsetAsync(deg, 0, (size_t)NREL * NN * 4, stream);
  count_deg<<<(NREL * NE + B - 1) / B, B, 0, stream>>>(edges, deg);
  deg_partial<<<150, B, 0, stream>>>(deg, psum);
  scan_psum<<<1, B, 0, stream>>>(psum, pexcl);
  deg_rowptr<<<150, B, 0, stream>>>(deg, pexcl, row_ptr, cursor);
  fill_csr<<<(NREL * NE + B - 1) / B, B, 0, stream>>>(edges, cursor, csr_src);

  const int AGG_G = (NN + 3) / 4;

  // ---------------- layer 1: scores, input-space gather, GEMM -> hb -------
  rowdot6<<<AGG_G, B, 0, stream>>>(xb, wvec1, el, er);
  gat_gather_hl<<<AGG_G, B, 0, stream>>>(row_ptr, csr_src, el, er, xb, A1);
  gemm_hl<<<(NN + 63) / 64, B, 0, stream>>>(A1, W1d, beff1, hb, NN);

  // ---------------- layer 2: project, gather+dots -------------------------
  {
    dim3 g((NN + 127) / 128, NREL);
    gemm_fused2<<<g, B, 0, stream>>>(hb, W2t, al2, ar2, featb2, el, er, NN);
  }
  gat_agg_dots<<<AGG_G, B, 0, stream>>>(row_ptr, csr_src, el, er, featb2,
                                        beff2, Wlin, dotl, dotr);

  // ---------------- pair predictor ----------------------------------------
  const int TOT = NREL * NE + NP;
  pair_out<<<(TOT + B - 1) / B, B, 0, stream>>>(edges, npairs, dotl, dotr, blin, out);
}

// Round 11
// 307.093 us; speedup vs baseline: 1.3440x; 1.1002x over previous
//
#include <hip/hip_runtime.h>
#include <cstddef>

#define NN 50000
#define NREL 3
#define NE 250000
#define NP 100000
#define FIN 128
#define HD 256
#define SLOPE 0.2f

typedef short bf16x8 __attribute__((ext_vector_type(8)));
typedef short bf16x4 __attribute__((ext_vector_type(4)));
typedef short bf16x2 __attribute__((ext_vector_type(2)));
typedef float f32x4 __attribute__((ext_vector_type(4)));

__device__ __forceinline__ short f2bf(float f) {
  unsigned u = __float_as_uint(f);
  unsigned r = (u + 0x7FFFu + ((u >> 16) & 1u)) >> 16;   // RNE
  return (short)r;
}
__device__ __forceinline__ float bf2f(short s) {
  return __uint_as_float(((unsigned)(unsigned short)s) << 16);
}

// async global->LDS, 16 bytes per lane; lds ptr must be wave-uniform base.
__device__ __forceinline__ void gload16(const short* g, short* l) {
  __builtin_amdgcn_global_load_lds(
      (const __attribute__((address_space(1))) unsigned int*)g,
      (__attribute__((address_space(3))) unsigned int*)l, 16, 0, 0);
}

// ---------------- fused prep: xb, W1d (dup hi/lo, PRE-SWIZZLED), W2t ------
// swizzle: element (n,k) stored at k ^ ((n&7)<<3)  [within 64-short windows]
__global__ __launch_bounds__(256) void prep_all(
    const float* __restrict__ x,  const float* __restrict__ W1,
    const float* __restrict__ W2, const float* __restrict__ al1,
    const float* __restrict__ ar1, const float* __restrict__ b1,
    const float* __restrict__ b2,
    short* __restrict__ xb, short* __restrict__ W1d, short* __restrict__ W2t,
    float* __restrict__ wvec1, float* __restrict__ beff1, float* __restrict__ beff2)
{
  const int blk = blockIdx.x;
  const int t = threadIdx.x;
  if (blk < 6250) {                                   // x -> bf16
    int i = (blk * 256 + t) * 4;
    float4 v = *(const float4*)&x[i];
    short4 o = {f2bf(v.x), f2bf(v.y), f2bf(v.z), f2bf(v.w)};
    *(short4*)&xb[i] = o;
  } else if (blk < 7018) {                            // W1d[n][kpos], k<768
    int o = (blk - 6250) * 256 + t;
    if (o < HD * 2 * NREL * FIN) {
      int n = o / (2 * NREL * FIN);
      int kpos = o - n * (2 * NREL * FIN);
      int ke = kpos ^ ((n & 7) << 3);                 // element for this slot
      int k2 = (ke < NREL * FIN) ? ke : ke - NREL * FIN;
      int r = k2 / FIN, kk = k2 - r * FIN;
      W1d[o] = f2bf(W1[((size_t)r * FIN + kk) * HD + n]);
    }
  } else if (blk < 7402) {                            // W2t[r][n][kpos]
    int o = (blk - 7018) * 256 + t;
    if (o < NREL * FIN * HD) {
      int r = o / (FIN * HD);
      int rem = o - r * (FIN * HD);
      int n = rem / HD, kpos = rem - n * HD;
      int ke = kpos ^ ((n & 7) << 3);
      W2t[o] = f2bf(W2[((size_t)r * HD + ke) * FIN + n]);
    }
  } else if (blk < 7594) {                            // wvec1[j][k] = W1_r[k,:]·v
    int wid = (blk - 7402) * 4 + (t >> 6);
    int lane = t & 63;
    if (wid < 6 * FIN) {
      int j = wid / FIN, k = wid - j * FIN;
      int side = j / 3, r = j - side * 3;
      const float* v  = (side ? ar1 : al1) + r * HD;
      const float* Wr = W1 + ((size_t)r * FIN + k) * HD;
      float s = 0.f;
      for (int n = lane; n < HD; n += 64) s += Wr[n] * v[n];
#pragma unroll
      for (int off = 32; off > 0; off >>= 1) s += __shfl_down(s, off);
      if (lane == 0) wvec1[wid] = s;
    }
  } else {                                            // beff
    int t2 = (blk - 7594) * 256 + t;
    if (t2 < HD) beff1[t2] = (b1[t2] + b1[HD + t2] + b1[2 * HD + t2]) * (1.f / 3.f);
    else if (t2 < HD + FIN) {
      int k = t2 - HD;
      beff2[k] = (b2[k] + b2[FIN + k] + b2[2 * FIN + k]) * (1.f / 3.f);
    }
  }
}

// ------- el/er for layer 1: d[j] = xb[i,:]·wvec1[j,:], j<6 ----------------
__global__ __launch_bounds__(256) void rowdot6(
    const short* __restrict__ feat, const float* __restrict__ wvec,
    float* __restrict__ el, float* __restrict__ er)
{
  const int lane = threadIdx.x & 63;
  const int node = blockIdx.x * 4 + (threadIdx.x >> 6);
  if (node >= NN) return;
  bf16x2 f16 = *(const bf16x2*)&feat[(size_t)node * FIN + lane * 2];
  float f0 = bf2f(f16[0]), f1 = bf2f(f16[1]);
  float d[6];
#pragma unroll
  for (int j = 0; j < 6; ++j)
    d[j] = f0 * wvec[j * FIN + lane * 2] + f1 * wvec[j * FIN + lane * 2 + 1];
#pragma unroll
  for (int off = 32; off > 0; off >>= 1)
#pragma unroll
    for (int j = 0; j < 6; ++j) d[j] += __shfl_xor(d[j], off);
  if (lane == 0) {
    el[0 * NN + node] = d[0]; el[1 * NN + node] = d[1]; el[2 * NN + node] = d[2];
    er[0 * NN + node] = d[3]; er[1 * NN + node] = d[4]; er[2 * NN + node] = d[5];
  }
}

// ------------- CSR build: degree count ------------------------------------
__global__ __launch_bounds__(256) void count_deg(
    const int* __restrict__ edges, int* __restrict__ deg)
{
  int tid = blockIdx.x * blockDim.x + threadIdx.x;
  if (tid >= NREL * NE) return;
  int r = tid / NE;
  int e = tid - r * NE;
  int d = edges[(size_t)r * 2 * NE + NE + e];
  atomicAdd(&deg[r * NN + d], 1);
}

// ------------- CSR scan phase 1 -------------------------------------------
__global__ __launch_bounds__(256) void deg_partial(
    const int* __restrict__ deg, int* __restrict__ psum)
{
  const int b = blockIdx.x;
  const int t = threadIdx.x;
  int4 v = {0, 0, 0, 0};
  if (t < 250) v = *(const int4*)&deg[b * 1000 + t * 4];
  int s = v.x + v.y + v.z + v.w;
#pragma unroll
  for (int off = 32; off > 0; off >>= 1) s += __shfl_down(s, off);
  __shared__ int ws[4];
  if ((t & 63) == 0) ws[t >> 6] = s;
  __syncthreads();
  if (t == 0) psum[b] = ws[0] + ws[1] + ws[2] + ws[3];
}

// ------------- CSR scan phase 2 -------------------------------------------
__global__ __launch_bounds__(256) void scan_psum(
    const int* __restrict__ psum, int* __restrict__ pexcl)
{
  __shared__ int lds[256];
  const int t = threadIdx.x;
  int v = (t < 150) ? psum[t] : 0;
  lds[t] = v;
  __syncthreads();
  for (int off = 1; off < 256; off <<= 1) {
    int add = (t >= off) ? lds[t - off] : 0;
    __syncthreads();
    lds[t] += add;
    __syncthreads();
  }
  if (t < 150) pexcl[t] = lds[t] - v;
}

// ------------- CSR scan phase 3: row_ptr + cursor init --------------------
__global__ __launch_bounds__(256) void deg_rowptr(
    const int* __restrict__ deg, const int* __restrict__ pexcl,
    int* __restrict__ row_ptr, int* __restrict__ cursor)
{
  const int b = blockIdx.x;
  const int t = threadIdx.x;
  int4 v = {0, 0, 0, 0};
  if (t < 250) v = *(const int4*)&deg[b * 1000 + t * 4];
  int s = v.x + v.y + v.z + v.w;
  __shared__ int lds[256];
  lds[t] = s;
  __syncthreads();
  for (int off = 1; off < 256; off <<= 1) {
    int add = (t >= off) ? lds[t - off] : 0;
    __syncthreads();
    lds[t] += add;
    __syncthreads();
  }
  int run = lds[t] - s + pexcl[b];
  if (t < 250) {
    int i = b * 1000 + t * 4;
    row_ptr[i] = run;     cursor[i] = run;     run += v.x;
    row_ptr[i + 1] = run; cursor[i + 1] = run; run += v.y;
    row_ptr[i + 2] = run; cursor[i + 2] = run; run += v.z;
    row_ptr[i + 3] = run; cursor[i + 3] = run;
  }
  if (b == 0 && t == 0) row_ptr[NREL * NN] = NREL * NE;
}

// ------------- CSR build: fill src lists ----------------------------------
__global__ __launch_bounds__(256) void fill_csr(
    const int* __restrict__ edges, int* __restrict__ cursor,
    int* __restrict__ csr_src)
{
  int tid = blockIdx.x * blockDim.x + threadIdx.x;
  if (tid >= NREL * NE) return;
  int r = tid / NE;
  int e = tid - r * NE;
  const int* base = edges + (size_t)r * 2 * NE;
  int s = base[e];
  int d = base[NE + e];
  int pos = atomicAdd(&cursor[r * NN + d], 1);
  csr_src[pos] = s;
}

// ------- L1: input-space fused 3-relation gather, hi/lo bf16 out ----------
// A1 rows written PRE-SWIZZLED: element (node,k) at k ^ ((node&7)<<3).
__global__ __launch_bounds__(256) void gat_gather_hl(
    const int* __restrict__ row_ptr, const int* __restrict__ csr_src,
    const float* __restrict__ el, const float* __restrict__ er,
    const short* __restrict__ xb,       // [NN][FIN] bf16
    short* __restrict__ A1)             // [NN][768] bf16, swizzled
{
  const int lane = threadIdx.x & 63;
  const int node = blockIdx.x * 4 + (threadIdx.x >> 6);
  if (node >= NN) return;
  const int g  = lane >> 5;
  const int cl = lane & 31;
  const int sw = (node & 7) << 3;
  const size_t rowbase = (size_t)node * (2 * NREL * FIN);

#pragma unroll
  for (int r = 0; r < NREL; ++r) {
    const int beg = row_ptr[r * NN + node];
    const int end = row_ptr[r * NN + node + 1];
    const float eri = er[r * NN + node];
    const float* elr = el + r * NN;

    float dsum = 0.f;
    float f0 = 0.f, f1 = 0.f, f2 = 0.f, f3 = 0.f;
    for (int chunk = beg; chunk < end; chunk += 64) {
      int e = chunk + lane;
      int sidx = 0; float a = 0.f;
      if (e < end) {
        sidx = csr_src[e];
        float tv = elr[sidx] + eri;
        tv = tv > 0.f ? tv : SLOPE * tv;
        a = __expf(tv);
      }
      dsum += a;
      const int cnt = (end - chunk < 64) ? end - chunk : 64;
      for (int i = g; i < cnt; i += 2) {
        float aj = __shfl(a, i);
        int   sj = __shfl(sidx, i);
        bf16x4 v = *(const bf16x4*)&xb[(size_t)sj * FIN + cl * 4];
        f0 = fmaf(bf2f(v[0]), aj, f0);
        f1 = fmaf(bf2f(v[1]), aj, f1);
        f2 = fmaf(bf2f(v[2]), aj, f2);
        f3 = fmaf(bf2f(v[3]), aj, f3);
      }
    }
#pragma unroll
    for (int off = 32; off > 0; off >>= 1) dsum += __shfl_xor(dsum, off);
    f0 += __shfl_xor(f0, 32);
    f1 += __shfl_xor(f1, 32);
    f2 += __shfl_xor(f2, 32);
    f3 += __shfl_xor(f3, 32);

    const float inv = 1.f / (3.f * fmaxf(dsum, 1e-9f));
    if (g == 0) {
      float a0 = f0 * inv, a1 = f1 * inv, a2 = f2 * inv, a3 = f3 * inv;
      short h0 = f2bf(a0), h1 = f2bf(a1), h2 = f2bf(a2), h3 = f2bf(a3);
      bf16x4 hi = {h0, h1, h2, h3};
      bf16x4 lo = {f2bf(a0 - bf2f(h0)), f2bf(a1 - bf2f(h1)),
                   f2bf(a2 - bf2f(h2)), f2bf(a3 - bf2f(h3))};
      int u = (r * FIN + cl * 4) ^ sw;       // swizzled within 64-short window
      *(bf16x4*)&A1[rowbase + u] = hi;
      *(bf16x4*)&A1[rowbase + NREL * FIN + u] = lo;
    }
  }
}

// ------- L1 GEMM v3: hb = relu(A1@W1d^T + beff1), global_load_lds staged --
// BM=64, BN=128 (grid y=2), BK=64. A,B both LDS. hb written PRE-SWIZZLED.
__global__ __launch_bounds__(256) void gemm_hl(
    const short* __restrict__ A, const short* __restrict__ Bt,
    const float* __restrict__ beff, short* __restrict__ hb, int M)
{
  constexpr int K = 2 * NREL * FIN;    // 768
  constexpr int BK = 64;
  __shared__ __align__(16) short AsB[(64 + 128) * BK];  // 24 KB
  short* As = AsB;
  short* Bs = AsB + 64 * BK;
  const int tid  = threadIdx.x;
  const int lane = tid & 63;
  const int wave = tid >> 6;
  const int m0  = blockIdx.x * 64;
  const int n00 = blockIdx.y * 128;
  const int c    = lane & 15;
  const int rgrp = lane >> 4;
  const int wbase = tid & ~63;         // wave-uniform chunk base

  f32x4 acc[4][2] = {};
  for (int k0 = 0; k0 < K; k0 += BK) {
    __syncthreads();
#pragma unroll
    for (int q = 0; q < 2; ++q) {      // A: 512 chunks
      int idx = q * 256 + tid;
      int row = idx >> 3, ch = idx & 7;
      int gr = m0 + row; gr = gr < M ? gr : M - 1;
      gload16(&A[(size_t)gr * K + k0 + ch * 8], As + (q * 256 + wbase) * 8);
    }
#pragma unroll
    for (int q = 0; q < 4; ++q) {      // B: 1024 chunks
      int jdx = q * 256 + tid;
      int col = jdx >> 3, ch = jdx & 7;
      gload16(&Bt[(size_t)(n00 + col) * K + k0 + ch * 8], Bs + (q * 256 + wbase) * 8);
    }
    __syncthreads();
#pragma unroll
    for (int ks = 0; ks < 2; ++ks) {
      const int ko = (ks * 32 + rgrp * 8) ^ ((c & 7) << 3);  // de-swizzle
      bf16x8 a[4], b[2];
#pragma unroll
      for (int i = 0; i < 4; ++i)
        a[i] = *(const bf16x8*)&As[(i * 16 + c) * BK + ko];
#pragma unroll
      for (int j = 0; j < 2; ++j)
        b[j] = *(const bf16x8*)&Bs[(wave * 32 + j * 16 + c) * BK + ko];
#pragma unroll
      for (int i = 0; i < 4; ++i)
#pragma unroll
        for (int j = 0; j < 2; ++j)
          acc[i][j] = __builtin_amdgcn_mfma_f32_16x16x32_bf16(a[i], b[j], acc[i][j], 0, 0, 0);
    }
  }
#pragma unroll
  for (int i = 0; i < 4; ++i)
#pragma unroll
    for (int v = 0; v < 4; ++v) {
      int row = m0 + i * 16 + rgrp * 4 + v;
      if (row < M) {
        int srow = (row & 7) << 3;
#pragma unroll
        for (int j = 0; j < 2; ++j) {
          int col = n00 + wave * 32 + j * 16 + c;
          hb[(size_t)row * HD + (col ^ srow)] =
              f2bf(fmaxf(acc[i][j][v] + beff[col], 0.f));
        }
      }
    }
}

// ---- L2 GEMM v3: featb[r] = hb @ W2t[r]^T + el/er epilogue ---------------
// BM=64, BN=128 (full N), BK=64, grid y=3. hb/W2t are pre-swizzled.
__global__ __launch_bounds__(256) void gemm_fused2(
    const short* __restrict__ A, const short* __restrict__ Wt,
    const float* __restrict__ al, const float* __restrict__ ar,
    short* __restrict__ featb, float* __restrict__ el, float* __restrict__ er,
    int M)
{
  constexpr int K = HD;                // 256
  constexpr int BK = 64;
  constexpr int N_ = FIN;              // 128
  __shared__ __align__(16) short AsB[(64 + 128) * BK];  // 24 KB
  __shared__ float2 part[4][64];
  short* As = AsB;
  short* Bs = AsB + 64 * BK;
  const int r = blockIdx.y;
  const short* Bt  = Wt + (size_t)r * N_ * K;
  const float* alr = al + r * N_;
  const float* arr = ar + r * N_;
  short* fb  = featb + (size_t)r * M * N_;
  float* elr = el + r * NN;
  float* err = er + r * NN;

  const int tid  = threadIdx.x;
  const int lane = tid & 63;
  const int wave = tid >> 6;
  const int m0 = blockIdx.x * 64;
  const int c    = lane & 15;
  const int rgrp = lane >> 4;
  const int wbase = tid & ~63;

  f32x4 acc[4][2] = {};
  for (int k0 = 0; k0 < K; k0 += BK) {
    __syncthreads();
#pragma unroll
    for (int q = 0; q < 2; ++q) {
      int idx = q * 256 + tid;
      int row = idx >> 3, ch = idx & 7;
      int gr = m0 + row; gr = gr < M ? gr : M - 1;
      gload16(&A[(size_t)gr * K + k0 + ch * 8], As + (q * 256 + wbase) * 8);
    }
#pragma unroll
    for (int q = 0; q < 4; ++q) {
      int jdx = q * 256 + tid;
      int col = jdx >> 3, ch = jdx & 7;
      gload16(&Bt[(size_t)col * K + k0 + ch * 8], Bs + (q * 256 + wbase) * 8);
    }
    __syncthreads();
#pragma unroll
    for (int ks = 0; ks < 2; ++ks) {
      const int ko = (ks * 32 + rgrp * 8) ^ ((c & 7) << 3);
      bf16x8 a[4], b[2];
#pragma unroll
      for (int i = 0; i < 4; ++i)
        a[i] = *(const bf16x8*)&As[(i * 16 + c) * BK + ko];
#pragma unroll
      for (int j = 0; j < 2; ++j)
        b[j] = *(const bf16x8*)&Bs[(wave * 32 + j * 16 + c) * BK + ko];
#pragma unroll
      for (int i = 0; i < 4; ++i)
#pragma unroll
        for (int j = 0; j < 2; ++j)
          acc[i][j] = __builtin_amdgcn_mfma_f32_16x16x32_bf16(a[i], b[j], acc[i][j], 0, 0, 0);
    }
  }

  // epilogue: featb (bf16, normal layout) + el/er dots
  float pe[4][4], pr[4][4];
#pragma unroll
  for (int i = 0; i < 4; ++i)
#pragma unroll
    for (int v = 0; v < 4; ++v) {
      float se = 0.f, sr = 0.f;
#pragma unroll
      for (int j = 0; j < 2; ++j) {
        float av = acc[i][j][v];
        int col = wave * 32 + j * 16 + c;
        se = fmaf(av, alr[col], se);
        sr = fmaf(av, arr[col], sr);
      }
      pe[i][v] = se; pr[i][v] = sr;
    }
#pragma unroll
  for (int i = 0; i < 4; ++i)
#pragma unroll
    for (int v = 0; v < 4; ++v) {
      int row = m0 + i * 16 + rgrp * 4 + v;
      if (row < M) {
#pragma unroll
        for (int j = 0; j < 2; ++j)
          fb[(size_t)row * N_ + wave * 32 + j * 16 + c] = f2bf(acc[i][j][v]);
      }
#pragma unroll
      for (int off = 1; off < 16; off <<= 1) {
        pe[i][v] += __shfl_xor(pe[i][v], off);
        pr[i][v] += __shfl_xor(pr[i][v], off);
      }
    }
  if (c == 0) {
#pragma unroll
    for (int i = 0; i < 4; ++i)
#pragma unroll
      for (int v = 0; v < 4; ++v)
        part[wave][i * 16 + rgrp * 4 + v] = make_float2(pe[i][v], pr[i][v]);
  }
  __syncthreads();
  if (tid < 64) {
    float se = 0.f, sr = 0.f;
#pragma unroll
    for (int w = 0; w < 4; ++w) { se += part[w][tid].x; sr += part[w][tid].y; }
    int row = m0 + tid;
    if (row < M) { elr[row] = se; err[row] = sr; }
  }
}

// ---- L2: projected-space fused 3-relation gather + relu + predictor dots -
__global__ __launch_bounds__(256) void gat_agg_dots(
    const int* __restrict__ row_ptr, const int* __restrict__ csr_src,
    const float* __restrict__ el, const float* __restrict__ er,
    const short* __restrict__ featb,    // [NREL][NN][FIN] bf16 (normal layout)
    const float* __restrict__ beff,     // [FIN]
    const float* __restrict__ Wlin,     // [2*FIN]
    float* __restrict__ dotl, float* __restrict__ dotr)
{
  const int lane = threadIdx.x & 63;
  const int node = blockIdx.x * 4 + (threadIdx.x >> 6);
  if (node >= NN) return;
  const int g  = lane >> 5;
  const int cl = lane & 31;

  float t0 = 0.f, t1 = 0.f, t2 = 0.f, t3 = 0.f;
#pragma unroll
  for (int r = 0; r < NREL; ++r) {
    const int beg = row_ptr[r * NN + node];
    const int end = row_ptr[r * NN + node + 1];
    const float eri = er[r * NN + node];
    const float* elr = el + r * NN;
    const short* fb  = featb + (size_t)r * NN * FIN;

    float dsum = 0.f;
    float f0 = 0.f, f1 = 0.f, f2 = 0.f, f3 = 0.f;
    for (int chunk = beg; chunk < end; chunk += 64) {
      int e = chunk + lane;
      int sidx = 0; float a = 0.f;
      if (e < end) {
        sidx = csr_src[e];
        float tv = elr[sidx] + eri;
        tv = tv > 0.f ? tv : SLOPE * tv;
        a = __expf(tv);
      }
      dsum += a;
      const int cnt = (end - chunk < 64) ? end - chunk : 64;
      for (int i = g; i < cnt; i += 2) {
        float aj = __shfl(a, i);
        int   sj = __shfl(sidx, i);
        bf16x4 v = *(const bf16x4*)&fb[(size_t)sj * FIN + cl * 4];
        f0 = fmaf(bf2f(v[0]), aj, f0);
        f1 = fmaf(bf2f(v[1]), aj, f1);
        f2 = fmaf(bf2f(v[2]), aj, f2);
        f3 = fmaf(bf2f(v[3]), aj, f3);
      }
    }
#pragma unroll
    for (int off = 32; off > 0; off >>= 1) dsum += __shfl_xor(dsum, off);
    const float inv = 1.f / (3.f * fmaxf(dsum, 1e-9f));
    t0 = fmaf(f0, inv, t0);
    t1 = fmaf(f1, inv, t1);
    t2 = fmaf(f2, inv, t2);
    t3 = fmaf(f3, inv, t3);
  }
  t0 += __shfl_xor(t0, 32);
  t1 += __shfl_xor(t1, 32);
  t2 += __shfl_xor(t2, 32);
  t3 += __shfl_xor(t3, 32);

  float dl = 0.f, dr = 0.f;
  if (g == 0) {
    const int c = cl * 4;
    float g0 = fmaxf(t0 + beff[c + 0], 0.f);
    float g1 = fmaxf(t1 + beff[c + 1], 0.f);
    float g2 = fmaxf(t2 + beff[c + 2], 0.f);
    float g3 = fmaxf(t3 + beff[c + 3], 0.f);
    dl = g0 * Wlin[c] + g1 * Wlin[c + 1] + g2 * Wlin[c + 2] + g3 * Wlin[c + 3];
    dr = g0 * Wlin[FIN + c] + g1 * Wlin[FIN + c + 1]
       + g2 * Wlin[FIN + c + 2] + g3 * Wlin[FIN + c + 3];
  }
#pragma unroll
  for (int off = 32; off > 0; off >>= 1) {
    dl += __shfl_xor(dl, off);
    dr += __shfl_xor(dr, off);
  }
  if (lane == 0) { dotl[node] = dl; dotr[node] = dr; }
}

// ------------- pair logits -------------------------------------------------
__global__ __launch_bounds__(256) void pair_out(
    const int* __restrict__ edges, const int* __restrict__ n_pairs,
    const float* __restrict__ dotl, const float* __restrict__ dotr,
    const float* __restrict__ blin, float* __restrict__ out)
{
  const int TOT = NREL * NE + NP;
  int p = blockIdx.x * blockDim.x + threadIdx.x;
  if (p >= TOT) return;
  int s, d;
  if (p < NREL * NE) {
    int r = p / NE;
    int e = p - r * NE;
    const int* base = edges + (size_t)r * 2 * NE;
    s = base[e];
    d = base[NE + e];
  } else {
    int q = p - NREL * NE;
    s = n_pairs[2 * q];
    d = n_pairs[2 * q + 1];
  }
  float logit = dotl[s] + dotr[d] + blin[0];
  out[p] = 1.f / (1.f + expf(-logit));
}

extern "C" void kernel_launch(void* const* d_in, const int* in_sizes, int n_in,
                              void* d_out, int out_size, void* d_ws, size_t ws_size,
                              hipStream_t stream) {
  const float* x      = (const float*)d_in[0];
  const int*   edges  = (const int*)d_in[1];
  const int*   npairs = (const int*)d_in[2];
  const float* W1     = (const float*)d_in[3];
  const float* al1    = (const float*)d_in[4];
  const float* ar1    = (const float*)d_in[5];
  const float* b1     = (const float*)d_in[6];
  const float* W2     = (const float*)d_in[7];
  const float* al2    = (const float*)d_in[8];
  const float* ar2    = (const float*)d_in[9];
  const float* b2     = (const float*)d_in[10];
  const float* Wlin   = (const float*)d_in[11];
  const float* blin   = (const float*)d_in[12];
  float* out = (float*)d_out;

  char* w = (char*)d_ws;
  size_t off = 0;
  auto alloc = [&](size_t bytes) {
    char* p = w + off;
    off = (off + bytes + 255) & ~(size_t)255;
    return p;
  };
  short* xb      = (short*)alloc((size_t)NN * FIN * 2);
  short* hb      = (short*)alloc((size_t)NN * HD * 2);
  short* A1      = (short*)alloc((size_t)NN * 2 * NREL * FIN * 2);
  short* featb2  = A1;   // aliased: A1 dead after gemm_hl
  short* W1d     = (short*)alloc((size_t)HD * 2 * NREL * FIN * 2);
  short* W2t     = (short*)alloc((size_t)NREL * FIN * HD * 2);
  float* wvec1   = (float*)alloc(6 * FIN * 4);
  float* beff1   = (float*)alloc(HD * 4);
  float* beff2   = (float*)alloc(FIN * 4);
  float* el      = (float*)alloc((size_t)NREL * NN * 4);
  float* er      = (float*)alloc((size_t)NREL * NN * 4);
  float* dotl    = (float*)alloc((size_t)NN * 4);
  float* dotr    = (float*)alloc((size_t)NN * 4);
  int*   deg     = (int*)  alloc((size_t)NREL * NN * 4);
  int*   cursor  = (int*)  alloc((size_t)NREL * NN * 4);
  int*   row_ptr = (int*)  alloc((size_t)(NREL * NN + 16) * 4);
  int*   psum    = (int*)  alloc(1024);
  int*   pexcl   = (int*)  alloc(1024);
  int*   csr_src = (int*)  alloc((size_t)NREL * NE * 4);

  const int B = 256;

  // ---------------- prep (1 kernel) ---------------------------------------
  prep_all<<<7596, B, 0, stream>>>(x, W1, W2, al1, ar1, b1, b2,
                                   xb, W1d, W2t, wvec1, beff1, beff2);

  // ---------------- CSR build ---------------------------------------------
  hipMemsetAsync(deg, 0, (size_t)NREL * NN * 4, stream);
  count_deg<<<(NREL * NE + B - 1) / B, B, 0, stream>>>(edges, deg);
  deg_partial<<<150, B, 0, stream>>>(deg, psum);
  scan_psum<<<1, B, 0, stream>>>(psum, pexcl);
  deg_rowptr<<<150, B, 0, stream>>>(deg, pexcl, row_ptr, cursor);
  fill_csr<<<(NREL * NE + B - 1) / B, B, 0, stream>>>(edges, cursor, csr_src);

  const int AGG_G = (NN + 3) / 4;
  const int GEMM_GX = (NN + 63) / 64;   // 782

  // ---------------- layer 1: scores, input-space gather, GEMM -> hb -------
  rowdot6<<<AGG_G, B, 0, stream>>>(xb, wvec1, el, er);
  gat_gather_hl<<<AGG_G, B, 0, stream>>>(row_ptr, csr_src, el, er, xb, A1);
  {
    dim3 g(GEMM_GX, 2);
    gemm_hl<<<g, B, 0, stream>>>(A1, W1d, beff1, hb, NN);
  }

  // ---------------- layer 2: project, gather+dots -------------------------
  {
    dim3 g(GEMM_GX, NREL);
    gemm_fused2<<<g, B, 0, stream>>>(hb, W2t, al2, ar2, featb2, el, er, NN);
  }
  gat_agg_dots<<<AGG_G, B, 0, stream>>>(row_ptr, csr_src, el, er, featb2,
                                        beff2, Wlin, dotl, dotr);

  // ---------------- pair predictor ----------------------------------------
  const int TOT = NREL * NE + NP;
  pair_out<<<(TOT + B - 1) / B, B, 0, stream>>>(edges, npairs, dotl, dotr, blin, out);
}

// Round 12
// 275.562 us; speedup vs baseline: 1.4978x; 1.1144x over previous
//
#include <hip/hip_runtime.h>
#include <cstddef>

#define NN 50000
#define NREL 3
#define NE 250000
#define NP 100000
#define FIN 128
#define HD 256
#define SLOPE 0.2f

typedef short bf16x8 __attribute__((ext_vector_type(8)));
typedef short bf16x4 __attribute__((ext_vector_type(4)));
typedef short bf16x2 __attribute__((ext_vector_type(2)));
typedef float f32x4 __attribute__((ext_vector_type(4)));

__device__ __forceinline__ short f2bf(float f) {
  unsigned u = __float_as_uint(f);
  unsigned r = (u + 0x7FFFu + ((u >> 16) & 1u)) >> 16;   // RNE
  return (short)r;
}
__device__ __forceinline__ float bf2f(short s) {
  return __uint_as_float(((unsigned)(unsigned short)s) << 16);
}

// async global->LDS, 16 bytes per lane; lds ptr must be wave-uniform base.
__device__ __forceinline__ void gload16(const short* g, short* l) {
  __builtin_amdgcn_global_load_lds(
      (const __attribute__((address_space(1))) unsigned int*)g,
      (__attribute__((address_space(3))) unsigned int*)l, 16, 0, 0);
}

// ---------------- fused prep: xb, W1d (dup hi/lo, PRE-SWIZZLED), W2t ------
// swizzle: element (n,k) stored at k ^ ((n&7)<<3)  [within 64-short windows]
__global__ __launch_bounds__(256) void prep_all(
    const float* __restrict__ x,  const float* __restrict__ W1,
    const float* __restrict__ W2, const float* __restrict__ al1,
    const float* __restrict__ ar1, const float* __restrict__ b1,
    const float* __restrict__ b2,
    short* __restrict__ xb, short* __restrict__ W1d, short* __restrict__ W2t,
    float* __restrict__ wvec1, float* __restrict__ beff1, float* __restrict__ beff2)
{
  const int blk = blockIdx.x;
  const int t = threadIdx.x;
  if (blk < 6250) {                                   // x -> bf16
    int i = (blk * 256 + t) * 4;
    float4 v = *(const float4*)&x[i];
    short4 o = {f2bf(v.x), f2bf(v.y), f2bf(v.z), f2bf(v.w)};
    *(short4*)&xb[i] = o;
  } else if (blk < 7018) {                            // W1d[n][kpos], k<768
    int o = (blk - 6250) * 256 + t;
    if (o < HD * 2 * NREL * FIN) {
      int n = o / (2 * NREL * FIN);
      int kpos = o - n * (2 * NREL * FIN);
      int ke = kpos ^ ((n & 7) << 3);                 // element for this slot
      int k2 = (ke < NREL * FIN) ? ke : ke - NREL * FIN;
      int r = k2 / FIN, kk = k2 - r * FIN;
      W1d[o] = f2bf(W1[((size_t)r * FIN + kk) * HD + n]);
    }
  } else if (blk < 7402) {                            // W2t[r][n][kpos]
    int o = (blk - 7018) * 256 + t;
    if (o < NREL * FIN * HD) {
      int r = o / (FIN * HD);
      int rem = o - r * (FIN * HD);
      int n = rem / HD, kpos = rem - n * HD;
      int ke = kpos ^ ((n & 7) << 3);
      W2t[o] = f2bf(W2[((size_t)r * HD + ke) * FIN + n]);
    }
  } else if (blk < 7594) {                            // wvec1[j][k] = W1_r[k,:]·v
    int wid = (blk - 7402) * 4 + (t >> 6);
    int lane = t & 63;
    if (wid < 6 * FIN) {
      int j = wid / FIN, k = wid - j * FIN;
      int side = j / 3, r = j - side * 3;
      const float* v  = (side ? ar1 : al1) + r * HD;
      const float* Wr = W1 + ((size_t)r * FIN + k) * HD;
      float s = 0.f;
      for (int n = lane; n < HD; n += 64) s += Wr[n] * v[n];
#pragma unroll
      for (int off = 32; off > 0; off >>= 1) s += __shfl_down(s, off);
      if (lane == 0) wvec1[wid] = s;
    }
  } else {                                            // beff
    int t2 = (blk - 7594) * 256 + t;
    if (t2 < HD) beff1[t2] = (b1[t2] + b1[HD + t2] + b1[2 * HD + t2]) * (1.f / 3.f);
    else if (t2 < HD + FIN) {
      int k = t2 - HD;
      beff2[k] = (b2[k] + b2[FIN + k] + b2[2 * FIN + k]) * (1.f / 3.f);
    }
  }
}

// ------- el/er for layer 1: d[j] = xb[i,:]·wvec1[j,:], j<6 ----------------
__global__ __launch_bounds__(256) void rowdot6(
    const short* __restrict__ feat, const float* __restrict__ wvec,
    float* __restrict__ el, float* __restrict__ er)
{
  const int lane = threadIdx.x & 63;
  const int node = blockIdx.x * 4 + (threadIdx.x >> 6);
  if (node >= NN) return;
  bf16x2 f16 = *(const bf16x2*)&feat[(size_t)node * FIN + lane * 2];
  float f0 = bf2f(f16[0]), f1 = bf2f(f16[1]);
  float d[6];
#pragma unroll
  for (int j = 0; j < 6; ++j)
    d[j] = f0 * wvec[j * FIN + lane * 2] + f1 * wvec[j * FIN + lane * 2 + 1];
#pragma unroll
  for (int off = 32; off > 0; off >>= 1)
#pragma unroll
    for (int j = 0; j < 6; ++j) d[j] += __shfl_xor(d[j], off);
  if (lane == 0) {
    el[0 * NN + node] = d[0]; el[1 * NN + node] = d[1]; el[2 * NN + node] = d[2];
    er[0 * NN + node] = d[3]; er[1 * NN + node] = d[4]; er[2 * NN + node] = d[5];
  }
}

// ------------- CSR build: degree count ------------------------------------
__global__ __launch_bounds__(256) void count_deg(
    const int* __restrict__ edges, int* __restrict__ deg)
{
  int tid = blockIdx.x * blockDim.x + threadIdx.x;
  if (tid >= NREL * NE) return;
  int r = tid / NE;
  int e = tid - r * NE;
  int d = edges[(size_t)r * 2 * NE + NE + e];
  atomicAdd(&deg[r * NN + d], 1);
}

// ------------- CSR scan phase 1 -------------------------------------------
__global__ __launch_bounds__(256) void deg_partial(
    const int* __restrict__ deg, int* __restrict__ psum)
{
  const int b = blockIdx.x;
  const int t = threadIdx.x;
  int4 v = {0, 0, 0, 0};
  if (t < 250) v = *(const int4*)&deg[b * 1000 + t * 4];
  int s = v.x + v.y + v.z + v.w;
#pragma unroll
  for (int off = 32; off > 0; off >>= 1) s += __shfl_down(s, off);
  __shared__ int ws[4];
  if ((t & 63) == 0) ws[t >> 6] = s;
  __syncthreads();
  if (t == 0) psum[b] = ws[0] + ws[1] + ws[2] + ws[3];
}

// ------------- CSR scan phase 2 -------------------------------------------
__global__ __launch_bounds__(256) void scan_psum(
    const int* __restrict__ psum, int* __restrict__ pexcl)
{
  __shared__ int lds[256];
  const int t = threadIdx.x;
  int v = (t < 150) ? psum[t] : 0;
  lds[t] = v;
  __syncthreads();
  for (int off = 1; off < 256; off <<= 1) {
    int add = (t >= off) ? lds[t - off] : 0;
    __syncthreads();
    lds[t] += add;
    __syncthreads();
  }
  if (t < 150) pexcl[t] = lds[t] - v;
}

// ------------- CSR scan phase 3: row_ptr + cursor init --------------------
__global__ __launch_bounds__(256) void deg_rowptr(
    const int* __restrict__ deg, const int* __restrict__ pexcl,
    int* __restrict__ row_ptr, int* __restrict__ cursor)
{
  const int b = blockIdx.x;
  const int t = threadIdx.x;
  int4 v = {0, 0, 0, 0};
  if (t < 250) v = *(const int4*)&deg[b * 1000 + t * 4];
  int s = v.x + v.y + v.z + v.w;
  __shared__ int lds[256];
  lds[t] = s;
  __syncthreads();
  for (int off = 1; off < 256; off <<= 1) {
    int add = (t >= off) ? lds[t - off] : 0;
    __syncthreads();
    lds[t] += add;
    __syncthreads();
  }
  int run = lds[t] - s + pexcl[b];
  if (t < 250) {
    int i = b * 1000 + t * 4;
    row_ptr[i] = run;     cursor[i] = run;     run += v.x;
    row_ptr[i + 1] = run; cursor[i + 1] = run; run += v.y;
    row_ptr[i + 2] = run; cursor[i + 2] = run; run += v.z;
    row_ptr[i + 3] = run; cursor[i + 3] = run;
  }
  if (b == 0 && t == 0) row_ptr[NREL * NN] = NREL * NE;
}

// ------------- CSR build: fill src lists ----------------------------------
__global__ __launch_bounds__(256) void fill_csr(
    const int* __restrict__ edges, int* __restrict__ cursor,
    int* __restrict__ csr_src)
{
  int tid = blockIdx.x * blockDim.x + threadIdx.x;
  if (tid >= NREL * NE) return;
  int r = tid / NE;
  int e = tid - r * NE;
  const int* base = edges + (size_t)r * 2 * NE;
  int s = base[e];
  int d = base[NE + e];
  int pos = atomicAdd(&cursor[r * NN + d], 1);
  csr_src[pos] = s;
}

// ------- L1: input-space fused 3-relation gather, 16 lanes per node -------
// 4 nodes/wave; each lane owns 8 channels (no facc reduction).
// A1 rows written PRE-SWIZZLED: element (node,k) at k ^ ((node&7)<<3).
__global__ __launch_bounds__(256) void gat_gather_hl(
    const int* __restrict__ row_ptr, const int* __restrict__ csr_src,
    const float* __restrict__ el, const float* __restrict__ er,
    const short* __restrict__ xb,       // [NN][FIN] bf16
    short* __restrict__ A1)             // [NN][768] bf16, swizzled
{
  const int lane  = threadIdx.x & 63;
  const int cl    = lane & 15;
  const int gbase = lane & 48;
  const int node  = blockIdx.x * 16 + (threadIdx.x >> 6) * 4 + (lane >> 4);
  if (node >= NN) return;
  const int sw = (node & 7) << 3;
  const size_t rowbase = (size_t)node * (2 * NREL * FIN);

#pragma unroll
  for (int r = 0; r < NREL; ++r) {
    const int beg = row_ptr[r * NN + node];
    const int end = row_ptr[r * NN + node + 1];
    const float eri = er[r * NN + node];
    const float* elr = el + r * NN;

    float dsum = 0.f;
    float f[8];
#pragma unroll
    for (int k = 0; k < 8; ++k) f[k] = 0.f;

    for (int chunk = beg; chunk < end; chunk += 16) {
      int e = chunk + cl;
      int sidx = 0; float a = 0.f;
      if (e < end) {
        sidx = csr_src[e];
        float tv = elr[sidx] + eri;
        tv = tv > 0.f ? tv : SLOPE * tv;
        a = __expf(tv);
      }
      dsum += a;
      const int cnt = (end - chunk < 16) ? end - chunk : 16;
      for (int i = 0; i < cnt; ++i) {
        float aj = __shfl(a, gbase + i);
        int   sj = __shfl(sidx, gbase + i);
        bf16x8 v = *(const bf16x8*)&xb[(size_t)sj * FIN + cl * 8];
#pragma unroll
        for (int k = 0; k < 8; ++k) f[k] = fmaf(bf2f(v[k]), aj, f[k]);
      }
    }
#pragma unroll
    for (int off = 8; off > 0; off >>= 1) dsum += __shfl_xor(dsum, off);
    const float inv = 1.f / (3.f * fmaxf(dsum, 1e-9f));

    bf16x8 hi, lo;
#pragma unroll
    for (int k = 0; k < 8; ++k) {
      float av = f[k] * inv;
      short hh = f2bf(av);
      hi[k] = hh;
      lo[k] = f2bf(av - bf2f(hh));
    }
    int u = (r * FIN + cl * 8) ^ sw;       // swizzled within 64-short window
    *(bf16x8*)&A1[rowbase + u] = hi;
    *(bf16x8*)&A1[rowbase + NREL * FIN + u] = lo;
  }
}

// ------- L1 GEMM v3: hb = relu(A1@W1d^T + beff1), global_load_lds staged --
// BM=64, BN=128 (grid y=2), BK=64. A,B both LDS. hb written PRE-SWIZZLED.
__global__ __launch_bounds__(256) void gemm_hl(
    const short* __restrict__ A, const short* __restrict__ Bt,
    const float* __restrict__ beff, short* __restrict__ hb, int M)
{
  constexpr int K = 2 * NREL * FIN;    // 768
  constexpr int BK = 64;
  __shared__ __align__(16) short AsB[(64 + 128) * BK];  // 24 KB
  short* As = AsB;
  short* Bs = AsB + 64 * BK;
  const int tid  = threadIdx.x;
  const int lane = tid & 63;
  const int wave = tid >> 6;
  const int m0  = blockIdx.x * 64;
  const int n00 = blockIdx.y * 128;
  const int c    = lane & 15;
  const int rgrp = lane >> 4;
  const int wbase = tid & ~63;         // wave-uniform chunk base

  f32x4 acc[4][2] = {};
  for (int k0 = 0; k0 < K; k0 += BK) {
    __syncthreads();
#pragma unroll
    for (int q = 0; q < 2; ++q) {      // A: 512 chunks
      int idx = q * 256 + tid;
      int row = idx >> 3, ch = idx & 7;
      int gr = m0 + row; gr = gr < M ? gr : M - 1;
      gload16(&A[(size_t)gr * K + k0 + ch * 8], As + (q * 256 + wbase) * 8);
    }
#pragma unroll
    for (int q = 0; q < 4; ++q) {      // B: 1024 chunks
      int jdx = q * 256 + tid;
      int col = jdx >> 3, ch = jdx & 7;
      gload16(&Bt[(size_t)(n00 + col) * K + k0 + ch * 8], Bs + (q * 256 + wbase) * 8);
    }
    __syncthreads();
#pragma unroll
    for (int ks = 0; ks < 2; ++ks) {
      const int ko = (ks * 32 + rgrp * 8) ^ ((c & 7) << 3);  // de-swizzle
      bf16x8 a[4], b[2];
#pragma unroll
      for (int i = 0; i < 4; ++i)
        a[i] = *(const bf16x8*)&As[(i * 16 + c) * BK + ko];
#pragma unroll
      for (int j = 0; j < 2; ++j)
        b[j] = *(const bf16x8*)&Bs[(wave * 32 + j * 16 + c) * BK + ko];
#pragma unroll
      for (int i = 0; i < 4; ++i)
#pragma unroll
        for (int j = 0; j < 2; ++j)
          acc[i][j] = __builtin_amdgcn_mfma_f32_16x16x32_bf16(a[i], b[j], acc[i][j], 0, 0, 0);
    }
  }
#pragma unroll
  for (int i = 0; i < 4; ++i)
#pragma unroll
    for (int v = 0; v < 4; ++v) {
      int row = m0 + i * 16 + rgrp * 4 + v;
      if (row < M) {
        int srow = (row & 7) << 3;
#pragma unroll
        for (int j = 0; j < 2; ++j) {
          int col = n00 + wave * 32 + j * 16 + c;
          hb[(size_t)row * HD + (col ^ srow)] =
              f2bf(fmaxf(acc[i][j][v] + beff[col], 0.f));
        }
      }
    }
}

// ---- L2 GEMM v3: featb[r] = hb @ W2t[r]^T + el/er epilogue ---------------
// BM=64, BN=128 (full N), BK=64, grid y=3. hb/W2t are pre-swizzled.
__global__ __launch_bounds__(256) void gemm_fused2(
    const short* __restrict__ A, const short* __restrict__ Wt,
    const float* __restrict__ al, const float* __restrict__ ar,
    short* __restrict__ featb, float* __restrict__ el, float* __restrict__ er,
    int M)
{
  constexpr int K = HD;                // 256
  constexpr int BK = 64;
  constexpr int N_ = FIN;              // 128
  __shared__ __align__(16) short AsB[(64 + 128) * BK];  // 24 KB
  __shared__ float2 part[4][64];
  short* As = AsB;
  short* Bs = AsB + 64 * BK;
  const int r = blockIdx.y;
  const short* Bt  = Wt + (size_t)r * N_ * K;
  const float* alr = al + r * N_;
  const float* arr = ar + r * N_;
  short* fb  = featb + (size_t)r * M * N_;
  float* elr = el + r * NN;
  float* err = er + r * NN;

  const int tid  = threadIdx.x;
  const int lane = tid & 63;
  const int wave = tid >> 6;
  const int m0 = blockIdx.x * 64;
  const int c    = lane & 15;
  const int rgrp = lane >> 4;
  const int wbase = tid & ~63;

  f32x4 acc[4][2] = {};
  for (int k0 = 0; k0 < K; k0 += BK) {
    __syncthreads();
#pragma unroll
    for (int q = 0; q < 2; ++q) {
      int idx = q * 256 + tid;
      int row = idx >> 3, ch = idx & 7;
      int gr = m0 + row; gr = gr < M ? gr : M - 1;
      gload16(&A[(size_t)gr * K + k0 + ch * 8], As + (q * 256 + wbase) * 8);
    }
#pragma unroll
    for (int q = 0; q < 4; ++q) {
      int jdx = q * 256 + tid;
      int col = jdx >> 3, ch = jdx & 7;
      gload16(&Bt[(size_t)col * K + k0 + ch * 8], Bs + (q * 256 + wbase) * 8);
    }
    __syncthreads();
#pragma unroll
    for (int ks = 0; ks < 2; ++ks) {
      const int ko = (ks * 32 + rgrp * 8) ^ ((c & 7) << 3);
      bf16x8 a[4], b[2];
#pragma unroll
      for (int i = 0; i < 4; ++i)
        a[i] = *(const bf16x8*)&As[(i * 16 + c) * BK + ko];
#pragma unroll
      for (int j = 0; j < 2; ++j)
        b[j] = *(const bf16x8*)&Bs[(wave * 32 + j * 16 + c) * BK + ko];
#pragma unroll
      for (int i = 0; i < 4; ++i)
#pragma unroll
        for (int j = 0; j < 2; ++j)
          acc[i][j] = __builtin_amdgcn_mfma_f32_16x16x32_bf16(a[i], b[j], acc[i][j], 0, 0, 0);
    }
  }

  // epilogue: featb (bf16, normal layout) + el/er dots
  float pe[4][4], pr[4][4];
#pragma unroll
  for (int i = 0; i < 4; ++i)
#pragma unroll
    for (int v = 0; v < 4; ++v) {
      float se = 0.f, sr = 0.f;
#pragma unroll
      for (int j = 0; j < 2; ++j) {
        float av = acc[i][j][v];
        int col = wave * 32 + j * 16 + c;
        se = fmaf(av, alr[col], se);
        sr = fmaf(av, arr[col], sr);
      }
      pe[i][v] = se; pr[i][v] = sr;
    }
#pragma unroll
  for (int i = 0; i < 4; ++i)
#pragma unroll
    for (int v = 0; v < 4; ++v) {
      int row = m0 + i * 16 + rgrp * 4 + v;
      if (row < M) {
#pragma unroll
        for (int j = 0; j < 2; ++j)
          fb[(size_t)row * N_ + wave * 32 + j * 16 + c] = f2bf(acc[i][j][v]);
      }
#pragma unroll
      for (int off = 1; off < 16; off <<= 1) {
        pe[i][v] += __shfl_xor(pe[i][v], off);
        pr[i][v] += __shfl_xor(pr[i][v], off);
      }
    }
  if (c == 0) {
#pragma unroll
    for (int i = 0; i < 4; ++i)
#pragma unroll
      for (int v = 0; v < 4; ++v)
        part[wave][i * 16 + rgrp * 4 + v] = make_float2(pe[i][v], pr[i][v]);
  }
  __syncthreads();
  if (tid < 64) {
    float se = 0.f, sr = 0.f;
#pragma unroll
    for (int w = 0; w < 4; ++w) { se += part[w][tid].x; sr += part[w][tid].y; }
    int row = m0 + tid;
    if (row < M) { elr[row] = se; err[row] = sr; }
  }
}

// ---- L2: projected-space gather + relu + predictor dots, 16 lanes/node ---
__global__ __launch_bounds__(256) void gat_agg_dots(
    const int* __restrict__ row_ptr, const int* __restrict__ csr_src,
    const float* __restrict__ el, const float* __restrict__ er,
    const short* __restrict__ featb,    // [NREL][NN][FIN] bf16 (normal layout)
    const float* __restrict__ beff,     // [FIN]
    const float* __restrict__ Wlin,     // [2*FIN]
    float* __restrict__ dotl, float* __restrict__ dotr)
{
  const int lane  = threadIdx.x & 63;
  const int cl    = lane & 15;
  const int gbase = lane & 48;
  const int node  = blockIdx.x * 16 + (threadIdx.x >> 6) * 4 + (lane >> 4);
  if (node >= NN) return;

  float t[8];
#pragma unroll
  for (int k = 0; k < 8; ++k) t[k] = 0.f;

#pragma unroll
  for (int r = 0; r < NREL; ++r) {
    const int beg = row_ptr[r * NN + node];
    const int end = row_ptr[r * NN + node + 1];
    const float eri = er[r * NN + node];
    const float* elr = el + r * NN;
    const short* fb  = featb + (size_t)r * NN * FIN;

    float dsum = 0.f;
    float f[8];
#pragma unroll
    for (int k = 0; k < 8; ++k) f[k] = 0.f;

    for (int chunk = beg; chunk < end; chunk += 16) {
      int e = chunk + cl;
      int sidx = 0; float a = 0.f;
      if (e < end) {
        sidx = csr_src[e];
        float tv = elr[sidx] + eri;
        tv = tv > 0.f ? tv : SLOPE * tv;
        a = __expf(tv);
      }
      dsum += a;
      const int cnt = (end - chunk < 16) ? end - chunk : 16;
      for (int i = 0; i < cnt; ++i) {
        float aj = __shfl(a, gbase + i);
        int   sj = __shfl(sidx, gbase + i);
        bf16x8 v = *(const bf16x8*)&fb[(size_t)sj * FIN + cl * 8];
#pragma unroll
        for (int k = 0; k < 8; ++k) f[k] = fmaf(bf2f(v[k]), aj, f[k]);
      }
    }
#pragma unroll
    for (int off = 8; off > 0; off >>= 1) dsum += __shfl_xor(dsum, off);
    const float inv = 1.f / (3.f * fmaxf(dsum, 1e-9f));
#pragma unroll
    for (int k = 0; k < 8; ++k) t[k] = fmaf(f[k], inv, t[k]);
  }

  const int c = cl * 8;
  float dl = 0.f, dr = 0.f;
#pragma unroll
  for (int k = 0; k < 8; ++k) {
    float g = fmaxf(t[k] + beff[c + k], 0.f);
    dl = fmaf(g, Wlin[c + k], dl);
    dr = fmaf(g, Wlin[FIN + c + k], dr);
  }
#pragma unroll
  for (int off = 8; off > 0; off >>= 1) {
    dl += __shfl_xor(dl, off);
    dr += __shfl_xor(dr, off);
  }
  if (cl == 0) { dotl[node] = dl; dotr[node] = dr; }
}

// ------------- pair logits -------------------------------------------------
__global__ __launch_bounds__(256) void pair_out(
    const int* __restrict__ edges, const int* __restrict__ n_pairs,
    const float* __restrict__ dotl, const float* __restrict__ dotr,
    const float* __restrict__ blin, float* __restrict__ out)
{
  const int TOT = NREL * NE + NP;
  int p = blockIdx.x * blockDim.x + threadIdx.x;
  if (p >= TOT) return;
  int s, d;
  if (p < NREL * NE) {
    int r = p / NE;
    int e = p - r * NE;
    const int* base = edges + (size_t)r * 2 * NE;
    s = base[e];
    d = base[NE + e];
  } else {
    int q = p - NREL * NE;
    s = n_pairs[2 * q];
    d = n_pairs[2 * q + 1];
  }
  float logit = dotl[s] + dotr[d] + blin[0];
  out[p] = 1.f / (1.f + expf(-logit));
}

extern "C" void kernel_launch(void* const* d_in, const int* in_sizes, int n_in,
                              void* d_out, int out_size, void* d_ws, size_t ws_size,
                              hipStream_t stream) {
  const float* x      = (const float*)d_in[0];
  const int*   edges  = (const int*)d_in[1];
  const int*   npairs = (const int*)d_in[2];
  const float* W1     = (const float*)d_in[3];
  const float* al1    = (const float*)d_in[4];
  const float* ar1    = (const float*)d_in[5];
  const float* b1     = (const float*)d_in[6];
  const float* W2     = (const float*)d_in[7];
  const float* al2    = (const float*)d_in[8];
  const float* ar2    = (const float*)d_in[9];
  const float* b2     = (const float*)d_in[10];
  const float* Wlin   = (const float*)d_in[11];
  const float* blin   = (const float*)d_in[12];
  float* out = (float*)d_out;

  char* w = (char*)d_ws;
  size_t off = 0;
  auto alloc = [&](size_t bytes) {
    char* p = w + off;
    off = (off + bytes + 255) & ~(size_t)255;
    return p;
  };
  short* xb      = (short*)alloc((size_t)NN * FIN * 2);
  short* hb      = (short*)alloc((size_t)NN * HD * 2);
  short* A1      = (short*)alloc((size_t)NN * 2 * NREL * FIN * 2);
  short* featb2  = A1;   // aliased: A1 dead after gemm_hl
  short* W1d     = (short*)alloc((size_t)HD * 2 * NREL * FIN * 2);
  short* W2t     = (short*)alloc((size_t)NREL * FIN * HD * 2);
  float* wvec1   = (float*)alloc(6 * FIN * 4);
  float* beff1   = (float*)alloc(HD * 4);
  float* beff2   = (float*)alloc(FIN * 4);
  float* el      = (float*)alloc((size_t)NREL * NN * 4);
  float* er      = (float*)alloc((size_t)NREL * NN * 4);
  float* dotl    = (float*)alloc((size_t)NN * 4);
  float* dotr    = (float*)alloc((size_t)NN * 4);
  int*   deg     = (int*)  alloc((size_t)NREL * NN * 4);
  int*   cursor  = (int*)  alloc((size_t)NREL * NN * 4);
  int*   row_ptr = (int*)  alloc((size_t)(NREL * NN + 16) * 4);
  int*   psum    = (int*)  alloc(1024);
  int*   pexcl   = (int*)  alloc(1024);
  int*   csr_src = (int*)  alloc((size_t)NREL * NE * 4);

  const int B = 256;

  // ---------------- prep (1 kernel) ---------------------------------------
  prep_all<<<7596, B, 0, stream>>>(x, W1, W2, al1, ar1, b1, b2,
                                   xb, W1d, W2t, wvec1, beff1, beff2);

  // ---------------- CSR build ---------------------------------------------
  hipMemsetAsync(deg, 0, (size_t)NREL * NN * 4, stream);
  count_deg<<<(NREL * NE + B - 1) / B, B, 0, stream>>>(edges, deg);
  deg_partial<<<150, B, 0, stream>>>(deg, psum);
  scan_psum<<<1, B, 0, stream>>>(psum, pexcl);
  deg_rowptr<<<150, B, 0, stream>>>(deg, pexcl, row_ptr, cursor);
  fill_csr<<<(NREL * NE + B - 1) / B, B, 0, stream>>>(edges, cursor, csr_src);

  const int AGG_G  = (NN + 3) / 4;
  const int AGG16  = (NN + 15) / 16;    // 3125
  const int GEMM_GX = (NN + 63) / 64;   // 782

  // ---------------- layer 1: scores, input-space gather, GEMM -> hb -------
  rowdot6<<<AGG_G, B, 0, stream>>>(xb, wvec1, el, er);
  gat_gather_hl<<<AGG16, B, 0, stream>>>(row_ptr, csr_src, el, er, xb, A1);
  {
    dim3 g(GEMM_GX, 2);
    gemm_hl<<<g, B, 0, stream>>>(A1, W1d, beff1, hb, NN);
  }

  // ---------------- layer 2: project, gather+dots -------------------------
  {
    dim3 g(GEMM_GX, NREL);
    gemm_fused2<<<g, B, 0, stream>>>(hb, W2t, al2, ar2, featb2, el, er, NN);
  }
  gat_agg_dots<<<AGG16, B, 0, stream>>>(row_ptr, csr_src, el, er, featb2,
                                        beff2, Wlin, dotl, dotr);

  // ---------------- pair predictor ----------------------------------------
  const int TOT = NREL * NE + NP;
  pair_out<<<(TOT + B - 1) / B, B, 0, stream>>>(edges, npairs, dotl, dotr, blin, out);
}

// Round 13
// 257.258 us; speedup vs baseline: 1.6043x; 1.0712x over previous
//
#include <hip/hip_runtime.h>
#include <cstddef>

#define NN 50000
#define NREL 3
#define NE 250000
#define NP 100000
#define FIN 128
#define HD 256
#define SLOPE 0.2f
#define K1 (NREL * FIN)          // 384

typedef short bf16x8 __attribute__((ext_vector_type(8)));
typedef short bf16x2 __attribute__((ext_vector_type(2)));
typedef float f32x4 __attribute__((ext_vector_type(4)));
typedef _Float16 half8 __attribute__((ext_vector_type(8)));

__device__ __forceinline__ short f2bf(float f) {
  unsigned u = __float_as_uint(f);
  unsigned r = (u + 0x7FFFu + ((u >> 16) & 1u)) >> 16;   // RNE
  return (short)r;
}
__device__ __forceinline__ float bf2f(short s) {
  return __uint_as_float(((unsigned)(unsigned short)s) << 16);
}

// async global->LDS, 16 bytes per lane; lds ptr must be wave-uniform base.
__device__ __forceinline__ void gload16(const short* g, short* l) {
  __builtin_amdgcn_global_load_lds(
      (const __attribute__((address_space(1))) unsigned int*)g,
      (__attribute__((address_space(3))) unsigned int*)l, 16, 0, 0);
}

// ---------------- fused prep: xb, W1d (f16, PRE-SWIZZLED), W2t, wvec1 -----
// swizzle: element (n,k) stored at k ^ ((n&7)<<3)  [within 64-short windows]
// ranges: [0,6250) xconv | [6250,6634) W1d | [6634,7018) W2t
//         [7018,7210) wvec1 | [7210,7212) beff
__global__ __launch_bounds__(256) void prep_all(
    const float* __restrict__ x,  const float* __restrict__ W1,
    const float* __restrict__ W2, const float* __restrict__ al1,
    const float* __restrict__ ar1, const float* __restrict__ b1,
    const float* __restrict__ b2,
    short* __restrict__ xb, short* __restrict__ W1d, short* __restrict__ W2t,
    float* __restrict__ wvec1, float* __restrict__ beff1, float* __restrict__ beff2)
{
  const int blk = blockIdx.x;
  const int t = threadIdx.x;
  if (blk < 6250) {                                   // x -> bf16
    int i = (blk * 256 + t) * 4;
    float4 v = *(const float4*)&x[i];
    short4 o = {f2bf(v.x), f2bf(v.y), f2bf(v.z), f2bf(v.w)};
    *(short4*)&xb[i] = o;
  } else if (blk < 6634) {                            // W1d[n][kpos] f16, k<384
    int o = (blk - 6250) * 256 + t;
    int n = o / K1;
    int kpos = o - n * K1;
    int ke = kpos ^ ((n & 7) << 3);                   // element for this slot
    int r = ke / FIN, kk = ke - r * FIN;
    ((_Float16*)W1d)[o] = (_Float16)W1[((size_t)r * FIN + kk) * HD + n];
  } else if (blk < 7018) {                            // W2t[r][n][kpos] bf16
    int o = (blk - 6634) * 256 + t;
    int r = o / (FIN * HD);
    int rem = o - r * (FIN * HD);
    int n = rem / HD, kpos = rem - n * HD;
    int ke = kpos ^ ((n & 7) << 3);
    W2t[o] = f2bf(W2[((size_t)r * HD + ke) * FIN + n]);
  } else if (blk < 7210) {                            // wvec1[j][k] = W1_r[k,:]·v
    int wid = (blk - 7018) * 4 + (t >> 6);
    int lane = t & 63;
    if (wid < 6 * FIN) {
      int j = wid / FIN, k = wid - j * FIN;
      int side = j / 3, r = j - side * 3;
      const float* v  = (side ? ar1 : al1) + r * HD;
      const float* Wr = W1 + ((size_t)r * FIN + k) * HD;
      float s = 0.f;
      for (int n = lane; n < HD; n += 64) s += Wr[n] * v[n];
#pragma unroll
      for (int off = 32; off > 0; off >>= 1) s += __shfl_down(s, off);
      if (lane == 0) wvec1[wid] = s;
    }
  } else {                                            // beff
    int t2 = (blk - 7210) * 256 + t;
    if (t2 < HD) beff1[t2] = (b1[t2] + b1[HD + t2] + b1[2 * HD + t2]) * (1.f / 3.f);
    else if (t2 < HD + FIN) {
      int k = t2 - HD;
      beff2[k] = (b2[k] + b2[FIN + k] + b2[2 * FIN + k]) * (1.f / 3.f);
    }
  }
}

// ------- el/er for layer 1: d[j] = xb[i,:]·wvec1[j,:], j<6 ----------------
__global__ __launch_bounds__(256) void rowdot6(
    const short* __restrict__ feat, const float* __restrict__ wvec,
    float* __restrict__ el, float* __restrict__ er)
{
  const int lane = threadIdx.x & 63;
  const int node = blockIdx.x * 4 + (threadIdx.x >> 6);
  if (node >= NN) return;
  bf16x2 f16 = *(const bf16x2*)&feat[(size_t)node * FIN + lane * 2];
  float f0 = bf2f(f16[0]), f1 = bf2f(f16[1]);
  float d[6];
#pragma unroll
  for (int j = 0; j < 6; ++j)
    d[j] = f0 * wvec[j * FIN + lane * 2] + f1 * wvec[j * FIN + lane * 2 + 1];
#pragma unroll
  for (int off = 32; off > 0; off >>= 1)
#pragma unroll
    for (int j = 0; j < 6; ++j) d[j] += __shfl_xor(d[j], off);
  if (lane == 0) {
    el[0 * NN + node] = d[0]; el[1 * NN + node] = d[1]; el[2 * NN + node] = d[2];
    er[0 * NN + node] = d[3]; er[1 * NN + node] = d[4]; er[2 * NN + node] = d[5];
  }
}

// ------------- CSR build: degree count ------------------------------------
__global__ __launch_bounds__(256) void count_deg(
    const int* __restrict__ edges, int* __restrict__ deg)
{
  int tid = blockIdx.x * blockDim.x + threadIdx.x;
  if (tid >= NREL * NE) return;
  int r = tid / NE;
  int e = tid - r * NE;
  int d = edges[(size_t)r * 2 * NE + NE + e];
  atomicAdd(&deg[r * NN + d], 1);
}

// ------------- CSR scan phase 1 -------------------------------------------
__global__ __launch_bounds__(256) void deg_partial(
    const int* __restrict__ deg, int* __restrict__ psum)
{
  const int b = blockIdx.x;
  const int t = threadIdx.x;
  int4 v = {0, 0, 0, 0};
  if (t < 250) v = *(const int4*)&deg[b * 1000 + t * 4];
  int s = v.x + v.y + v.z + v.w;
#pragma unroll
  for (int off = 32; off > 0; off >>= 1) s += __shfl_down(s, off);
  __shared__ int ws[4];
  if ((t & 63) == 0) ws[t >> 6] = s;
  __syncthreads();
  if (t == 0) psum[b] = ws[0] + ws[1] + ws[2] + ws[3];
}

// ------------- CSR scan phase 2 -------------------------------------------
__global__ __launch_bounds__(256) void scan_psum(
    const int* __restrict__ psum, int* __restrict__ pexcl)
{
  __shared__ int lds[256];
  const int t = threadIdx.x;
  int v = (t < 150) ? psum[t] : 0;
  lds[t] = v;
  __syncthreads();
  for (int off = 1; off < 256; off <<= 1) {
    int add = (t >= off) ? lds[t - off] : 0;
    __syncthreads();
    lds[t] += add;
    __syncthreads();
  }
  if (t < 150) pexcl[t] = lds[t] - v;
}

// ------------- CSR scan phase 3: row_ptr + cursor init --------------------
__global__ __launch_bounds__(256) void deg_rowptr(
    const int* __restrict__ deg, const int* __restrict__ pexcl,
    int* __restrict__ row_ptr, int* __restrict__ cursor)
{
  const int b = blockIdx.x;
  const int t = threadIdx.x;
  int4 v = {0, 0, 0, 0};
  if (t < 250) v = *(const int4*)&deg[b * 1000 + t * 4];
  int s = v.x + v.y + v.z + v.w;
  __shared__ int lds[256];
  lds[t] = s;
  __syncthreads();
  for (int off = 1; off < 256; off <<= 1) {
    int add = (t >= off) ? lds[t - off] : 0;
    __syncthreads();
    lds[t] += add;
    __syncthreads();
  }
  int run = lds[t] - s + pexcl[b];
  if (t < 250) {
    int i = b * 1000 + t * 4;
    row_ptr[i] = run;     cursor[i] = run;     run += v.x;
    row_ptr[i + 1] = run; cursor[i + 1] = run; run += v.y;
    row_ptr[i + 2] = run; cursor[i + 2] = run; run += v.z;
    row_ptr[i + 3] = run; cursor[i + 3] = run;
  }
  if (b == 0 && t == 0) row_ptr[NREL * NN] = NREL * NE;
}

// ------------- CSR build: fill src lists ----------------------------------
__global__ __launch_bounds__(256) void fill_csr(
    const int* __restrict__ edges, int* __restrict__ cursor,
    int* __restrict__ csr_src)
{
  int tid = blockIdx.x * blockDim.x + threadIdx.x;
  if (tid >= NREL * NE) return;
  int r = tid / NE;
  int e = tid - r * NE;
  const int* base = edges + (size_t)r * 2 * NE;
  int s = base[e];
  int d = base[NE + e];
  int pos = atomicAdd(&cursor[r * NN + d], 1);
  csr_src[pos] = s;
}

// ------- L1: input-space fused 3-relation gather, 16 lanes per node -------
// 4 nodes/wave; each lane owns 8 channels. A1 written as fp16, PRE-SWIZZLED:
// element (node,k) at k ^ ((node&7)<<3).
__global__ __launch_bounds__(256) void gat_gather_hl(
    const int* __restrict__ row_ptr, const int* __restrict__ csr_src,
    const float* __restrict__ el, const float* __restrict__ er,
    const short* __restrict__ xb,       // [NN][FIN] bf16
    short* __restrict__ A1)             // [NN][384] f16, swizzled
{
  const int lane  = threadIdx.x & 63;
  const int cl    = lane & 15;
  const int gbase = lane & 48;
  const int node  = blockIdx.x * 16 + (threadIdx.x >> 6) * 4 + (lane >> 4);
  if (node >= NN) return;
  const int sw = (node & 7) << 3;
  const size_t rowbase = (size_t)node * K1;

#pragma unroll
  for (int r = 0; r < NREL; ++r) {
    const int beg = row_ptr[r * NN + node];
    const int end = row_ptr[r * NN + node + 1];
    const float eri = er[r * NN + node];
    const float* elr = el + r * NN;

    float dsum = 0.f;
    float f[8];
#pragma unroll
    for (int k = 0; k < 8; ++k) f[k] = 0.f;

    for (int chunk = beg; chunk < end; chunk += 16) {
      int e = chunk + cl;
      int sidx = 0; float a = 0.f;
      if (e < end) {
        sidx = csr_src[e];
        float tv = elr[sidx] + eri;
        tv = tv > 0.f ? tv : SLOPE * tv;
        a = __expf(tv);
      }
      dsum += a;
      const int cnt = (end - chunk < 16) ? end - chunk : 16;
      for (int i = 0; i < cnt; ++i) {
        float aj = __shfl(a, gbase + i);
        int   sj = __shfl(sidx, gbase + i);
        bf16x8 v = *(const bf16x8*)&xb[(size_t)sj * FIN + cl * 8];
#pragma unroll
        for (int k = 0; k < 8; ++k) f[k] = fmaf(bf2f(v[k]), aj, f[k]);
      }
    }
#pragma unroll
    for (int off = 8; off > 0; off >>= 1) dsum += __shfl_xor(dsum, off);
    const float inv = 1.f / (3.f * fmaxf(dsum, 1e-9f));

    half8 hv;
#pragma unroll
    for (int k = 0; k < 8; ++k) hv[k] = (_Float16)(f[k] * inv);
    int u = (r * FIN + cl * 8) ^ sw;       // swizzled within 64-short window
    *(half8*)&A1[rowbase + u] = hv;
  }
}

// ------- L1 GEMM: hb = relu(A1@W1d^T + beff1), f16 MFMA, A read ONCE ------
// BM=64, BN=256 (full width, wave=64 cols), BK=64, K=384. LDS 40 KB.
__global__ __launch_bounds__(256) void gemm_hl(
    const short* __restrict__ A, const short* __restrict__ Bt,
    const float* __restrict__ beff, short* __restrict__ hb, int M)
{
  constexpr int BK = 64;
  __shared__ __align__(16) short AsB[(64 + 256) * BK];  // 40 KB
  short* As = AsB;
  short* Bs = AsB + 64 * BK;
  const int tid  = threadIdx.x;
  const int lane = tid & 63;
  const int wave = tid >> 6;
  const int m0 = blockIdx.x * 64;
  const int n0 = wave * 64;
  const int c    = lane & 15;
  const int rgrp = lane >> 4;
  const int wbase = tid & ~63;         // wave-uniform chunk base

  f32x4 acc[4][4] = {};
  for (int k0 = 0; k0 < K1; k0 += BK) {
    __syncthreads();
#pragma unroll
    for (int q = 0; q < 2; ++q) {      // A: 512 chunks
      int idx = q * 256 + tid;
      int row = idx >> 3, ch = idx & 7;
      int gr = m0 + row; gr = gr < M ? gr : M - 1;
      gload16(&A[(size_t)gr * K1 + k0 + ch * 8], As + (q * 256 + wbase) * 8);
    }
#pragma unroll
    for (int q = 0; q < 8; ++q) {      // B: 2048 chunks (256 cols)
      int jdx = q * 256 + tid;
      int col = jdx >> 3, ch = jdx & 7;
      gload16(&Bt[(size_t)col * K1 + k0 + ch * 8], Bs + (q * 256 + wbase) * 8);
    }
    __syncthreads();
#pragma unroll
    for (int ks = 0; ks < 2; ++ks) {
      const int ko = (ks * 32 + rgrp * 8) ^ ((c & 7) << 3);  // de-swizzle
      half8 a[4], b[4];
#pragma unroll
      for (int i = 0; i < 4; ++i)
        a[i] = *(const half8*)&As[(i * 16 + c) * BK + ko];
#pragma unroll
      for (int j = 0; j < 4; ++j)
        b[j] = *(const half8*)&Bs[(n0 + j * 16 + c) * BK + ko];
#pragma unroll
      for (int i = 0; i < 4; ++i)
#pragma unroll
        for (int j = 0; j < 4; ++j)
          acc[i][j] = __builtin_amdgcn_mfma_f32_16x16x32_f16(a[i], b[j], acc[i][j], 0, 0, 0);
    }
  }
#pragma unroll
  for (int i = 0; i < 4; ++i)
#pragma unroll
    for (int v = 0; v < 4; ++v) {
      int row = m0 + i * 16 + rgrp * 4 + v;
      if (row < M) {
        int srow = (row & 7) << 3;
#pragma unroll
        for (int j = 0; j < 4; ++j) {
          int col = n0 + j * 16 + c;
          hb[(size_t)row * HD + (col ^ srow)] =
              f2bf(fmaxf(acc[i][j][v] + beff[col], 0.f));
        }
      }
    }
}

// ---- L2 GEMM: featb[r] = hb @ W2t[r]^T + el/er epilogue (bf16 MFMA) ------
// BM=64, BN=128 (full N), BK=64, grid y=3. hb/W2t are pre-swizzled.
__global__ __launch_bounds__(256) void gemm_fused2(
    const short* __restrict__ A, const short* __restrict__ Wt,
    const float* __restrict__ al, const float* __restrict__ ar,
    short* __restrict__ featb, float* __restrict__ el, float* __restrict__ er,
    int M)
{
  constexpr int K = HD;                // 256
  constexpr int BK = 64;
  constexpr int N_ = FIN;              // 128
  __shared__ __align__(16) short AsB[(64 + 128) * BK];  // 24 KB
  __shared__ float2 part[4][64];
  short* As = AsB;
  short* Bs = AsB + 64 * BK;
  const int r = blockIdx.y;
  const short* Bt  = Wt + (size_t)r * N_ * K;
  const float* alr = al + r * N_;
  const float* arr = ar + r * N_;
  short* fb  = featb + (size_t)r * M * N_;
  float* elr = el + r * NN;
  float* err = er + r * NN;

  const int tid  = threadIdx.x;
  const int lane = tid & 63;
  const int wave = tid >> 6;
  const int m0 = blockIdx.x * 64;
  const int c    = lane & 15;
  const int rgrp = lane >> 4;
  const int wbase = tid & ~63;

  f32x4 acc[4][2] = {};
  for (int k0 = 0; k0 < K; k0 += BK) {
    __syncthreads();
#pragma unroll
    for (int q = 0; q < 2; ++q) {
      int idx = q * 256 + tid;
      int row = idx >> 3, ch = idx & 7;
      int gr = m0 + row; gr = gr < M ? gr : M - 1;
      gload16(&A[(size_t)gr * K + k0 + ch * 8], As + (q * 256 + wbase) * 8);
    }
#pragma unroll
    for (int q = 0; q < 4; ++q) {
      int jdx = q * 256 + tid;
      int col = jdx >> 3, ch = jdx & 7;
      gload16(&Bt[(size_t)col * K + k0 + ch * 8], Bs + (q * 256 + wbase) * 8);
    }
    __syncthreads();
#pragma unroll
    for (int ks = 0; ks < 2; ++ks) {
      const int ko = (ks * 32 + rgrp * 8) ^ ((c & 7) << 3);
      bf16x8 a[4], b[2];
#pragma unroll
      for (int i = 0; i < 4; ++i)
        a[i] = *(const bf16x8*)&As[(i * 16 + c) * BK + ko];
#pragma unroll
      for (int j = 0; j < 2; ++j)
        b[j] = *(const bf16x8*)&Bs[(wave * 32 + j * 16 + c) * BK + ko];
#pragma unroll
      for (int i = 0; i < 4; ++i)
#pragma unroll
        for (int j = 0; j < 2; ++j)
          acc[i][j] = __builtin_amdgcn_mfma_f32_16x16x32_bf16(a[i], b[j], acc[i][j], 0, 0, 0);
    }
  }

  // epilogue: featb (bf16, normal layout) + el/er dots
  float pe[4][4], pr[4][4];
#pragma unroll
  for (int i = 0; i < 4; ++i)
#pragma unroll
    for (int v = 0; v < 4; ++v) {
      float se = 0.f, sr = 0.f;
#pragma unroll
      for (int j = 0; j < 2; ++j) {
        float av = acc[i][j][v];
        int col = wave * 32 + j * 16 + c;
        se = fmaf(av, alr[col], se);
        sr = fmaf(av, arr[col], sr);
      }
      pe[i][v] = se; pr[i][v] = sr;
    }
#pragma unroll
  for (int i = 0; i < 4; ++i)
#pragma unroll
    for (int v = 0; v < 4; ++v) {
      int row = m0 + i * 16 + rgrp * 4 + v;
      if (row < M) {
#pragma unroll
        for (int j = 0; j < 2; ++j)
          fb[(size_t)row * N_ + wave * 32 + j * 16 + c] = f2bf(acc[i][j][v]);
      }
#pragma unroll
      for (int off = 1; off < 16; off <<= 1) {
        pe[i][v] += __shfl_xor(pe[i][v], off);
        pr[i][v] += __shfl_xor(pr[i][v], off);
      }
    }
  if (c == 0) {
#pragma unroll
    for (int i = 0; i < 4; ++i)
#pragma unroll
      for (int v = 0; v < 4; ++v)
        part[wave][i * 16 + rgrp * 4 + v] = make_float2(pe[i][v], pr[i][v]);
  }
  __syncthreads();
  if (tid < 64) {
    float se = 0.f, sr = 0.f;
#pragma unroll
    for (int w = 0; w < 4; ++w) { se += part[w][tid].x; sr += part[w][tid].y; }
    int row = m0 + tid;
    if (row < M) { elr[row] = se; err[row] = sr; }
  }
}

// ---- L2: projected-space gather + relu + predictor dots, 16 lanes/node ---
__global__ __launch_bounds__(256) void gat_agg_dots(
    const int* __restrict__ row_ptr, const int* __restrict__ csr_src,
    const float* __restrict__ el, const float* __restrict__ er,
    const short* __restrict__ featb,    // [NREL][NN][FIN] bf16 (normal layout)
    const float* __restrict__ beff,     // [FIN]
    const float* __restrict__ Wlin,     // [2*FIN]
    float* __restrict__ dotl, float* __restrict__ dotr)
{
  const int lane  = threadIdx.x & 63;
  const int cl    = lane & 15;
  const int gbase = lane & 48;
  const int node  = blockIdx.x * 16 + (threadIdx.x >> 6) * 4 + (lane >> 4);
  if (node >= NN) return;

  float t[8];
#pragma unroll
  for (int k = 0; k < 8; ++k) t[k] = 0.f;

#pragma unroll
  for (int r = 0; r < NREL; ++r) {
    const int beg = row_ptr[r * NN + node];
    const int end = row_ptr[r * NN + node + 1];
    const float eri = er[r * NN + node];
    const float* elr = el + r * NN;
    const short* fb  = featb + (size_t)r * NN * FIN;

    float dsum = 0.f;
    float f[8];
#pragma unroll
    for (int k = 0; k < 8; ++k) f[k] = 0.f;

    for (int chunk = beg; chunk < end; chunk += 16) {
      int e = chunk + cl;
      int sidx = 0; float a = 0.f;
      if (e < end) {
        sidx = csr_src[e];
        float tv = elr[sidx] + eri;
        tv = tv > 0.f ? tv : SLOPE * tv;
        a = __expf(tv);
      }
      dsum += a;
      const int cnt = (end - chunk < 16) ? end - chunk : 16;
      for (int i = 0; i < cnt; ++i) {
        float aj = __shfl(a, gbase + i);
        int   sj = __shfl(sidx, gbase + i);
        bf16x8 v = *(const bf16x8*)&fb[(size_t)sj * FIN + cl * 8];
#pragma unroll
        for (int k = 0; k < 8; ++k) f[k] = fmaf(bf2f(v[k]), aj, f[k]);
      }
    }
#pragma unroll
    for (int off = 8; off > 0; off >>= 1) dsum += __shfl_xor(dsum, off);
    const float inv = 1.f / (3.f * fmaxf(dsum, 1e-9f));
#pragma unroll
    for (int k = 0; k < 8; ++k) t[k] = fmaf(f[k], inv, t[k]);
  }

  const int c = cl * 8;
  float dl = 0.f, dr = 0.f;
#pragma unroll
  for (int k = 0; k < 8; ++k) {
    float g = fmaxf(t[k] + beff[c + k], 0.f);
    dl = fmaf(g, Wlin[c + k], dl);
    dr = fmaf(g, Wlin[FIN + c + k], dr);
  }
#pragma unroll
  for (int off = 8; off > 0; off >>= 1) {
    dl += __shfl_xor(dl, off);
    dr += __shfl_xor(dr, off);
  }
  if (cl == 0) { dotl[node] = dl; dotr[node] = dr; }
}

// ------------- pair logits -------------------------------------------------
__global__ __launch_bounds__(256) void pair_out(
    const int* __restrict__ edges, const int* __restrict__ n_pairs,
    const float* __restrict__ dotl, const float* __restrict__ dotr,
    const float* __restrict__ blin, float* __restrict__ out)
{
  const int TOT = NREL * NE + NP;
  int p = blockIdx.x * blockDim.x + threadIdx.x;
  if (p >= TOT) return;
  int s, d;
  if (p < NREL * NE) {
    int r = p / NE;
    int e = p - r * NE;
    const int* base = edges + (size_t)r * 2 * NE;
    s = base[e];
    d = base[NE + e];
  } else {
    int q = p - NREL * NE;
    s = n_pairs[2 * q];
    d = n_pairs[2 * q + 1];
  }
  float logit = dotl[s] + dotr[d] + blin[0];
  out[p] = 1.f / (1.f + expf(-logit));
}

extern "C" void kernel_launch(void* const* d_in, const int* in_sizes, int n_in,
                              void* d_out, int out_size, void* d_ws, size_t ws_size,
                              hipStream_t stream) {
  const float* x      = (const float*)d_in[0];
  const int*   edges  = (const int*)d_in[1];
  const int*   npairs = (const int*)d_in[2];
  const float* W1     = (const float*)d_in[3];
  const float* al1    = (const float*)d_in[4];
  const float* ar1    = (const float*)d_in[5];
  const float* b1     = (const float*)d_in[6];
  const float* W2     = (const float*)d_in[7];
  const float* al2    = (const float*)d_in[8];
  const float* ar2    = (const float*)d_in[9];
  const float* b2     = (const float*)d_in[10];
  const float* Wlin   = (const float*)d_in[11];
  const float* blin   = (const float*)d_in[12];
  float* out = (float*)d_out;

  char* w = (char*)d_ws;
  size_t off = 0;
  auto alloc = [&](size_t bytes) {
    char* p = w + off;
    off = (off + bytes + 255) & ~(size_t)255;
    return p;
  };
  short* xb      = (short*)alloc((size_t)NN * FIN * 2);     // 12.8 MB
  short* hb      = (short*)alloc((size_t)NN * HD * 2);      // 25.6 MB
  short* A1      = (short*)alloc((size_t)NN * K1 * 2);      // 38.4 MB (f16)
  short* featb2  = A1;   // aliased: A1 dead after gemm_hl (needs 38.4 MB)
  short* W1d     = (short*)alloc((size_t)HD * K1 * 2);      // 196 KB (f16)
  short* W2t     = (short*)alloc((size_t)NREL * FIN * HD * 2);
  float* wvec1   = (float*)alloc(6 * FIN * 4);
  float* beff1   = (float*)alloc(HD * 4);
  float* beff2   = (float*)alloc(FIN * 4);
  float* el      = (float*)alloc((size_t)NREL * NN * 4);
  float* er      = (float*)alloc((size_t)NREL * NN * 4);
  float* dotl    = (float*)alloc((size_t)NN * 4);
  float* dotr    = (float*)alloc((size_t)NN * 4);
  int*   deg     = (int*)  alloc((size_t)NREL * NN * 4);
  int*   cursor  = (int*)  alloc((size_t)NREL * NN * 4);
  int*   row_ptr = (int*)  alloc((size_t)(NREL * NN + 16) * 4);
  int*   psum    = (int*)  alloc(1024);
  int*   pexcl   = (int*)  alloc(1024);
  int*   csr_src = (int*)  alloc((size_t)NREL * NE * 4);

  const int B = 256;

  // ---------------- prep (1 kernel) ---------------------------------------
  prep_all<<<7212, B, 0, stream>>>(x, W1, W2, al1, ar1, b1, b2,
                                   xb, W1d, W2t, wvec1, beff1, beff2);

  // ---------------- CSR build ---------------------------------------------
  hipMemsetAsync(deg, 0, (size_t)NREL * NN * 4, stream);
  count_deg<<<(NREL * NE + B - 1) / B, B, 0, stream>>>(edges, deg);
  deg_partial<<<150, B, 0, stream>>>(deg, psum);
  scan_psum<<<1, B, 0, stream>>>(psum, pexcl);
  deg_rowptr<<<150, B, 0, stream>>>(deg, pexcl, row_ptr, cursor);
  fill_csr<<<(NREL * NE + B - 1) / B, B, 0, stream>>>(edges, cursor, csr_src);

  const int AGG_G  = (NN + 3) / 4;
  const int AGG16  = (NN + 15) / 16;    // 3125
  const int GEMM_GX = (NN + 63) / 64;   // 782

  // ---------------- layer 1: scores, input-space gather, GEMM -> hb -------
  rowdot6<<<AGG_G, B, 0, stream>>>(xb, wvec1, el, er);
  gat_gather_hl<<<AGG16, B, 0, stream>>>(row_ptr, csr_src, el, er, xb, A1);
  gemm_hl<<<GEMM_GX, B, 0, stream>>>(A1, W1d, beff1, hb, NN);

  // ---------------- layer 2: project, gather+dots -------------------------
  {
    dim3 g(GEMM_GX, NREL);
    gemm_fused2<<<g, B, 0, stream>>>(hb, W2t, al2, ar2, featb2, el, er, NN);
  }
  gat_agg_dots<<<AGG16, B, 0, stream>>>(row_ptr, csr_src, el, er, featb2,
                                        beff2, Wlin, dotl, dotr);

  // ---------------- pair predictor ----------------------------------------
  const int TOT = NREL * NE + NP;
  pair_out<<<(TOT + B - 1) / B, B, 0, stream>>>(edges, npairs, dotl, dotr, blin, out);
}

// Round 14
// 225.831 us; speedup vs baseline: 1.8276x; 1.1392x over previous
//
#include <hip/hip_runtime.h>
#include <cstddef>

#define NN 50000
#define NREL 3
#define NE 250000
#define NP 100000
#define FIN 128
#define HD 256
#define SLOPE 0.2f
#define K1 (NREL * FIN)          // 384

typedef short bf16x8 __attribute__((ext_vector_type(8)));
typedef short bf16x2 __attribute__((ext_vector_type(2)));
typedef float f32x4 __attribute__((ext_vector_type(4)));
typedef _Float16 half8 __attribute__((ext_vector_type(8)));

__device__ __forceinline__ short f2bf(float f) {
  unsigned u = __float_as_uint(f);
  unsigned r = (u + 0x7FFFu + ((u >> 16) & 1u)) >> 16;   // RNE
  return (short)r;
}
__device__ __forceinline__ float bf2f(short s) {
  return __uint_as_float(((unsigned)(unsigned short)s) << 16);
}

// async global->LDS, 16 bytes per lane; lds ptr must be wave-uniform base.
__device__ __forceinline__ void gload16(const short* g, short* l) {
  __builtin_amdgcn_global_load_lds(
      (const __attribute__((address_space(1))) unsigned int*)g,
      (__attribute__((address_space(3))) unsigned int*)l, 16, 0, 0);
}

// -------- fused prep + edge counting (rank capture) -----------------------
// ranges: [0,2930) count+rank | [2930,9180) xconv | [9180,9564) W1d f16
//         [9564,9948) W2t | [9948,10140) wvec1 | [10140,10142) beff
// swizzle: element (n,k) stored at k ^ ((n&7)<<3)  [within 64-short windows]
__global__ __launch_bounds__(256) void prep_all(
    const float* __restrict__ x,  const float* __restrict__ W1,
    const float* __restrict__ W2, const float* __restrict__ al1,
    const float* __restrict__ ar1, const float* __restrict__ b1,
    const float* __restrict__ b2,  const int* __restrict__ edges,
    int* __restrict__ deg, int* __restrict__ rank,
    short* __restrict__ xb, short* __restrict__ W1d, short* __restrict__ W2t,
    float* __restrict__ wvec1, float* __restrict__ beff1, float* __restrict__ beff2)
{
  const int blk = blockIdx.x;
  const int t = threadIdx.x;
  if (blk < 2930) {                                   // edge count + rank
    int tid2 = blk * 256 + t;
    if (tid2 < NREL * NE) {
      int r = tid2 / NE;
      int e = tid2 - r * NE;
      int d = edges[(size_t)r * 2 * NE + NE + e];
      rank[tid2] = atomicAdd(&deg[r * NN + d], 1);
    }
  } else if (blk < 9180) {                            // x -> bf16
    int i = ((blk - 2930) * 256 + t) * 4;
    float4 v = *(const float4*)&x[i];
    short4 o = {f2bf(v.x), f2bf(v.y), f2bf(v.z), f2bf(v.w)};
    *(short4*)&xb[i] = o;
  } else if (blk < 9564) {                            // W1d[n][kpos] f16, k<384
    int o = (blk - 9180) * 256 + t;
    int n = o / K1;
    int kpos = o - n * K1;
    int ke = kpos ^ ((n & 7) << 3);                   // element for this slot
    int r = ke / FIN, kk = ke - r * FIN;
    ((_Float16*)W1d)[o] = (_Float16)W1[((size_t)r * FIN + kk) * HD + n];
  } else if (blk < 9948) {                            // W2t[r][n][kpos] bf16
    int o = (blk - 9564) * 256 + t;
    int r = o / (FIN * HD);
    int rem = o - r * (FIN * HD);
    int n = rem / HD, kpos = rem - n * HD;
    int ke = kpos ^ ((n & 7) << 3);
    W2t[o] = f2bf(W2[((size_t)r * HD + ke) * FIN + n]);
  } else if (blk < 10140) {                           // wvec1[j][k] = W1_r[k,:]·v
    int wid = (blk - 9948) * 4 + (t >> 6);
    int lane = t & 63;
    if (wid < 6 * FIN) {
      int j = wid / FIN, k = wid - j * FIN;
      int side = j / 3, r = j - side * 3;
      const float* v  = (side ? ar1 : al1) + r * HD;
      const float* Wr = W1 + ((size_t)r * FIN + k) * HD;
      float s = 0.f;
      for (int n = lane; n < HD; n += 64) s += Wr[n] * v[n];
#pragma unroll
      for (int off = 32; off > 0; off >>= 1) s += __shfl_down(s, off);
      if (lane == 0) wvec1[wid] = s;
    }
  } else {                                            // beff
    int t2 = (blk - 10140) * 256 + t;
    if (t2 < HD) beff1[t2] = (b1[t2] + b1[HD + t2] + b1[2 * HD + t2]) * (1.f / 3.f);
    else if (t2 < HD + FIN) {
      int k = t2 - HD;
      beff2[k] = (b2[k] + b2[FIN + k] + b2[2 * FIN + k]) * (1.f / 3.f);
    }
  }
}

// ------- el/er for layer 1: d[j] = xb[i,:]·wvec1[j,:], j<6 ----------------
__global__ __launch_bounds__(256) void rowdot6(
    const short* __restrict__ feat, const float* __restrict__ wvec,
    float* __restrict__ el, float* __restrict__ er)
{
  const int lane = threadIdx.x & 63;
  const int node = blockIdx.x * 4 + (threadIdx.x >> 6);
  if (node >= NN) return;
  bf16x2 f16 = *(const bf16x2*)&feat[(size_t)node * FIN + lane * 2];
  float f0 = bf2f(f16[0]), f1 = bf2f(f16[1]);
  float d[6];
#pragma unroll
  for (int j = 0; j < 6; ++j)
    d[j] = f0 * wvec[j * FIN + lane * 2] + f1 * wvec[j * FIN + lane * 2 + 1];
#pragma unroll
  for (int off = 32; off > 0; off >>= 1)
#pragma unroll
    for (int j = 0; j < 6; ++j) d[j] += __shfl_xor(d[j], off);
  if (lane == 0) {
    el[0 * NN + node] = d[0]; el[1 * NN + node] = d[1]; el[2 * NN + node] = d[2];
    er[0 * NN + node] = d[3]; er[1 * NN + node] = d[4]; er[2 * NN + node] = d[5];
  }
}

// ------------- CSR scan phase 1 -------------------------------------------
__global__ __launch_bounds__(256) void deg_partial(
    const int* __restrict__ deg, int* __restrict__ psum)
{
  const int b = blockIdx.x;
  const int t = threadIdx.x;
  int4 v = {0, 0, 0, 0};
  if (t < 250) v = *(const int4*)&deg[b * 1000 + t * 4];
  int s = v.x + v.y + v.z + v.w;
#pragma unroll
  for (int off = 32; off > 0; off >>= 1) s += __shfl_down(s, off);
  __shared__ int ws[4];
  if ((t & 63) == 0) ws[t >> 6] = s;
  __syncthreads();
  if (t == 0) psum[b] = ws[0] + ws[1] + ws[2] + ws[3];
}

// ------------- CSR scan phase 2 -------------------------------------------
__global__ __launch_bounds__(256) void scan_psum(
    const int* __restrict__ psum, int* __restrict__ pexcl)
{
  __shared__ int lds[256];
  const int t = threadIdx.x;
  int v = (t < 150) ? psum[t] : 0;
  lds[t] = v;
  __syncthreads();
  for (int off = 1; off < 256; off <<= 1) {
    int add = (t >= off) ? lds[t - off] : 0;
    __syncthreads();
    lds[t] += add;
    __syncthreads();
  }
  if (t < 150) pexcl[t] = lds[t] - v;
}

// ------------- CSR scan phase 3: row_ptr --------------------------------
__global__ __launch_bounds__(256) void deg_rowptr(
    const int* __restrict__ deg, const int* __restrict__ pexcl,
    int* __restrict__ row_ptr)
{
  const int b = blockIdx.x;
  const int t = threadIdx.x;
  int4 v = {0, 0, 0, 0};
  if (t < 250) v = *(const int4*)&deg[b * 1000 + t * 4];
  int s = v.x + v.y + v.z + v.w;
  __shared__ int lds[256];
  lds[t] = s;
  __syncthreads();
  for (int off = 1; off < 256; off <<= 1) {
    int add = (t >= off) ? lds[t - off] : 0;
    __syncthreads();
    lds[t] += add;
    __syncthreads();
  }
  int run = lds[t] - s + pexcl[b];
  if (t < 250) {
    int i = b * 1000 + t * 4;
    row_ptr[i] = run;     run += v.x;
    row_ptr[i + 1] = run; run += v.y;
    row_ptr[i + 2] = run; run += v.z;
    row_ptr[i + 3] = run;
  }
  if (b == 0 && t == 0) row_ptr[NREL * NN] = NREL * NE;
}

// ------------- CSR fill: atomic-free (uses captured rank) -----------------
__global__ __launch_bounds__(256) void fill_csr(
    const int* __restrict__ edges, const int* __restrict__ row_ptr,
    const int* __restrict__ rank, int* __restrict__ csr_src)
{
  int tid = blockIdx.x * blockDim.x + threadIdx.x;
  if (tid >= NREL * NE) return;
  int r = tid / NE;
  int e = tid - r * NE;
  const int* base = edges + (size_t)r * 2 * NE;
  int s = base[e];
  int d = base[NE + e];
  csr_src[row_ptr[r * NN + d] + rank[tid]] = s;
}

// ------- L1: input-space fused 3-relation gather, 16 lanes per node -------
// 4 nodes/wave; each lane owns 8 channels. A1 written as fp16, PRE-SWIZZLED:
// element (node,k) at k ^ ((node&7)<<3).
__global__ __launch_bounds__(256) void gat_gather_hl(
    const int* __restrict__ row_ptr, const int* __restrict__ csr_src,
    const float* __restrict__ el, const float* __restrict__ er,
    const short* __restrict__ xb,       // [NN][FIN] bf16
    short* __restrict__ A1)             // [NN][384] f16, swizzled
{
  const int lane  = threadIdx.x & 63;
  const int cl    = lane & 15;
  const int gbase = lane & 48;
  const int node  = blockIdx.x * 16 + (threadIdx.x >> 6) * 4 + (lane >> 4);
  if (node >= NN) return;
  const int sw = (node & 7) << 3;
  const size_t rowbase = (size_t)node * K1;

#pragma unroll
  for (int r = 0; r < NREL; ++r) {
    const int beg = row_ptr[r * NN + node];
    const int end = row_ptr[r * NN + node + 1];
    const float eri = er[r * NN + node];
    const float* elr = el + r * NN;

    float dsum = 0.f;
    float f[8];
#pragma unroll
    for (int k = 0; k < 8; ++k) f[k] = 0.f;

    for (int chunk = beg; chunk < end; chunk += 16) {
      int e = chunk + cl;
      int sidx = 0; float a = 0.f;
      if (e < end) {
        sidx = csr_src[e];
        float tv = elr[sidx] + eri;
        tv = tv > 0.f ? tv : SLOPE * tv;
        a = __expf(tv);
      }
      dsum += a;
      const int cnt = (end - chunk < 16) ? end - chunk : 16;
      for (int i = 0; i < cnt; ++i) {
        float aj = __shfl(a, gbase + i);
        int   sj = __shfl(sidx, gbase + i);
        bf16x8 v = *(const bf16x8*)&xb[(size_t)sj * FIN + cl * 8];
#pragma unroll
        for (int k = 0; k < 8; ++k) f[k] = fmaf(bf2f(v[k]), aj, f[k]);
      }
    }
#pragma unroll
    for (int off = 8; off > 0; off >>= 1) dsum += __shfl_xor(dsum, off);
    const float inv = 1.f / (3.f * fmaxf(dsum, 1e-9f));

    half8 hv;
#pragma unroll
    for (int k = 0; k < 8; ++k) hv[k] = (_Float16)(f[k] * inv);
    int u = (r * FIN + cl * 8) ^ sw;       // swizzled within 64-short window
    *(half8*)&A1[rowbase + u] = hv;
  }
}

// ------- L1 GEMM: hb = relu(A1@W1d^T + beff1), f16 MFMA, A read ONCE ------
// BM=64, BN=256 (full width, wave=64 cols), BK=64, K=384. LDS 40 KB.
__global__ __launch_bounds__(256) void gemm_hl(
    const short* __restrict__ A, const short* __restrict__ Bt,
    const float* __restrict__ beff, short* __restrict__ hb, int M)
{
  constexpr int BK = 64;
  __shared__ __align__(16) short AsB[(64 + 256) * BK];  // 40 KB
  short* As = AsB;
  short* Bs = AsB + 64 * BK;
  const int tid  = threadIdx.x;
  const int lane = tid & 63;
  const int wave = tid >> 6;
  const int m0 = blockIdx.x * 64;
  const int n0 = wave * 64;
  const int c    = lane & 15;
  const int rgrp = lane >> 4;
  const int wbase = tid & ~63;         // wave-uniform chunk base

  f32x4 acc[4][4] = {};
  for (int k0 = 0; k0 < K1; k0 += BK) {
    __syncthreads();
#pragma unroll
    for (int q = 0; q < 2; ++q) {      // A: 512 chunks
      int idx = q * 256 + tid;
      int row = idx >> 3, ch = idx & 7;
      int gr = m0 + row; gr = gr < M ? gr : M - 1;
      gload16(&A[(size_t)gr * K1 + k0 + ch * 8], As + (q * 256 + wbase) * 8);
    }
#pragma unroll
    for (int q = 0; q < 8; ++q) {      // B: 2048 chunks (256 cols)
      int jdx = q * 256 + tid;
      int col = jdx >> 3, ch = jdx & 7;
      gload16(&Bt[(size_t)col * K1 + k0 + ch * 8], Bs + (q * 256 + wbase) * 8);
    }
    __syncthreads();
#pragma unroll
    for (int ks = 0; ks < 2; ++ks) {
      const int ko = (ks * 32 + rgrp * 8) ^ ((c & 7) << 3);  // de-swizzle
      half8 a[4], b[4];
#pragma unroll
      for (int i = 0; i < 4; ++i)
        a[i] = *(const half8*)&As[(i * 16 + c) * BK + ko];
#pragma unroll
      for (int j = 0; j < 4; ++j)
        b[j] = *(const half8*)&Bs[(n0 + j * 16 + c) * BK + ko];
#pragma unroll
      for (int i = 0; i < 4; ++i)
#pragma unroll
        for (int j = 0; j < 4; ++j)
          acc[i][j] = __builtin_amdgcn_mfma_f32_16x16x32_f16(a[i], b[j], acc[i][j], 0, 0, 0);
    }
  }
#pragma unroll
  for (int i = 0; i < 4; ++i)
#pragma unroll
    for (int v = 0; v < 4; ++v) {
      int row = m0 + i * 16 + rgrp * 4 + v;
      if (row < M) {
        int srow = (row & 7) << 3;
#pragma unroll
        for (int j = 0; j < 4; ++j) {
          int col = n0 + j * 16 + c;
          hb[(size_t)row * HD + (col ^ srow)] =
              f2bf(fmaxf(acc[i][j][v] + beff[col], 0.f));
        }
      }
    }
}

// ---- L2 GEMM: featb[r] = hb @ W2t[r]^T + el/er epilogue (bf16 MFMA) ------
// BM=64, BN=128 (full N), BK=64, grid y=3. hb/W2t are pre-swizzled.
__global__ __launch_bounds__(256) void gemm_fused2(
    const short* __restrict__ A, const short* __restrict__ Wt,
    const float* __restrict__ al, const float* __restrict__ ar,
    short* __restrict__ featb, float* __restrict__ el, float* __restrict__ er,
    int M)
{
  constexpr int K = HD;                // 256
  constexpr int BK = 64;
  constexpr int N_ = FIN;              // 128
  __shared__ __align__(16) short AsB[(64 + 128) * BK];  // 24 KB
  __shared__ float2 part[4][64];
  short* As = AsB;
  short* Bs = AsB + 64 * BK;
  const int r = blockIdx.y;
  const short* Bt  = Wt + (size_t)r * N_ * K;
  const float* alr = al + r * N_;
  const float* arr = ar + r * N_;
  short* fb  = featb + (size_t)r * M * N_;
  float* elr = el + r * NN;
  float* err = er + r * NN;

  const int tid  = threadIdx.x;
  const int lane = tid & 63;
  const int wave = tid >> 6;
  const int m0 = blockIdx.x * 64;
  const int c    = lane & 15;
  const int rgrp = lane >> 4;
  const int wbase = tid & ~63;

  f32x4 acc[4][2] = {};
  for (int k0 = 0; k0 < K; k0 += BK) {
    __syncthreads();
#pragma unroll
    for (int q = 0; q < 2; ++q) {
      int idx = q * 256 + tid;
      int row = idx >> 3, ch = idx & 7;
      int gr = m0 + row; gr = gr < M ? gr : M - 1;
      gload16(&A[(size_t)gr * K + k0 + ch * 8], As + (q * 256 + wbase) * 8);
    }
#pragma unroll
    for (int q = 0; q < 4; ++q) {
      int jdx = q * 256 + tid;
      int col = jdx >> 3, ch = jdx & 7;
      gload16(&Bt[(size_t)col * K + k0 + ch * 8], Bs + (q * 256 + wbase) * 8);
    }
    __syncthreads();
#pragma unroll
    for (int ks = 0; ks < 2; ++ks) {
      const int ko = (ks * 32 + rgrp * 8) ^ ((c & 7) << 3);
      bf16x8 a[4], b[2];
#pragma unroll
      for (int i = 0; i < 4; ++i)
        a[i] = *(const bf16x8*)&As[(i * 16 + c) * BK + ko];
#pragma unroll
      for (int j = 0; j < 2; ++j)
        b[j] = *(const bf16x8*)&Bs[(wave * 32 + j * 16 + c) * BK + ko];
#pragma unroll
      for (int i = 0; i < 4; ++i)
#pragma unroll
        for (int j = 0; j < 2; ++j)
          acc[i][j] = __builtin_amdgcn_mfma_f32_16x16x32_bf16(a[i], b[j], acc[i][j], 0, 0, 0);
    }
  }

  // epilogue: featb (bf16, normal layout) + el/er dots
  float pe[4][4], pr[4][4];
#pragma unroll
  for (int i = 0; i < 4; ++i)
#pragma unroll
    for (int v = 0; v < 4; ++v) {
      float se = 0.f, sr = 0.f;
#pragma unroll
      for (int j = 0; j < 2; ++j) {
        float av = acc[i][j][v];
        int col = wave * 32 + j * 16 + c;
        se = fmaf(av, alr[col], se);
        sr = fmaf(av, arr[col], sr);
      }
      pe[i][v] = se; pr[i][v] = sr;
    }
#pragma unroll
  for (int i = 0; i < 4; ++i)
#pragma unroll
    for (int v = 0; v < 4; ++v) {
      int row = m0 + i * 16 + rgrp * 4 + v;
      if (row < M) {
#pragma unroll
        for (int j = 0; j < 2; ++j)
          fb[(size_t)row * N_ + wave * 32 + j * 16 + c] = f2bf(acc[i][j][v]);
      }
#pragma unroll
      for (int off = 1; off < 16; off <<= 1) {
        pe[i][v] += __shfl_xor(pe[i][v], off);
        pr[i][v] += __shfl_xor(pr[i][v], off);
      }
    }
  if (c == 0) {
#pragma unroll
    for (int i = 0; i < 4; ++i)
#pragma unroll
      for (int v = 0; v < 4; ++v)
        part[wave][i * 16 + rgrp * 4 + v] = make_float2(pe[i][v], pr[i][v]);
  }
  __syncthreads();
  if (tid < 64) {
    float se = 0.f, sr = 0.f;
#pragma unroll
    for (int w = 0; w < 4; ++w) { se += part[w][tid].x; sr += part[w][tid].y; }
    int row = m0 + tid;
    if (row < M) { elr[row] = se; err[row] = sr; }
  }
}

// ---- L2: projected-space gather + relu + predictor dots, 16 lanes/node ---
__global__ __launch_bounds__(256) void gat_agg_dots(
    const int* __restrict__ row_ptr, const int* __restrict__ csr_src,
    const float* __restrict__ el, const float* __restrict__ er,
    const short* __restrict__ featb,    // [NREL][NN][FIN] bf16 (normal layout)
    const float* __restrict__ beff,     // [FIN]
    const float* __restrict__ Wlin,     // [2*FIN]
    float* __restrict__ dotl, float* __restrict__ dotr)
{
  const int lane  = threadIdx.x & 63;
  const int cl    = lane & 15;
  const int gbase = lane & 48;
  const int node  = blockIdx.x * 16 + (threadIdx.x >> 6) * 4 + (lane >> 4);
  if (node >= NN) return;

  float t[8];
#pragma unroll
  for (int k = 0; k < 8; ++k) t[k] = 0.f;

#pragma unroll
  for (int r = 0; r < NREL; ++r) {
    const int beg = row_ptr[r * NN + node];
    const int end = row_ptr[r * NN + node + 1];
    const float eri = er[r * NN + node];
    const float* elr = el + r * NN;
    const short* fb  = featb + (size_t)r * NN * FIN;

    float dsum = 0.f;
    float f[8];
#pragma unroll
    for (int k = 0; k < 8; ++k) f[k] = 0.f;

    for (int chunk = beg; chunk < end; chunk += 16) {
      int e = chunk + cl;
      int sidx = 0; float a = 0.f;
      if (e < end) {
        sidx = csr_src[e];
        float tv = elr[sidx] + eri;
        tv = tv > 0.f ? tv : SLOPE * tv;
        a = __expf(tv);
      }
      dsum += a;
      const int cnt = (end - chunk < 16) ? end - chunk : 16;
      for (int i = 0; i < cnt; ++i) {
        float aj = __shfl(a, gbase + i);
        int   sj = __shfl(sidx, gbase + i);
        bf16x8 v = *(const bf16x8*)&fb[(size_t)sj * FIN + cl * 8];
#pragma unroll
        for (int k = 0; k < 8; ++k) f[k] = fmaf(bf2f(v[k]), aj, f[k]);
      }
    }
#pragma unroll
    for (int off = 8; off > 0; off >>= 1) dsum += __shfl_xor(dsum, off);
    const float inv = 1.f / (3.f * fmaxf(dsum, 1e-9f));
#pragma unroll
    for (int k = 0; k < 8; ++k) t[k] = fmaf(f[k], inv, t[k]);
  }

  const int c = cl * 8;
  float dl = 0.f, dr = 0.f;
#pragma unroll
  for (int k = 0; k < 8; ++k) {
    float g = fmaxf(t[k] + beff[c + k], 0.f);
    dl = fmaf(g, Wlin[c + k], dl);
    dr = fmaf(g, Wlin[FIN + c + k], dr);
  }
#pragma unroll
  for (int off = 8; off > 0; off >>= 1) {
    dl += __shfl_xor(dl, off);
    dr += __shfl_xor(dr, off);
  }
  if (cl == 0) { dotl[node] = dl; dotr[node] = dr; }
}

// ------------- pair logits -------------------------------------------------
__global__ __launch_bounds__(256) void pair_out(
    const int* __restrict__ edges, const int* __restrict__ n_pairs,
    const float* __restrict__ dotl, const float* __restrict__ dotr,
    const float* __restrict__ blin, float* __restrict__ out)
{
  const int TOT = NREL * NE + NP;
  int p = blockIdx.x * blockDim.x + threadIdx.x;
  if (p >= TOT) return;
  int s, d;
  if (p < NREL * NE) {
    int r = p / NE;
    int e = p - r * NE;
    const int* base = edges + (size_t)r * 2 * NE;
    s = base[e];
    d = base[NE + e];
  } else {
    int q = p - NREL * NE;
    s = n_pairs[2 * q];
    d = n_pairs[2 * q + 1];
  }
  float logit = dotl[s] + dotr[d] + blin[0];
  out[p] = 1.f / (1.f + expf(-logit));
}

extern "C" void kernel_launch(void* const* d_in, const int* in_sizes, int n_in,
                              void* d_out, int out_size, void* d_ws, size_t ws_size,
                              hipStream_t stream) {
  const float* x      = (const float*)d_in[0];
  const int*   edges  = (const int*)d_in[1];
  const int*   npairs = (const int*)d_in[2];
  const float* W1     = (const float*)d_in[3];
  const float* al1    = (const float*)d_in[4];
  const float* ar1    = (const float*)d_in[5];
  const float* b1     = (const float*)d_in[6];
  const float* W2     = (const float*)d_in[7];
  const float* al2    = (const float*)d_in[8];
  const float* ar2    = (const float*)d_in[9];
  const float* b2     = (const float*)d_in[10];
  const float* Wlin   = (const float*)d_in[11];
  const float* blin   = (const float*)d_in[12];
  float* out = (float*)d_out;

  char* w = (char*)d_ws;
  size_t off = 0;
  auto alloc = [&](size_t bytes) {
    char* p = w + off;
    off = (off + bytes + 255) & ~(size_t)255;
    return p;
  };
  short* xb      = (short*)alloc((size_t)NN * FIN * 2);     // 12.8 MB
  short* hb      = (short*)alloc((size_t)NN * HD * 2);      // 25.6 MB
  short* A1      = (short*)alloc((size_t)NN * K1 * 2);      // 38.4 MB (f16)
  short* featb2  = A1;   // aliased: A1 dead after gemm_hl (needs 38.4 MB)
  short* W1d     = (short*)alloc((size_t)HD * K1 * 2);      // 196 KB (f16)
  short* W2t     = (short*)alloc((size_t)NREL * FIN * HD * 2);
  float* wvec1   = (float*)alloc(6 * FIN * 4);
  float* beff1   = (float*)alloc(HD * 4);
  float* beff2   = (float*)alloc(FIN * 4);
  float* el      = (float*)alloc((size_t)NREL * NN * 4);
  float* er      = (float*)alloc((size_t)NREL * NN * 4);
  float* dotl    = (float*)alloc((size_t)NN * 4);
  float* dotr    = (float*)alloc((size_t)NN * 4);
  int*   deg     = (int*)  alloc((size_t)NREL * NN * 4);
  int*   rank    = (int*)  alloc((size_t)NREL * NE * 4);    // 3 MB
  int*   row_ptr = (int*)  alloc((size_t)(NREL * NN + 16) * 4);
  int*   psum    = (int*)  alloc(1024);
  int*   pexcl   = (int*)  alloc(1024);
  int*   csr_src = (int*)  alloc((size_t)NREL * NE * 4);

  const int B = 256;

  // ---------------- prep + edge count (1 kernel) --------------------------
  hipMemsetAsync(deg, 0, (size_t)NREL * NN * 4, stream);
  prep_all<<<10142, B, 0, stream>>>(x, W1, W2, al1, ar1, b1, b2, edges,
                                    deg, rank, xb, W1d, W2t, wvec1, beff1, beff2);

  // ---------------- CSR scan + atomic-free fill ---------------------------
  deg_partial<<<150, B, 0, stream>>>(deg, psum);
  scan_psum<<<1, B, 0, stream>>>(psum, pexcl);
  deg_rowptr<<<150, B, 0, stream>>>(deg, pexcl, row_ptr);
  fill_csr<<<(NREL * NE + B - 1) / B, B, 0, stream>>>(edges, row_ptr, rank, csr_src);

  const int AGG_G  = (NN + 3) / 4;
  const int AGG16  = (NN + 15) / 16;    // 3125
  const int GEMM_GX = (NN + 63) / 64;   // 782

  // ---------------- layer 1: scores, input-space gather, GEMM -> hb -------
  rowdot6<<<AGG_G, B, 0, stream>>>(xb, wvec1, el, er);
  gat_gather_hl<<<AGG16, B, 0, stream>>>(row_ptr, csr_src, el, er, xb, A1);
  gemm_hl<<<GEMM_GX, B, 0, stream>>>(A1, W1d, beff1, hb, NN);

  // ---------------- layer 2: project, gather+dots -------------------------
  {
    dim3 g(GEMM_GX, NREL);
    gemm_fused2<<<g, B, 0, stream>>>(hb, W2t, al2, ar2, featb2, el, er, NN);
  }
  gat_agg_dots<<<AGG16, B, 0, stream>>>(row_ptr, csr_src, el, er, featb2,
                                        beff2, Wlin, dotl, dotr);

  // ---------------- pair predictor ----------------------------------------
  const int TOT = NREL * NE + NP;
  pair_out<<<(TOT + B - 1) / B, B, 0, stream>>>(edges, npairs, dotl, dotr, blin, out);
}